// Round 22
// baseline (1992.451 us; speedup 1.0000x reference)
//
#include <hip/hip_runtime.h>
#include <math.h>

#define DI __device__ __forceinline__

namespace {
constexpr int B_ = 32;
constexpr int T_ = 512;
constexpr int N_ = 512;   // d_model
constexpr int C_ = 32;    // c_out / conv_ch / skip_ch
constexpr int KH_ = 481;
constexpr int HOP_ = 48;
constexpr int WIN_ = 48;
constexpr int NFR_ = 11;
constexpr int NBIN_ = 257;
constexpr int NMT_ = B_ * NFR_ * 4;   // 1408 sample-tiles (44 per batch, contiguous)
constexpr int TOKMAX = 21760;   // 170*128 == exact max tokens (L=680)
constexpr int PLW = TOKMAX * 512;     // plane elements for token buffers
constexpr float EPS_ = 1e-5f;

constexpr size_t MBY = 1ull << 20;
constexpr size_t OFF_META = 0;
constexpr size_t OFF_FREQ = 4096;
constexpr size_t OFF_SW   = 8192;
constexpr size_t OFF_BEFF = 16384;       // 1024 floats
constexpr size_t OFF_P12  = 32768;       // 2048 floats
constexpr size_t OFF_FSB  = 65536;       // 257*32 floats (per-(k,b) sums)
constexpr size_t OFF_OSM  = 1 * MBY;     // 2MB (1..3MB)
constexpr size_t OFF_TWH  = 3 * MBY;         // twiddle hi planes [2][384][64] bf16
constexpr size_t OFF_TWL  = 3 * MBY + 131072;// twiddle lo planes
constexpr size_t OFF_WB   = 4 * MBY;     // 6 hi planes x 512KB = 3MB (Q,K,V contiguous!)
constexpr size_t OFF_WDH  = 10 * MBY;    // 1MB  (WdT hi plane [512][1024])
constexpr size_t OFF_EWH  = 12 * MBY;    // 16MB
constexpr size_t OFF_CUR  = 44 * MBY;    // 32MB
constexpr size_t OFF_ACC  = 76 * MBY;    // 32MB
constexpr size_t TR       = 108 * MBY;   // transient union region
// graph phase
constexpr size_t OFF_T    = TR;            // 4MB  T [1024][1024]
constexpr size_t OFF_WPH  = TR + 6 * MBY;  // 1MB  W' hi plane
constexpr size_t OFF_G    = TR + 64 * MBY; // 32MB bf16 [16384][1024]
constexpr size_t OFF_G2   = TR + 128 * MBY;// 32MB bf16 [1024][16384]
constexpr size_t OFF_PART = TR + 192 * MBY;// 32MB [16][1024][512]
// attention phase (aliases graph region): each buffer = hi plane + lo plane
constexpr size_t OFF_A0 = TR;              // 44MB stride each
constexpr size_t OFF_A2 = TR + 44 * MBY;
constexpr size_t OFF_A3 = TR + 88 * MBY;
constexpr size_t OFF_A4 = TR + 132 * MBY;
constexpr size_t OFF_A5 = TR + 176 * MBY;  // ends 328MB
// stft scratch aliases TR (stft completes before graph phase starts)
constexpr size_t OFF_XWH = TR;              // 23MB bf16 [180224][64] (x hi)
constexpr size_t OFF_XWL = TR + 24 * MBY;   // 23MB bf16 (x lo)
constexpr size_t OFF_FP  = TR + 48 * MBY;   // NBIN_*NMT_ floats ~1.45MB
} // namespace

typedef __attribute__((ext_vector_type(2))) float f32x2;
typedef __attribute__((ext_vector_type(4))) float f32x4;
typedef __attribute__((ext_vector_type(8))) short bf8;
typedef __attribute__((ext_vector_type(8))) unsigned short u16x8;

DI float gelu_exact(float x) { return 0.5f * x * (1.0f + erff(x * 0.7071067811865475f)); }
DI unsigned short f2bf(float f) {   // round-to-nearest-even
  unsigned u = __float_as_uint(f);
  u += 0x7FFFu + ((u >> 16) & 1u);
  return (unsigned short)(u >> 16);
}
DI float bf2f(unsigned short s) { return __uint_as_float(((unsigned)s) << 16); }
DI float ld2(const unsigned short* __restrict__ H, const unsigned short* __restrict__ L,
             size_t i) { return bf2f(H[i]) + bf2f(L[i]); }
DI void st2(unsigned short* __restrict__ H, unsigned short* __restrict__ L,
            size_t i, float v) {
  unsigned short h = f2bf(v);
  H[i] = h;
  L[i] = f2bf(v - bf2f(h));
}
DI void gll16(const unsigned short* g, unsigned short* l) {
  __builtin_amdgcn_global_load_lds(
      (const __attribute__((address_space(1))) void*)g,
      (__attribute__((address_space(3))) void*)l, 16, 0, 0);
}

// ---------------- build raw-x frames hi/lo: XW [180224][64] (NO window here) ----------------
__global__ __launch_bounds__(256) void k_xw(const float* __restrict__ x,
                                            unsigned short* __restrict__ XWH,
                                            unsigned short* __restrict__ XWL) {
  int bf = blockIdx.x;            // b*NFR + f
  int f = bf % NFR_, b = bf / NFR_;
  int tid = threadIdx.x;
  for (int i = tid; i < 512 * 8; i += 256) {
    int n = i >> 3, jc = i & 7;
    size_t m = (size_t)bf * 512 + n;
    u16x8 vh, vl;
#pragma unroll
    for (int q = 0; q < 8; ++q) {
      int j = jc * 8 + q;
      if (j < WIN_) {
        int gi = f * HOP_ + 232 + j - 256;
        if (gi < 0) gi = -gi;   // reflect pad (left only)
        float v = x[((size_t)b * T_ + gi) * N_ + n];
        unsigned short h = f2bf(v);
        vh[q] = h;
        vl[q] = f2bf(v - bf2f(h));
      } else { vh[q] = 0; vl[q] = 0; }
    }
    *(u16x8*)&XWH[m * 64 + jc * 8] = vh;
    *(u16x8*)&XWL[m * 64 + jc * 8] = vl;
  }
}

// ---------------- build twiddle hi/lo planes [2][384][64] (window baked in HERE) ----------------
__global__ void k_tw(unsigned short* __restrict__ TWH, unsigned short* __restrict__ TWL) {
  int idx = blockIdx.x * 256 + threadIdx.x;   // 2*384*64 = 49152
  if (idx >= 2 * 384 * 64) return;
  int pl = idx / (384 * 64);
  int rem = idx % (384 * 64);
  int k = rem >> 6, j = rem & 63;
  float v = 0.f;
  if (k < NBIN_ && j < WIN_) {
    int r = (k * (232 + j)) & 511;
    float ang = (float)r * 0.012271846303085130f;   // 2pi/512
    float w = 0.5f - 0.5f * cosf((float)j * 0.13089969389957472f);
    v = pl == 0 ? w * cosf(ang) : w * sinf(ang);
  }
  unsigned short h = f2bf(v);
  TWH[idx] = h;
  TWL[idx] = f2bf(v - bf2f(h));
}

// ---------------- MFMA STFT: mags summed per (k, sample-tile) ----------------
__global__ __launch_bounds__(256, 2) void k_stftmm(
    const unsigned short* __restrict__ XWH, const unsigned short* __restrict__ XWL,
    const unsigned short* __restrict__ TWH, const unsigned short* __restrict__ TWL,
    float* __restrict__ fpart) {
  const int bn = blockIdx.x * 128;     // k-tile base (0,128,256)
  const int mtile = blockIdx.y;
  const int bm = mtile * 128;

  __shared__ __align__(16) unsigned short AHS[4096], ALS[4096], RHS[4096], RLS[4096],
                                          IHS[4096], ILS[4096];
  __shared__ float colpart[2][128];

  const int tid = threadIdx.x;
  const int wave = tid >> 6, lane = tid & 63;
  const int wr = wave >> 1, wc = wave & 1;
  const int fr = lane & 15, fs = lane >> 4;

  const int row0 = tid >> 2;
  const int s0 = (tid & 3) ^ ((row0 >> 1) & 3);
  const unsigned short* gAH0 = XWH + (size_t)(bm + row0) * 64 + s0 * 8;
  const unsigned short* gAH1 = gAH0 + (size_t)64 * 64;
  const unsigned short* gAL0 = XWL + (size_t)(bm + row0) * 64 + s0 * 8;
  const unsigned short* gAL1 = gAL0 + (size_t)64 * 64;
  const unsigned short* gRH0 = TWH + (size_t)(bn + row0) * 64 + s0 * 8;
  const unsigned short* gRH1 = gRH0 + (size_t)64 * 64;
  const unsigned short* gRL0 = TWL + (size_t)(bn + row0) * 64 + s0 * 8;
  const unsigned short* gRL1 = gRL0 + (size_t)64 * 64;
  const unsigned short* gIH0 = gRH0 + (size_t)384 * 64;
  const unsigned short* gIH1 = gRH1 + (size_t)384 * 64;
  const unsigned short* gIL0 = gRL0 + (size_t)384 * 64;
  const unsigned short* gIL1 = gRL1 + (size_t)384 * 64;
  const int lb0 = wave * 512, lb1 = 2048 + wave * 512;

  int aoff[4], boff[4];
#pragma unroll
  for (int m = 0; m < 4; ++m) {
    int ra = wr * 64 + m * 16 + fr;
    aoff[m] = ra * 32 + 8 * (fs ^ ((ra >> 1) & 3));
    int rb = wc * 64 + m * 16 + fr;
    boff[m] = rb * 32 + 8 * (fs ^ ((rb >> 1) & 3));
  }

  f32x4 are[4][4], aim[4][4];
#pragma unroll
  for (int m = 0; m < 4; ++m)
#pragma unroll
    for (int n = 0; n < 4; ++n) {
      are[m][n] = (f32x4){0.f, 0.f, 0.f, 0.f};
      aim[m][n] = (f32x4){0.f, 0.f, 0.f, 0.f};
    }

  for (int k0 = 0; k0 < 64; k0 += 32) {
    __syncthreads();
    gll16(gAH0 + k0, &AHS[lb0]); gll16(gAH1 + k0, &AHS[lb1]);
    gll16(gAL0 + k0, &ALS[lb0]); gll16(gAL1 + k0, &ALS[lb1]);
    gll16(gRH0 + k0, &RHS[lb0]); gll16(gRH1 + k0, &RHS[lb1]);
    gll16(gRL0 + k0, &RLS[lb0]); gll16(gRL1 + k0, &RLS[lb1]);
    gll16(gIH0 + k0, &IHS[lb0]); gll16(gIH1 + k0, &IHS[lb1]);
    gll16(gIL0 + k0, &ILS[lb0]); gll16(gIL1 + k0, &ILS[lb1]);
    __syncthreads();
    bf8 ah[4], al[4], rh[4], rl[4], ih[4], il[4];
#pragma unroll
    for (int m = 0; m < 4; ++m) {
      ah[m] = *(const bf8*)&AHS[aoff[m]];
      al[m] = *(const bf8*)&ALS[aoff[m]];
    }
#pragma unroll
    for (int n = 0; n < 4; ++n) {
      rh[n] = *(const bf8*)&RHS[boff[n]];
      rl[n] = *(const bf8*)&RLS[boff[n]];
      ih[n] = *(const bf8*)&IHS[boff[n]];
      il[n] = *(const bf8*)&ILS[boff[n]];
    }
#pragma unroll
    for (int m = 0; m < 4; ++m)
#pragma unroll
      for (int n = 0; n < 4; ++n) {
        are[m][n] = __builtin_amdgcn_mfma_f32_16x16x32_bf16(ah[m], rh[n], are[m][n], 0, 0, 0);
        are[m][n] = __builtin_amdgcn_mfma_f32_16x16x32_bf16(ah[m], rl[n], are[m][n], 0, 0, 0);
        are[m][n] = __builtin_amdgcn_mfma_f32_16x16x32_bf16(al[m], rh[n], are[m][n], 0, 0, 0);
        aim[m][n] = __builtin_amdgcn_mfma_f32_16x16x32_bf16(ah[m], ih[n], aim[m][n], 0, 0, 0);
        aim[m][n] = __builtin_amdgcn_mfma_f32_16x16x32_bf16(ah[m], il[n], aim[m][n], 0, 0, 0);
        aim[m][n] = __builtin_amdgcn_mfma_f32_16x16x32_bf16(al[m], ih[n], aim[m][n], 0, 0, 0);
      }
  }

  float s[4];
#pragma unroll
  for (int n = 0; n < 4; ++n) {
    float acc = 0.f;
#pragma unroll
    for (int m = 0; m < 4; ++m)
#pragma unroll
      for (int r = 0; r < 4; ++r) {
        float re = are[m][n][r], im = aim[m][n][r];
        acc += sqrtf(re * re + im * im);
      }
    acc += __shfl_xor(acc, 16);
    acc += __shfl_xor(acc, 32);
    s[n] = acc;
  }
  if (fs == 0) {
#pragma unroll
    for (int n = 0; n < 4; ++n) colpart[wr][wc * 64 + n * 16 + fr] = s[n];
  }
  __syncthreads();
  if (tid < 128) {
    int k = bn + tid;
    if (k < NBIN_) fpart[(size_t)k * NMT_ + mtile] = colpart[0][tid] + colpart[1][tid];
  }
}

// ---------------- reduce -> freq (all-b) and fsumb (per-b) ----------------
__global__ __launch_bounds__(256) void k_fred(const float* __restrict__ fpart,
                                              float* __restrict__ freq,
                                              float* __restrict__ fsumb) {
  int k = blockIdx.x;
  int tid = threadIdx.x;
  int b = tid >> 3, j = tid & 7;   // 8 lanes per batch, 44 values each batch
  float s = 0.f;
  for (int i = j; i < 44; i += 8) s += fpart[(size_t)k * NMT_ + b * 44 + i];
  for (int off = 4; off > 0; off >>= 1) s += __shfl_xor(s, off);
  __shared__ float bs[32];
  if (j == 0) bs[b] = s;
  __syncthreads();
  if (tid < 32) {
    float v = bs[tid];
    fsumb[k * 32 + tid] = v;
    for (int off = 16; off > 0; off >>= 1) v += __shfl_xor(v, off);
    if (tid == 0) freq[k] = v;
  }
}

// ---------------- top-k + meta + sw softmax (fused) ----------------
__global__ void k_topk(const float* __restrict__ freq, const float* __restrict__ fsumb,
                       int* __restrict__ meta, float* __restrict__ swb) {
  __shared__ int stop[3];
  int tid = threadIdx.x;
  if (tid == 0) {
    float bv[3] = {-1e30f, -1e30f, -1e30f};
    int bi[3] = {1, 1, 1};
    for (int k = 1; k < NBIN_; ++k) {
      float v = freq[k];
      if (v > bv[0]) { bv[2]=bv[1]; bi[2]=bi[1]; bv[1]=bv[0]; bi[1]=bi[0]; bv[0]=v; bi[0]=k; }
      else if (v > bv[1]) { bv[2]=bv[1]; bi[2]=bi[1]; bv[1]=v; bi[1]=k; }
      else if (v > bv[2]) { bv[2]=v; bi[2]=k; }
    }
    for (int i = 0; i < 3; ++i) {
      int top = bi[i];
      int p = T_ / top;
      int L = ((T_ + p - 1) / p) * p;
      meta[i] = top;
      meta[3 + i] = p;
      meta[6 + i] = L;
      meta[9 + i] = L / p;
      meta[15 + i] = B_ * L;   // tokens
      stop[i] = top;
    }
  }
  __syncthreads();
  int b = tid;
  if (b < B_) {
    float inv = 1.0f / (float)(NFR_ * N_);
    float m0 = fsumb[stop[0] * 32 + b] * inv;
    float m1 = fsumb[stop[1] * 32 + b] * inv;
    float m2 = fsumb[stop[2] * 32 + b] * inv;
    float mx = fmaxf(m0, fmaxf(m1, m2));
    float e0 = expf(m0 - mx), e1 = expf(m1 - mx), e2 = expf(m2 - mx);
    float s = e0 + e1 + e2;
    swb[b * 4 + 0] = e0 / s; swb[b * 4 + 1] = e1 / s; swb[b * 4 + 2] = e2 / s;
  }
}

// ---------------- fused adjacency + GCN operator prep ----------------
__global__ __launch_bounds__(1024) void k_adjprep(const float* __restrict__ nv1,
                                                  const float* __restrict__ nv2,
                                                  const float* __restrict__ mw,
                                                  const float* __restrict__ mb,
                                                  const float* __restrict__ sb,
                                                  float* __restrict__ P12,
                                                  float* __restrict__ beff) {
  __shared__ float A32s[32][32];
  __shared__ float Ms[32][32], P1s[32][32], P2s[32][32], S1[32], S2[32], sbl[32];
  int tid = threadIdx.x;
  if (tid < 32) {
    int v = tid;
    float row[32];
    for (int w = 0; w < 32; ++w) {
      float s = 0.f;
      for (int d = 0; d < 10; ++d) s += nv1[v * 10 + d] * nv2[d * 32 + w];
      row[w] = fmaxf(s, 0.f);
    }
    float mx = -1e30f;
    for (int w = 0; w < 32; ++w) mx = fmaxf(mx, row[w]);
    float sm = 0.f;
    for (int w = 0; w < 32; ++w) { row[w] = expf(row[w] - mx); sm += row[w]; }
    for (int w = 0; w < 32; ++w) row[w] /= sm;
    row[v] += 1.0f;
    float rs = 0.f;
    for (int w = 0; w < 32; ++w) rs += row[w];
    for (int w = 0; w < 32; ++w) A32s[v][w] = row[w] / rs;
    sbl[tid] = sb[tid];
  }
  __syncthreads();
  int w = tid >> 5, v = tid & 31;
  Ms[w][v] = A32s[v][w];
  __syncthreads();
  float p1 = 0.95f * Ms[w][v] + (w == v ? 0.05f : 0.f);
  P1s[w][v] = p1;
  __syncthreads();
  float p2 = 0.f;
  for (int u = 0; u < 32; ++u) p2 += P1s[w][u] * Ms[u][v];
  p2 = 0.95f * p2 + (w == v ? 0.05f : 0.f);
  P2s[w][v] = p2;
  P12[tid] = p1;
  P12[1024 + tid] = p2;
  __syncthreads();
  if (tid < 32) {
    float s1 = 0.f, s2 = 0.f;
    for (int u = 0; u < 32; ++u) { s1 += P1s[u][tid]; s2 += P2s[u][tid]; }
    S1[tid] = s1; S2[tid] = s2;
  }
  __syncthreads();
  int o = w;
  float be = mb[o];
  for (int c = 0; c < 32; ++c) {
    float sc = sbl[c];
    be += mw[o * 96 + c] * sc;
    be += mw[o * 96 + 32 + c] * sc * S1[v];
    be += mw[o * 96 + 64 + c] * sc * S2[v];
  }
  beff[tid] = be;
}

// ---------------- build T [1024][1024]: T[(o,v)][(c,w)] ----------------
__global__ __launch_bounds__(256) void k_T(const float* __restrict__ P12,
                                           const float* __restrict__ mw,
                                           float* __restrict__ Tm) {
  int idx = blockIdx.x * 256 + threadIdx.x;
  int r = idx >> 10, k2 = idx & 1023;
  int o = r >> 5, v = r & 31;
  int c = k2 >> 5, w = k2 & 31;
  float t = mw[o * 96 + 32 + c] * P12[w * 32 + v]
          + mw[o * 96 + 64 + c] * P12[1024 + w * 32 + v];
  if (w == v) t += mw[o * 96 + c];
  Tm[idx] = t;
}

// ---------------- build WdT hi: WdT[j][(c,w)] = sw[c][j-w] ----------------
__global__ void k_wdh(const float* __restrict__ swi, unsigned short* __restrict__ WH) {
  int idx = blockIdx.x * 256 + threadIdx.x;   // 512*1024
  int j = idx >> 10, k2 = idx & 1023;
  int c = k2 >> 5, w = k2 & 31;
  int kk = j - w;
  float vv = (kk >= 0 && kk < KH_) ? swi[c * KH_ + kk] : 0.f;
  WH[idx] = f2bf(vv);
}

// ---------------- weight hi split ----------------
__global__ void k_splith(const float* __restrict__ src, unsigned short* __restrict__ Hi,
                         int n) {
  int i = blockIdx.x * 256 + threadIdx.x;
  if (i * 4 >= n) return;
  float4 v = *(const float4*)&src[i * 4];
  ushort4 h;
  h.x = f2bf(v.x); h.y = f2bf(v.y); h.z = f2bf(v.z); h.w = f2bf(v.w);
  *(ushort4*)&Hi[i * 4] = h;
}

// ---------------- 2-MFMA GEMM (fp32 A hi/lo; bf16 weight hi; fold GEMM only) ----------------
__global__ __launch_bounds__(256, 2) void k_mm2(
    const float* __restrict__ A, const unsigned short* __restrict__ Bh,
    const float* __restrict__ bias,
    float* __restrict__ C, float* __restrict__ Cpart,
    int M, int N, int K, int lda, int dogelu) {
  const int bm = blockIdx.y * 128;
  if (bm >= M) return;
  const int bn = blockIdx.x * 128;
  const int nz = gridDim.z, z = blockIdx.z;
  const int kpb = K / nz;
  const int kbeg = z * kpb, kend = kbeg + kpb;

  __shared__ __align__(16) unsigned short AhS[4096], AlS[4096], BhS[4096];

  const int tid = threadIdx.x;
  const int wave = tid >> 6, lane = tid & 63;
  const int wr = wave >> 1, wc = wave & 1;
  const int fr = lane & 15, fs = lane >> 4;

  const int sr = tid >> 1, ss = (tid & 1) * 2;
  const int sx = (sr >> 1) & 3;
  const int so0 = sr * 32 + 8 * (ss ^ sx);
  const int so1 = sr * 32 + 8 * ((ss + 1) ^ sx);

  const int row0 = tid >> 2;
  const int s0 = (tid & 3) ^ ((row0 >> 1) & 3);
  const unsigned short* gBh0 = Bh + (size_t)(bn + row0) * K + s0 * 8;
  const unsigned short* gBh1 = gBh0 + (size_t)64 * K;
  unsigned short* lB0 = &BhS[wave * 512];
  unsigned short* lB1 = &BhS[2048 + wave * 512];

  int aoff[4], boff[4];
#pragma unroll
  for (int m = 0; m < 4; ++m) {
    int ra = wr * 64 + m * 16 + fr;
    aoff[m] = ra * 32 + 8 * (fs ^ ((ra >> 1) & 3));
    int rb = wc * 64 + m * 16 + fr;
    boff[m] = rb * 32 + 8 * (fs ^ ((rb >> 1) & 3));
  }

  const bool aok = (bm + sr) < M;
  const float* Arow = A + (size_t)(bm + sr) * lda + ss * 8;

  f32x4 acc[4][4];
#pragma unroll
  for (int m = 0; m < 4; ++m)
#pragma unroll
    for (int n = 0; n < 4; ++n) acc[m][n] = (f32x4){0.f, 0.f, 0.f, 0.f};

  for (int k0 = kbeg; k0 < kend; k0 += 32) {
    float4 a0, a1, a2, a3;
    if (aok) {
      const float4* p = (const float4*)(Arow + k0);
      a0 = p[0]; a1 = p[1]; a2 = p[2]; a3 = p[3];
    } else {
      a0 = a1 = a2 = a3 = make_float4(0.f, 0.f, 0.f, 0.f);
    }
    float av[16];
    av[0]=a0.x; av[1]=a0.y; av[2]=a0.z; av[3]=a0.w;
    av[4]=a1.x; av[5]=a1.y; av[6]=a1.z; av[7]=a1.w;
    av[8]=a2.x; av[9]=a2.y; av[10]=a2.z; av[11]=a2.w;
    av[12]=a3.x; av[13]=a3.y; av[14]=a3.z; av[15]=a3.w;
    u16x8 h0, h1, l0, l1;
#pragma unroll
    for (int j = 0; j < 8; ++j) {
      unsigned u = __float_as_uint(av[j]);
      h0[j] = (unsigned short)(u >> 16);
      float r2 = av[j] - __uint_as_float(u & 0xffff0000u);
      l0[j] = (unsigned short)(__float_as_uint(r2) >> 16);
      unsigned u2 = __float_as_uint(av[j + 8]);
      h1[j] = (unsigned short)(u2 >> 16);
      float r3 = av[j + 8] - __uint_as_float(u2 & 0xffff0000u);
      l1[j] = (unsigned short)(__float_as_uint(r3) >> 16);
    }
    __syncthreads();   // prior frag reads done
    gll16(gBh0 + k0, lB0); gll16(gBh1 + k0, lB1);
    *(u16x8*)&AhS[so0] = h0; *(u16x8*)&AhS[so1] = h1;
    *(u16x8*)&AlS[so0] = l0; *(u16x8*)&AlS[so1] = l1;
    __syncthreads();   // drains vmcnt + lgkm
    bf8 ah[4], al4[4], bh4[4];
#pragma unroll
    for (int m = 0; m < 4; ++m) {
      ah[m]  = *(const bf8*)&AhS[aoff[m]];
      al4[m] = *(const bf8*)&AlS[aoff[m]];
    }
#pragma unroll
    for (int n = 0; n < 4; ++n) bh4[n] = *(const bf8*)&BhS[boff[n]];
#pragma unroll
    for (int m = 0; m < 4; ++m)
#pragma unroll
      for (int n = 0; n < 4; ++n) {
        acc[m][n] = __builtin_amdgcn_mfma_f32_16x16x32_bf16(ah[m],  bh4[n], acc[m][n], 0, 0, 0);
        acc[m][n] = __builtin_amdgcn_mfma_f32_16x16x32_bf16(al4[m], bh4[n], acc[m][n], 0, 0, 0);
      }
  }

  if (nz > 1) {
    float* P = Cpart + (size_t)z * M * N;
#pragma unroll
    for (int m = 0; m < 4; ++m)
#pragma unroll
      for (int r = 0; r < 4; ++r) {
        int row = bm + wr * 64 + m * 16 + fs * 4 + r;
        if (row < M) {
#pragma unroll
          for (int n = 0; n < 4; ++n) {
            int col = bn + wc * 64 + n * 16 + fr;
            P[(size_t)row * N + col] = acc[m][n][r];
          }
        }
      }
  } else {
    float bcol[4];
#pragma unroll
    for (int n = 0; n < 4; ++n) bcol[n] = bias ? bias[bn + wc * 64 + n * 16 + fr] : 0.f;
#pragma unroll
    for (int m = 0; m < 4; ++m)
#pragma unroll
      for (int r = 0; r < 4; ++r) {
        int row = bm + wr * 64 + m * 16 + fs * 4 + r;
        if (row < M) {
#pragma unroll
          for (int n = 0; n < 4; ++n) {
            int col = bn + wc * 64 + n * 16 + fr;
            float v = acc[m][n][r] + bcol[n];
            if (dogelu) v = gelu_exact(v);
            C[(size_t)row * N + col] = v;
          }
        }
      }
  }
}

// ---------------- conv GEMM: fp32 A hi-only, 1 MFMA, bf16 output + gelu ----------------
__global__ __launch_bounds__(256, 4) void k_mmcv(
    const float* __restrict__ A, const unsigned short* __restrict__ Bh,
    const float* __restrict__ bias,
    unsigned short* __restrict__ C,
    int M, int N, int K, int lda) {
  const int bm = blockIdx.y * 128;
  const int bn = blockIdx.x * 128;

  __shared__ __align__(16) unsigned short AhS[4096], BhS[4096];

  const int tid = threadIdx.x;
  const int wave = tid >> 6, lane = tid & 63;
  const int wr = wave >> 1, wc = wave & 1;
  const int fr = lane & 15, fs = lane >> 4;

  const int sr = tid >> 1, ss = (tid & 1) * 2;
  const int sx = (sr >> 1) & 3;
  const int so0 = sr * 32 + 8 * (ss ^ sx);
  const int so1 = sr * 32 + 8 * ((ss + 1) ^ sx);

  const int row0 = tid >> 2;
  const int s0 = (tid & 3) ^ ((row0 >> 1) & 3);
  const unsigned short* gBh0 = Bh + (size_t)(bn + row0) * K + s0 * 8;
  const unsigned short* gBh1 = gBh0 + (size_t)64 * K;
  unsigned short* lB0 = &BhS[wave * 512];
  unsigned short* lB1 = &BhS[2048 + wave * 512];

  int aoff[4], boff[4];
#pragma unroll
  for (int m = 0; m < 4; ++m) {
    int ra = wr * 64 + m * 16 + fr;
    aoff[m] = ra * 32 + 8 * (fs ^ ((ra >> 1) & 3));
    int rb = wc * 64 + m * 16 + fr;
    boff[m] = rb * 32 + 8 * (fs ^ ((rb >> 1) & 3));
  }

  const float* Arow = A + (size_t)(bm + sr) * lda + ss * 8;

  f32x4 acc[4][4];
#pragma unroll
  for (int m = 0; m < 4; ++m)
#pragma unroll
    for (int n = 0; n < 4; ++n) acc[m][n] = (f32x4){0.f, 0.f, 0.f, 0.f};

  for (int k0 = 0; k0 < K; k0 += 32) {
    const float4* p = (const float4*)(Arow + k0);
    float4 a0 = p[0], a1 = p[1], a2 = p[2], a3 = p[3];
    u16x8 h0, h1;
    h0[0]=f2bf(a0.x); h0[1]=f2bf(a0.y); h0[2]=f2bf(a0.z); h0[3]=f2bf(a0.w);
    h0[4]=f2bf(a1.x); h0[5]=f2bf(a1.y); h0[6]=f2bf(a1.z); h0[7]=f2bf(a1.w);
    h1[0]=f2bf(a2.x); h1[1]=f2bf(a2.y); h1[2]=f2bf(a2.z); h1[3]=f2bf(a2.w);
    h1[4]=f2bf(a3.x); h1[5]=f2bf(a3.y); h1[6]=f2bf(a3.z); h1[7]=f2bf(a3.w);
    __syncthreads();   // prior frag reads done
    gll16(gBh0 + k0, lB0); gll16(gBh1 + k0, lB1);
    *(u16x8*)&AhS[so0] = h0; *(u16x8*)&AhS[so1] = h1;
    __syncthreads();   // drains vmcnt + lgkm
    bf8 ah[4], bh4[4];
#pragma unroll
    for (int m = 0; m < 4; ++m) ah[m] = *(const bf8*)&AhS[aoff[m]];
#pragma unroll
    for (int n = 0; n < 4; ++n) bh4[n] = *(const bf8*)&BhS[boff[n]];
#pragma unroll
    for (int m = 0; m < 4; ++m)
#pragma unroll
      for (int n = 0; n < 4; ++n)
        acc[m][n] = __builtin_amdgcn_mfma_f32_16x16x32_bf16(ah[m], bh4[n], acc[m][n], 0, 0, 0);
  }

  float bcol[4];
#pragma unroll
  for (int n = 0; n < 4; ++n) bcol[n] = bias[bn + wc * 64 + n * 16 + fr];
#pragma unroll
  for (int m = 0; m < 4; ++m)
#pragma unroll
    for (int r = 0; r < 4; ++r) {
      int row = bm + wr * 64 + m * 16 + fs * 4 + r;
#pragma unroll
      for (int n = 0; n < 4; ++n) {
        int col = bn + wc * 64 + n * 16 + fr;
        C[(size_t)row * N + col] = f2bf(gelu_exact(acc[m][n][r] + bcol[n]));
      }
    }
}

// ---------------- end GEMM: bf16 A, bf16 B, 1 MFMA, split-K partials ----------------
__global__ __launch_bounds__(256, 4) void k_mmend(
    const unsigned short* __restrict__ Ah, const unsigned short* __restrict__ Bh,
    float* __restrict__ Cpart, int M, int N, int K) {
  const int bm = blockIdx.y * 128;
  const int bn = blockIdx.x * 128;
  const int nz = gridDim.z, z = blockIdx.z;
  const int kpb = K / nz;
  const int kbeg = z * kpb, kend = kbeg + kpb;

  __shared__ __align__(16) unsigned short AhS[4096], BhS[4096];

  const int tid = threadIdx.x;
  const int wave = tid >> 6, lane = tid & 63;
  const int wr = wave >> 1, wc = wave & 1;
  const int fr = lane & 15, fs = lane >> 4;

  const int row0 = tid >> 2;
  const int s0 = (tid & 3) ^ ((row0 >> 1) & 3);
  const unsigned short* gAh0 = Ah + (size_t)(bm + row0) * K + s0 * 8;
  const unsigned short* gAh1 = gAh0 + (size_t)64 * K;
  const unsigned short* gBh0 = Bh + (size_t)(bn + row0) * K + s0 * 8;
  const unsigned short* gBh1 = gBh0 + (size_t)64 * K;
  const int lb0 = wave * 512, lb1 = 2048 + wave * 512;

  int aoff[4], boff[4];
#pragma unroll
  for (int m = 0; m < 4; ++m) {
    int ra = wr * 64 + m * 16 + fr;
    aoff[m] = ra * 32 + 8 * (fs ^ ((ra >> 1) & 3));
    int rb = wc * 64 + m * 16 + fr;
    boff[m] = rb * 32 + 8 * (fs ^ ((rb >> 1) & 3));
  }

  f32x4 acc[4][4];
#pragma unroll
  for (int m = 0; m < 4; ++m)
#pragma unroll
    for (int n = 0; n < 4; ++n) acc[m][n] = (f32x4){0.f, 0.f, 0.f, 0.f};

  for (int k0 = kbeg; k0 < kend; k0 += 32) {
    __syncthreads();
    gll16(gAh0 + k0, &AhS[lb0]); gll16(gAh1 + k0, &AhS[lb1]);
    gll16(gBh0 + k0, &BhS[lb0]); gll16(gBh1 + k0, &BhS[lb1]);
    __syncthreads();
    bf8 ah[4], bh4[4];
#pragma unroll
    for (int m = 0; m < 4; ++m) ah[m] = *(const bf8*)&AhS[aoff[m]];
#pragma unroll
    for (int n = 0; n < 4; ++n) bh4[n] = *(const bf8*)&BhS[boff[n]];
#pragma unroll
    for (int m = 0; m < 4; ++m)
#pragma unroll
      for (int n = 0; n < 4; ++n)
        acc[m][n] = __builtin_amdgcn_mfma_f32_16x16x32_bf16(ah[m], bh4[n], acc[m][n], 0, 0, 0);
  }

  float* P = Cpart + (size_t)z * M * N;
#pragma unroll
  for (int m = 0; m < 4; ++m)
#pragma unroll
    for (int r = 0; r < 4; ++r) {
      int row = bm + wr * 64 + m * 16 + fs * 4 + r;
#pragma unroll
      for (int n = 0; n < 4; ++n) {
        int col = bn + wc * 64 + n * 16 + fr;
        P[(size_t)row * N + col] = acc[m][n][r];
      }
    }
}

// ---------------- 1-MFMA plane GEMM (attention pipeline; optional lo write) ----------------
__global__ __launch_bounds__(256, 4) void k_mmb1(
    const unsigned short* __restrict__ Ah,
    const unsigned short* __restrict__ Bh,
    const float* __restrict__ bias,
    unsigned short* __restrict__ Ch, unsigned short* __restrict__ Cl,
    int M, int N, int K, const int* __restrict__ Mdyn, int dogelu) {
  if (Mdyn) M = *Mdyn;
  const int bm = blockIdx.y * 128;
  if (bm >= M) return;
  const int bn = blockIdx.x * 128;

  __shared__ __align__(16) unsigned short AhS[4096], BhS[4096];

  const int tid = threadIdx.x;
  const int wave = tid >> 6, lane = tid & 63;
  const int wr = wave >> 1, wc = wave & 1;
  const int fr = lane & 15, fs = lane >> 4;

  const int row0 = tid >> 2;
  const int s0 = (tid & 3) ^ ((row0 >> 1) & 3);
  const unsigned short* gAh0 = Ah + (size_t)(bm + row0) * K + s0 * 8;
  const unsigned short* gAh1 = gAh0 + (size_t)64 * K;
  const unsigned short* gBh0 = Bh + (size_t)(bn + row0) * K + s0 * 8;
  const unsigned short* gBh1 = gBh0 + (size_t)64 * K;
  const int lb0 = wave * 512, lb1 = 2048 + wave * 512;

  int aoff[4], boff[4];
#pragma unroll
  for (int m = 0; m < 4; ++m) {
    int ra = wr * 64 + m * 16 + fr;
    aoff[m] = ra * 32 + 8 * (fs ^ ((ra >> 1) & 3));
    int rb = wc * 64 + m * 16 + fr;
    boff[m] = rb * 32 + 8 * (fs ^ ((rb >> 1) & 3));
  }

  f32x4 acc[4][4];
#pragma unroll
  for (int m = 0; m < 4; ++m)
#pragma unroll
    for (int n = 0; n < 4; ++n) acc[m][n] = (f32x4){0.f, 0.f, 0.f, 0.f};

  for (int k0 = 0; k0 < K; k0 += 32) {
    __syncthreads();
    gll16(gAh0 + k0, &AhS[lb0]); gll16(gAh1 + k0, &AhS[lb1]);
    gll16(gBh0 + k0, &BhS[lb0]); gll16(gBh1 + k0, &BhS[lb1]);
    __syncthreads();
    bf8 ah[4], bh4[4];
#pragma unroll
    for (int m = 0; m < 4; ++m) ah[m] = *(const bf8*)&AhS[aoff[m]];
#pragma unroll
    for (int n = 0; n < 4; ++n) bh4[n] = *(const bf8*)&BhS[boff[n]];
#pragma unroll
    for (int m = 0; m < 4; ++m)
#pragma unroll
      for (int n = 0; n < 4; ++n)
        acc[m][n] = __builtin_amdgcn_mfma_f32_16x16x32_bf16(ah[m], bh4[n], acc[m][n], 0, 0, 0);
  }

  float bcol[4];
#pragma unroll
  for (int n = 0; n < 4; ++n) bcol[n] = bias[bn + wc * 64 + n * 16 + fr];
#pragma unroll
  for (int m = 0; m < 4; ++m)
#pragma unroll
    for (int r = 0; r < 4; ++r) {
      int row = bm + wr * 64 + m * 16 + fs * 4 + r;
      if (row < M) {
#pragma unroll
        for (int n = 0; n < 4; ++n) {
          int col = bn + wc * 64 + n * 16 + fr;
          float v = acc[m][n][r] + bcol[n];
          if (dogelu) v = gelu_exact(v);
          size_t o = (size_t)row * N + col;
          unsigned short h = f2bf(v);
          Ch[o] = h;
          if (Cl) Cl[o] = f2bf(v - bf2f(h));
        }
      }
    }
}

// ---------------- fused QKV GEMM: B=[1536][512] hi; dest selected per n-tile ----------------
__global__ __launch_bounds__(256, 4) void k_mmqkv(
    const unsigned short* __restrict__ Ah,
    const unsigned short* __restrict__ Bh,
    const float* __restrict__ bq, const float* __restrict__ bk,
    const float* __restrict__ bv,
    unsigned short* __restrict__ Qh, unsigned short* __restrict__ Kh,
    unsigned short* __restrict__ Vh,
    int M, int K, const int* __restrict__ Mdyn) {
  if (Mdyn) M = *Mdyn;
  const int bm = blockIdx.y * 128;
  if (bm >= M) return;
  const int bn = blockIdx.x * 128;   // in [0,1536)
  const int sel = bn >> 9;
  unsigned short* Ch = sel == 0 ? Qh : (sel == 1 ? Kh : Vh);
  const float* bias = sel == 0 ? bq : (sel == 1 ? bk : bv);
  const int cb = bn & 511;

  __shared__ __align__(16) unsigned short AhS[4096], BhS[4096];

  const int tid = threadIdx.x;
  const int wave = tid >> 6, lane = tid & 63;
  const int wr = wave >> 1, wc = wave & 1;
  const int fr = lane & 15, fs = lane >> 4;

  const int row0 = tid >> 2;
  const int s0 = (tid & 3) ^ ((row0 >> 1) & 3);
  const unsigned short* gAh0 = Ah + (size_t)(bm + row0) * K + s0 * 8;
  const unsigned short* gAh1 = gAh0 + (size_t)64 * K;
  const unsigned short* gBh0 = Bh + (size_t)(bn + row0) * K + s0 * 8;
  const unsigned short* gBh1 = gBh0 + (size_t)64 * K;
  const int lb0 = wave * 512, lb1 = 2048 + wave * 512;

  int aoff[4], boff[4];
#pragma unroll
  for (int m = 0; m < 4; ++m) {
    int ra = wr * 64 + m * 16 + fr;
    aoff[m] = ra * 32 + 8 * (fs ^ ((ra >> 1) & 3));
    int rb = wc * 64 + m * 16 + fr;
    boff[m] = rb * 32 + 8 * (fs ^ ((rb >> 1) & 3));
  }

  f32x4 acc[4][4];
#pragma unroll
  for (int m = 0; m < 4; ++m)
#pragma unroll
    for (int n = 0; n < 4; ++n) acc[m][n] = (f32x4){0.f, 0.f, 0.f, 0.f};

  for (int k0 = 0; k0 < K; k0 += 32) {
    __syncthreads();
    gll16(gAh0 + k0, &AhS[lb0]); gll16(gAh1 + k0, &AhS[lb1]);
    gll16(gBh0 + k0, &BhS[lb0]); gll16(gBh1 + k0, &BhS[lb1]);
    __syncthreads();
    bf8 ah[4], bh4[4];
#pragma unroll
    for (int m = 0; m < 4; ++m) ah[m] = *(const bf8*)&AhS[aoff[m]];
#pragma unroll
    for (int n = 0; n < 4; ++n) bh4[n] = *(const bf8*)&BhS[boff[n]];
#pragma unroll
    for (int m = 0; m < 4; ++m)
#pragma unroll
      for (int n = 0; n < 4; ++n)
        acc[m][n] = __builtin_amdgcn_mfma_f32_16x16x32_bf16(ah[m], bh4[n], acc[m][n], 0, 0, 0);
  }

  float bcol[4];
#pragma unroll
  for (int n = 0; n < 4; ++n) bcol[n] = bias[cb + wc * 64 + n * 16 + fr];
#pragma unroll
  for (int m = 0; m < 4; ++m)
#pragma unroll
    for (int r = 0; r < 4; ++r) {
      int row = bm + wr * 64 + m * 16 + fs * 4 + r;
      if (row < M) {
#pragma unroll
        for (int n = 0; n < 4; ++n) {
          int col = cb + wc * 64 + n * 16 + fr;
          Ch[(size_t)row * 512 + col] = f2bf(acc[m][n][r] + bcol[n]);
        }
      }
    }
}

// ---------------- split-K reduce 16 (+bias) ----------------
__global__ void k_red16(const float* __restrict__ part, const float* __restrict__ eb,
                        float* __restrict__ dst) {
  int idx = blockIdx.x * 256 + threadIdx.x;   // 1024*512
  float s = eb ? eb[idx & 511] : 0.f;
#pragma unroll
  for (int zz = 0; zz < 16; ++zz) s += part[(size_t)zz * 524288 + idx];
  dst[idx] = s;
}

// ---------------- split-K reduce 8 -> bf16 hi (W' fold) ----------------
__global__ void k_redsplit(const float* __restrict__ part, unsigned short* __restrict__ WH) {
  int idx = blockIdx.x * 256 + threadIdx.x;   // 1024*512
  float s = 0.f;
#pragma unroll
  for (int zz = 0; zz < 8; ++zz) s += part[(size_t)zz * 524288 + idx];
  WH[idx] = f2bf(s);
}

// ---------------- bf16 repack G[(b,s),(c,n)] -> G2[(b,n),(c,s)] ----------------
__global__ __launch_bounds__(256) void k_repackb(const unsigned short* __restrict__ G,
                                                 unsigned short* __restrict__ G2) {
  int bid = blockIdx.x;
  int st = bid & 15, c = (bid >> 4) & 31, b = bid >> 9;
  __shared__ unsigned short tile[32][34];
  int tid = threadIdx.x;
  int n = tid & 31, s = tid >> 5;
  for (int q = 0; q < 4; ++q) {
    int ss = s + q * 8;
    tile[ss][n] = G[((size_t)b * T_ + st * 32 + ss) * 1024 + c * 32 + n];
  }
  __syncthreads();
  int s2 = tid & 31, n2 = tid >> 5;
  for (int q = 0; q < 4; ++q) {
    int nn = n2 + q * 8;
    G2[((size_t)b * 32 + nn) * 16384 + c * 512 + st * 32 + s2] = tile[s2][nn];
  }
}

// ---------------- lw projection + residual + LN -> cur fp32 AND A0 planes ----------------
__global__ __launch_bounds__(256) void k_lwln(const float* __restrict__ osm,
                                              const float* __restrict__ lw,
                                              const float* __restrict__ lb,
                                              const float* __restrict__ curIn,
                                              const float* __restrict__ g,
                                              const float* __restrict__ bt,
                                              float* __restrict__ curOut,
                                              unsigned short* __restrict__ xh,
                                              unsigned short* __restrict__ xl,
                                              const int* __restrict__ meta, int iter) {
  int tok = blockIdx.x;
  int b = tok >> 9, t = tok & 511;
  __shared__ float os[C_];
  __shared__ float red[256];
  int tid = threadIdx.x;
  if (tid < C_) os[tid] = osm[((size_t)b * C_ + tid) * T_ + t];
  __syncthreads();
  float val[2];
#pragma unroll
  for (int q = 0; q < 2; ++q) {
    int m = tid + q * 256;
    float s = lb[m] + curIn[(size_t)tok * N_ + m];
    for (int n2 = 0; n2 < C_; ++n2) s += os[n2] * lw[n2 * N_ + m];
    val[q] = s;
  }
  red[tid] = val[0] + val[1];
  __syncthreads();
  for (int off = 128; off > 0; off >>= 1) { if (tid < off) red[tid] += red[tid + off]; __syncthreads(); }
  float mean = red[0] * (1.0f / N_);
  __syncthreads();
  float d0 = val[0] - mean, d1 = val[1] - mean;
  red[tid] = d0 * d0 + d1 * d1;
  __syncthreads();
  for (int off = 128; off > 0; off >>= 1) { if (tid < off) red[tid] += red[tid + off]; __syncthreads(); }
  float inv = rsqrtf(red[0] * (1.0f / N_) + EPS_);
  float o0 = d0 * inv * g[tid] + bt[tid];
  float o1 = d1 * inv * g[tid + 256] + bt[tid + 256];
  curOut[(size_t)tok * N_ + tid] = o0;
  curOut[(size_t)tok * N_ + tid + 256] = o1;
  int L = meta[6 + iter];
  size_t pi = ((size_t)b * L + t) * N_;
  st2(xh, xl, pi + tid, o0);
  st2(xh, xl, pi + tid + 256, o1);
}

// ---------------- zero pad rows l in [T,L) of A0 planes ----------------
__global__ void k_padtail(unsigned short* __restrict__ xh, unsigned short* __restrict__ xl,
                          const int* __restrict__ meta, int iter) {
  int L = meta[6 + iter];
  int pad = L - T_;
  if (pad <= 0) return;
  size_t total = (size_t)B_ * pad * N_;
  for (size_t idx = (size_t)blockIdx.x * 256 + threadIdx.x; idx < total;
       idx += (size_t)gridDim.x * 256) {
    size_t row = idx >> 9;
    int d = (int)(idx & 511);
    int b = (int)(row / pad), l = T_ + (int)(row % pad);
    size_t o = ((size_t)b * L + l) * N_ + d;
    xh[o] = 0; xl[o] = 0;
  }
}

// ---------------- residual add + LN (planes in, planes out) ----------------
__global__ __launch_bounds__(256) void k_lnadd(const unsigned short* __restrict__ r1h,
                                               const unsigned short* __restrict__ r1l,
                                               const unsigned short* __restrict__ r2h,
                                               const unsigned short* __restrict__ r2l,
                                               const float* __restrict__ g,
                                               const float* __restrict__ bt,
                                               unsigned short* __restrict__ dh,
                                               unsigned short* __restrict__ dl,
                                               const int* __restrict__ meta, int iter) {
  int tokens = meta[15 + iter];
  int tok = blockIdx.x;
  if (tok >= tokens) return;
  __shared__ float red[256];
  int tid = threadIdx.x;
  float val[2];
#pragma unroll
  for (int q = 0; q < 2; ++q) {
    size_t i = (size_t)tok * N_ + tid + q * 256;
    val[q] = ld2(r1h, r1l, i) + ld2(r2h, r2l, i);
  }
  red[tid] = val[0] + val[1];
  __syncthreads();
  for (int off = 128; off > 0; off >>= 1) { if (tid < off) red[tid] += red[tid + off]; __syncthreads(); }
  float mean = red[0] * (1.0f / N_);
  __syncthreads();
  float d0 = val[0] - mean, d1 = val[1] - mean;
  red[tid] = d0 * d0 + d1 * d1;
  __syncthreads();
  for (int off = 128; off > 0; off >>= 1) { if (tid < off) red[tid] += red[tid + off]; __syncthreads(); }
  float inv = rsqrtf(red[0] * (1.0f / N_) + EPS_);
  st2(dh, dl, (size_t)tok * N_ + tid, d0 * inv * g[tid] + bt[tid]);
  st2(dh, dl, (size_t)tok * N_ + tid + 256, d1 * inv * g[tid + 256] + bt[tid + 256]);
}

// ---------------- fused: LN(r1+r2) -> LN -> gelu -> weighted accumulate ----------------
__global__ __launch_bounds__(256) void k_lnfin(const unsigned short* __restrict__ r1h,
                                               const unsigned short* __restrict__ r1l,
                                               const unsigned short* __restrict__ r2h,
                                               const unsigned short* __restrict__ r2l,
                                               const float* __restrict__ g1,
                                               const float* __restrict__ b1,
                                               const float* __restrict__ g2,
                                               const float* __restrict__ b2,
                                               const float* __restrict__ swb,
                                               float* __restrict__ acc,
                                               const int* __restrict__ meta, int iter) {
  int L = meta[6 + iter];
  int tok = blockIdx.x;
  if (tok >= B_ * L) return;
  int b = tok / L, l = tok % L;
  if (l >= T_) return;   // truncated away
  __shared__ float red[256];
  int tid = threadIdx.x;
  float val[2];
#pragma unroll
  for (int q = 0; q < 2; ++q) {
    size_t i = (size_t)tok * N_ + tid + q * 256;
    val[q] = ld2(r1h, r1l, i) + ld2(r2h, r2l, i);
  }
  red[tid] = val[0] + val[1];
  __syncthreads();
  for (int off = 128; off > 0; off >>= 1) { if (tid < off) red[tid] += red[tid + off]; __syncthreads(); }
  float mean = red[0] * (1.0f / N_);
  __syncthreads();
  float d0 = val[0] - mean, d1 = val[1] - mean;
  red[tid] = d0 * d0 + d1 * d1;
  __syncthreads();
  for (int off = 128; off > 0; off >>= 1) { if (tid < off) red[tid] += red[tid + off]; __syncthreads(); }
  float inv = rsqrtf(red[0] * (1.0f / N_) + EPS_);
  float y0 = d0 * inv * g1[tid] + b1[tid];
  float y1 = d1 * inv * g1[tid + 256] + b1[tid + 256];
  // second LN over y
  __syncthreads();
  red[tid] = y0 + y1;
  __syncthreads();
  for (int off = 128; off > 0; off >>= 1) { if (tid < off) red[tid] += red[tid + off]; __syncthreads(); }
  float mean2 = red[0] * (1.0f / N_);
  __syncthreads();
  float e0 = y0 - mean2, e1 = y1 - mean2;
  red[tid] = e0 * e0 + e1 * e1;
  __syncthreads();
  for (int off = 128; off > 0; off >>= 1) { if (tid < off) red[tid] += red[tid + off]; __syncthreads(); }
  float inv2 = rsqrtf(red[0] * (1.0f / N_) + EPS_);
  float s = swb[b * 4 + iter];
  float u0 = gelu_exact(e0 * inv2 * g2[tid] + b2[tid]);
  float u1 = gelu_exact(e1 * inv2 * g2[tid + 256] + b2[tid + 256]);
  size_t o = ((size_t)b * T_ + l) * N_;
  acc[o + tid] += s * u0;
  acc[o + tid + 256] += s * u1;
}

// ---------------- attention S<=32: wave-per-pair, lane=t scores, barrier-free ----------------
__global__ __launch_bounds__(256) void k_attn32(
    const unsigned short* __restrict__ qh,
    const unsigned short* __restrict__ kh,
    const unsigned short* __restrict__ vh,
    unsigned short* __restrict__ oh,
    const int* __restrict__ meta, int iter) {
  int S = meta[3 + iter];
  if (S > 32) return;
  int L = meta[6 + iter], nseq = meta[9 + iter];
  int npair = B_ * nseq * 8;
  __shared__ float Kt[4][64 * 33];
  __shared__ unsigned short Vsh[4][32 * 66];
  __shared__ float qs[4][64];
  int tid = threadIdx.x;
  int wave = tid >> 6, lane = tid & 63;
  float* Ktw = Kt[wave];
  unsigned short* Vw = Vsh[wave];
  int gw = (blockIdx.x * 256 + tid) >> 6;
  int nw = (gridDim.x * 256) >> 6;
  const int tt = lane & 31;
  const int hf = lane >> 5;
  for (int pair = gw; pair < npair; pair += nw) {
    int h = pair & 7;
    int m = pair >> 3;
    int b = m / nseq, g2 = m - b * nseq;
    size_t base = ((size_t)b * L + (size_t)g2 * S) * N_ + h * 64;
    for (int i = lane; i < S * 64; i += 64) {
      int t = i >> 6, d = i & 63;
      size_t gi = base + (size_t)t * N_ + d;
      Ktw[d * 33 + t] = bf2f(kh[gi]);
      Vw[t * 66 + d] = vh[gi];
    }
    bool tok = tt < S;
    for (int s = 0; s < S; ++s) {
      qs[wave][lane] = bf2f(qh[base + (size_t)s * N_ + lane]);
      float part = 0.f;
      if (tok) {
        const float* kp = &Ktw[hf * 32 * 33 + tt];
        const float* qp = &qs[wave][hf * 32];
#pragma unroll 8
        for (int j = 0; j < 32; ++j) part += qp[j] * kp[j * 33];
      }
      part += __shfl_xor(part, 32);
      float sc = tok ? part * 0.125f : -3.0e38f;
      float mx = sc;
      for (int off = 16; off > 0; off >>= 1) mx = fmaxf(mx, __shfl_xor(mx, off));
      float p = tok ? expf(sc - mx) : 0.f;
      float ssum = p;
      for (int off = 16; off > 0; off >>= 1) ssum += __shfl_xor(ssum, off);
      float ov = 0.f;
      for (int t = 0; t < S; ++t) {
        float pt = __shfl(p, t);
        ov += pt * bf2f(Vw[t * 66 + lane]);
      }
      oh[base + (size_t)s * N_ + lane] = f2bf(ov / ssum);
    }
  }
}

// ---------------- MFMA flash attention, 32<S<=128: one block per (seq,head) ----------------
// QK^T and PV via mfma_f32_16x16x32_bf16 reusing the GEMM fragment machinery.
__global__ __launch_bounds__(256, 3) void k_attn_small(
    const unsigned short* __restrict__ qh,
    const unsigned short* __restrict__ kh,
    const unsigned short* __restrict__ vh,
    unsigned short* __restrict__ oh,
    const int* __restrict__ meta, int iter) {
  int S = meta[3 + iter];
  if (S <= 32 || S > 128) return;
  int L = meta[6 + iter], nseq = meta[9 + iter];
  int M = B_ * nseq;
  int mh = blockIdx.x;
  int m0 = mh >> 3, h = mh & 7;
  if (m0 >= M) return;
  int b = m0 / nseq, g2 = m0 % nseq;
  size_t tok0 = (size_t)b * L + (size_t)g2 * S;

  // U: QK phase = {Q kstep0, Q kstep1, K kstep0, K kstep1}; PV phase = P[4 ksteps]
  __shared__ __align__(16) unsigned short U[16384];
  __shared__ __align__(16) unsigned short VT[8192];   // V^T, 4 k-steps [64][32]
  __shared__ float rb1[2][128], rb2[2][128];

  const int tid = threadIdx.x;
  const int wave = tid >> 6, lane = tid & 63;
  const int wr = wave >> 1, wc = wave & 1;
  const int fr = lane & 15, fs = lane >> 4;

  // ---- stage Q,K via global_load_lds (mmb1 pattern, K=64 -> 2 k-steps) ----
  const int row0 = tid >> 2;
  const int s0 = (tid & 3) ^ ((row0 >> 1) & 3);
  const unsigned short* gQ0 = qh + (tok0 + row0) * N_ + h * 64 + s0 * 8;
  const unsigned short* gQ1 = gQ0 + (size_t)64 * N_;
  const unsigned short* gK0 = kh + (tok0 + row0) * N_ + h * 64 + s0 * 8;
  const unsigned short* gK1 = gK0 + (size_t)64 * N_;
  const int lb0 = wave * 512, lb1 = 2048 + wave * 512;
  gll16(gQ0,      &U[lb0]);         gll16(gQ1,      &U[lb1]);
  gll16(gQ0 + 32, &U[4096 + lb0]);  gll16(gQ1 + 32, &U[4096 + lb1]);
  gll16(gK0,      &U[8192 + lb0]);  gll16(gK1,      &U[8192 + lb1]);
  gll16(gK0 + 32, &U[12288 + lb0]); gll16(gK1 + 32, &U[12288 + lb1]);
  // ---- stage V^T via reg transpose into swizzled B layout ----
  for (int i = tid; i < 128 * 8; i += 256) {
    int t = i >> 3, c8 = i & 7;
    u16x8 vv8 = *(const u16x8*)&vh[(tok0 + t) * N_ + h * 64 + c8 * 8];
    int kk = t >> 5, chunk = (t & 31) >> 3, e = t & 7;
#pragma unroll
    for (int q = 0; q < 8; ++q) {
      int d = c8 * 8 + q;
      VT[kk * 2048 + d * 32 + 8 * (chunk ^ ((d >> 1) & 3)) + e] = vv8[q];
    }
  }
  __syncthreads();

  // ---- QK^T: scores[q][k] ----
  int aoff[4], boff[4];
#pragma unroll
  for (int m = 0; m < 4; ++m) {
    int ra = wr * 64 + m * 16 + fr;
    aoff[m] = ra * 32 + 8 * (fs ^ ((ra >> 1) & 3));
    int rb = wc * 64 + m * 16 + fr;
    boff[m] = rb * 32 + 8 * (fs ^ ((rb >> 1) & 3));
  }
  f32x4 acc[4][4];
#pragma unroll
  for (int m = 0; m < 4; ++m)
#pragma unroll
    for (int n = 0; n < 4; ++n) acc[m][n] = (f32x4){0.f, 0.f, 0.f, 0.f};
#pragma unroll
  for (int kk = 0; kk < 2; ++kk) {
    bf8 ah[4], bh[4];
#pragma unroll
    for (int m = 0; m < 4; ++m) ah[m] = *(const bf8*)&U[kk * 4096 + aoff[m]];
#pragma unroll
    for (int n = 0; n < 4; ++n) bh[n] = *(const bf8*)&U[8192 + kk * 4096 + boff[n]];
#pragma unroll
    for (int m = 0; m < 4; ++m)
#pragma unroll
      for (int n = 0; n < 4; ++n)
        acc[m][n] = __builtin_amdgcn_mfma_f32_16x16x32_bf16(ah[m], bh[n], acc[m][n], 0, 0, 0);
  }

  // ---- mask + scale; row-max partials ----
  bool colok[4];
#pragma unroll
  for (int n = 0; n < 4; ++n) colok[n] = (wc * 64 + n * 16 + fr) < S;
#pragma unroll
  for (int m = 0; m < 4; ++m)
#pragma unroll
    for (int n = 0; n < 4; ++n)
#pragma unroll
      for (int r = 0; r < 4; ++r)
        acc[m][n][r] = colok[n] ? acc[m][n][r] * 0.125f : -3.0e38f;
#pragma unroll
  for (int m = 0; m < 4; ++m)
#pragma unroll
    for (int r = 0; r < 4; ++r) {
      float pm = fmaxf(fmaxf(acc[m][0][r], acc[m][1][r]), fmaxf(acc[m][2][r], acc[m][3][r]));
      pm = fmaxf(pm, __shfl_xor(pm, 1));
      pm = fmaxf(pm, __shfl_xor(pm, 2));
      pm = fmaxf(pm, __shfl_xor(pm, 4));
      pm = fmaxf(pm, __shfl_xor(pm, 8));
      if (fr == 0) rb1[wc][wr * 64 + m * 16 + fs * 4 + r] = pm;
    }
  __syncthreads();   // rb1 ready; all U fragment reads complete

  // ---- exp + row-sum partials; scatter P (bf16) into U as PV A-operand ----
#pragma unroll
  for (int m = 0; m < 4; ++m)
#pragma unroll
    for (int r = 0; r < 4; ++r) {
      int row = wr * 64 + m * 16 + fs * 4 + r;
      float mx = fmaxf(rb1[0][row], rb1[1][row]);
      float ps = 0.f;
#pragma unroll
      for (int n = 0; n < 4; ++n) {
        float e = expf(acc[m][n][r] - mx);
        acc[m][n][r] = e;
        ps += e;
      }
      ps += __shfl_xor(ps, 1);
      ps += __shfl_xor(ps, 2);
      ps += __shfl_xor(ps, 4);
      ps += __shfl_xor(ps, 8);
      if (fr == 0) rb2[wc][row] = ps;
    }
#pragma unroll
  for (int m = 0; m < 4; ++m)
#pragma unroll
    for (int n = 0; n < 4; ++n) {
      int col = wc * 64 + n * 16 + fr;
      int kk = col >> 5, chunk = (col & 31) >> 3, e = col & 7;
#pragma unroll
      for (int r = 0; r < 4; ++r) {
        int row = wr * 64 + m * 16 + fs * 4 + r;
        U[kk * 4096 + row * 32 + 8 * (chunk ^ ((row >> 1) & 3)) + e] = f2bf(acc[m][n][r]);
      }
    }
  __syncthreads();   // P + rb2 ready

  // ---- PV: out[q][d] = sum_t P[q][t] * VT[d][t]; waves split rows (32 each) ----
  int nk = (S + 31) >> 5;
  int aoff2[2], boff2[4];
#pragma unroll
  for (int m = 0; m < 2; ++m) {
    int ra = wave * 32 + m * 16 + fr;
    aoff2[m] = ra * 32 + 8 * (fs ^ ((ra >> 1) & 3));
  }
#pragma unroll
  for (int n = 0; n < 4; ++n) {
    int rb = n * 16 + fr;
    boff2[n] = rb * 32 + 8 * (fs ^ ((rb >> 1) & 3));
  }
  f32x4 o2[2][4];
#pragma unroll
  for (int m = 0; m < 2; ++m)
#pragma unroll
    for (int n = 0; n < 4; ++n) o2[m][n] = (f32x4){0.f, 0.f, 0.f, 0.f};
  for (int kk = 0; kk < nk; ++kk) {
    bf8 pa[2], vb[4];
#pragma unroll
    for (int m = 0; m < 2; ++m) pa[m] = *(const bf8*)&U[kk * 4096 + aoff2[m]];
#pragma unroll
    for (int n = 0; n < 4; ++n) vb[n] = *(const bf8*)&VT[kk * 2048 + boff2[n]];
#pragma unroll
    for (int m = 0; m < 2; ++m)
#pragma unroll
      for (int n = 0; n < 4; ++n)
        o2[m][n] = __builtin_amdgcn_mfma_f32_16x16x32_bf16(pa[m], vb[n], o2[m][n], 0, 0, 0);
  }

  // ---- epilogue: divide by row sums, write ----
#pragma unroll
  for (int m = 0; m < 2; ++m)
#pragma unroll
    for (int r = 0; r < 4; ++r) {
      int orow = wave * 32 + m * 16 + fs * 4 + r;
      if (orow < S) {
        float inv = 1.0f / (rb2[0][orow] + rb2[1][orow]);
#pragma unroll
        for (int n = 0; n < 4; ++n)
          oh[(tok0 + orow) * N_ + h * 64 + n * 16 + fr] = f2bf(o2[m][n][r] * inv);
      }
    }
}

// ---------------- fused attention, 128<S<=512 — barrier-free waves ----------------
__global__ __launch_bounds__(256) void k_attn_big(
    const unsigned short* __restrict__ qh,
    const unsigned short* __restrict__ kh,
    const unsigned short* __restrict__ vh,
    unsigned short* __restrict__ oh,
    const int* __restrict__ meta, int iter) {
  int p = meta[3 + iter];
  if (p <= 128) return;
  int L = meta[6 + iter], nseq = meta[9 + iter];
  int M = B_ * nseq;
  int mh = blockIdx.x;
  int m = mh >> 3, h = mh & 7;
  if (m >= M) return;
  int S = p;
  int b = m / nseq, g2 = m % nseq;
  size_t tok0 = (size_t)b * L + (size_t)g2 * S;
  __shared__ unsigned short Ks[512 * 66];
  __shared__ unsigned short Vs[512 * 66];
  __shared__ float qrow[4][64];
  __shared__ float Pr[4][512];
  int tid = threadIdx.x;
  for (int i = tid; i < S * 64; i += 256) {
    int t = i >> 6, d = i & 63;
    size_t gi = (tok0 + t) * N_ + h * 64 + d;
    Ks[t * 66 + d] = kh[gi];
    Vs[t * 66 + d] = vh[gi];
  }
  __syncthreads();   // only barrier
  int wave = tid >> 6, lane = tid & 63;
  for (int s = wave; s < S; s += 4) {
    qrow[wave][lane] = bf2f(qh[(tok0 + s) * N_ + h * 64 + lane]);
    const float2* qp = (const float2*)&qrow[wave][0];
    float sc[8];
    float mx = -3.0e38f;
#pragma unroll
    for (int c2 = 0; c2 < 8; ++c2) {
      int t = lane + c2 * 64;
      float sv = -3.0e38f;
      if (t < S) {
        const unsigned int* kp = (const unsigned int*)&Ks[t * 66];
        float ad = 0.f;
#pragma unroll
        for (int j2 = 0; j2 < 32; ++j2) {
          float2 qq = qp[j2];
          unsigned int kw = kp[j2];
          ad += qq.x * bf2f((unsigned short)(kw & 0xffffu));
          ad += qq.y * bf2f((unsigned short)(kw >> 16));
        }
        sv = ad * 0.125f;
      }
      sc[c2] = sv;
      mx = fmaxf(mx, sv);
    }
    for (int off = 32; off > 0; off >>= 1) mx = fmaxf(mx, __shfl_xor(mx, off));
    float ssum = 0.f;
#pragma unroll
    for (int c2 = 0; c2 < 8; ++c2) {
      int t = lane + c2 * 64;
      float e = 0.f;
      if (t < S) { e = expf(sc[c2] - mx); Pr[wave][t] = e; }
      ssum += e;
    }
    for (int off = 32; off > 0; off >>= 1) ssum += __shfl_xor(ssum, off);
    float inv = 1.0f / ssum;
    float ov = 0.f;
#pragma unroll 8
    for (int t = 0; t < S; ++t) ov += Pr[wave][t] * bf2f(Vs[t * 66 + lane]);
    oh[(tok0 + s) * N_ + h * 64 + lane] = f2bf(ov * inv);
  }
}

// ---------------- final output ----------------
__global__ void k_final(const float* __restrict__ acc, const float* __restrict__ cur,
                        float* __restrict__ out) {
  size_t idx = (size_t)blockIdx.x * 256 + threadIdx.x;
  out[idx] = acc[idx] + cur[idx];
}

extern "C" void kernel_launch(void* const* d_in, const int* in_sizes, int n_in,
                              void* d_out, int out_size, void* d_ws, size_t ws_size,
                              hipStream_t stream) {
  (void)in_sizes; (void)n_in; (void)out_size; (void)ws_size;
  const float* x       = (const float*)d_in[0];
  const float* nv1     = (const float*)d_in[1];
  const float* nv2     = (const float*)d_in[2];
  const float* start_w = (const float*)d_in[3];
  const float* start_b = (const float*)d_in[4];
  const float* mix_w   = (const float*)d_in[5];
  const float* mix_b   = (const float*)d_in[6];
  const float* end_w   = (const float*)d_in[7];
  const float* end_b   = (const float*)d_in[8];
  const float* glin_w  = (const float*)d_in[9];
  const float* glin_b  = (const float*)d_in[10];
  const float* gnorm_g = (const float*)d_in[11];
  const float* gnorm_b = (const float*)d_in[12];
  const float* wq = (const float*)d_in[13];
  const float* bq = (const float*)d_in[14];
  const float* wk = (const float*)d_in[15];
  const float* bk = (const float*)d_in[16];
  const float* wv = (const float*)d_in[17];
  const float* bv = (const float*)d_in[18];
  const float* wo = (const float*)d_in[19];
  const float* bo = (const float*)d_in[20];
  const float* ff1w = (const float*)d_in[21];
  const float* ff1b = (const float*)d_in[22];
  const float* ff2w = (const float*)d_in[23];
  const float* ff2b = (const float*)d_in[24];
  const float* an1g = (const float*)d_in[25];
  const float* an1b = (const float*)d_in[26];
  const float* an2g = (const float*)d_in[27];
  const float* an2b = (const float*)d_in[28];
  const float* nrmg = (const float*)d_in[29];
  const float* nrmb = (const float*)d_in[30];

  char* ws = (char*)d_ws;
  int*   meta = (int*)(ws + OFF_META);
  float* freq = (float*)(ws + OFF_FREQ);
  float* swb  = (float*)(ws + OFF_SW);
  float* beff = (float*)(ws + OFF_BEFF);
  float* P12  = (float*)(ws + OFF_P12);
  float* fsumb = (float*)(ws + OFF_FSB);
  float* osm  = (float*)(ws + OFF_OSM);
  unsigned short* TWH = (unsigned short*)(ws + OFF_TWH);
  unsigned short* TWL = (unsigned short*)(ws + OFF_TWL);
  unsigned short* WB  = (unsigned short*)(ws + OFF_WB);
  unsigned short* WdH = (unsigned short*)(ws + OFF_WDH);
  unsigned short* EWH = (unsigned short*)(ws + OFF_EWH);
  float* cur  = (float*)(ws + OFF_CUR);
  float* accb = (float*)(ws + OFF_ACC);
  unsigned short* XWH = (unsigned short*)(ws + OFF_XWH);
  unsigned short* XWL = (unsigned short*)(ws + OFF_XWL);
  float* fpart = (float*)(ws + OFF_FP);
  float* Tm   = (float*)(ws + OFF_T);
  unsigned short* WPH = (unsigned short*)(ws + OFF_WPH);
  unsigned short* Gb  = (unsigned short*)(ws + OFF_G);
  unsigned short* G2b = (unsigned short*)(ws + OFF_G2);
  float* PART = (float*)(ws + OFF_PART);
  unsigned short* A0h = (unsigned short*)(ws + OFF_A0); unsigned short* A0l = A0h + PLW;
  unsigned short* A2h = (unsigned short*)(ws + OFF_A2); unsigned short* A2l = A2h + PLW;
  unsigned short* A3h = (unsigned short*)(ws + OFF_A3); unsigned short* A3l = A3h + PLW;
  unsigned short* A4h = (unsigned short*)(ws + OFF_A4);
  unsigned short* A5h = (unsigned short*)(ws + OFF_A5); unsigned short* A5l = A5h + PLW;

  hipMemsetAsync(accb, 0, (size_t)B_ * T_ * N_ * 4, stream);

  // ---- STFT via MFMA (window on twiddle side ONLY; x split exactly hi/lo) ----
  k_xw<<<B_ * NFR_, 256, 0, stream>>>(x, XWH, XWL);
  k_tw<<<(2 * 384 * 64 + 255) / 256, 256, 0, stream>>>(TWH, TWL);
  k_stftmm<<<dim3(3, NMT_), 256, 0, stream>>>(XWH, XWL, TWH, TWL, fpart);
  k_fred<<<NBIN_, 256, 0, stream>>>(fpart, freq, fsumb);
  k_topk<<<1, 64, 0, stream>>>(freq, fsumb, meta, swb);

  // split attention/FF weights into bf16 hi planes (once); Q,K,V contiguous
  const float* wlist[6] = {wq, wk, wv, wo, ff1w, ff2w};
  for (int w = 0; w < 6; ++w)
    k_splith<<<256, 256, 0, stream>>>(wlist[w], WB + (size_t)w * 262144, 262144);
  unsigned short* WqkvH = WB;              // [1536][512]
  unsigned short* WoH = WB + 3 * 262144;
  unsigned short* F1H = WB + 4 * 262144;
  unsigned short* F2H = WB + 5 * 262144;

  const float* curIn = x;
  for (int i = 0; i < 3; ++i) {
    // ---- graph block: fold conv+GCN+mix into one weight W' = T @ Wd ----
    k_adjprep<<<1, 1024, 0, stream>>>(nv1 + i * C_ * 10, nv2 + i * 10 * C_,
                                      mix_w + i * C_ * 96, mix_b + i * C_,
                                      start_b + i * C_, P12, beff);
    k_T<<<4096, 256, 0, stream>>>(P12, mix_w + i * C_ * 96, Tm);
    k_wdh<<<2048, 256, 0, stream>>>(start_w + i * C_ * KH_, WdH);
    k_mm2<<<dim3(4, 8, 8), 256, 0, stream>>>(Tm, WdH, nullptr, nullptr, PART,
                                             1024, 512, 1024, 1024, 0);
    k_redsplit<<<2048, 256, 0, stream>>>(PART, WPH);
    // G = gelu(curIn @ W'^T + b_eff)   [16384 x 1024] bf16
    k_mmcv<<<dim3(8, 128), 256, 0, stream>>>(curIn, WPH, beff, Gb, 16384, 1024, 512, 512);
    k_repackb<<<B_ * C_ * 16, 256, 0, stream>>>(Gb, G2b);
    k_splith<<<8192, 256, 0, stream>>>(end_w + (size_t)i * 8388608, EWH, 8388608);
    k_mmend<<<dim3(4, 8, 16), 256, 0, stream>>>(G2b, EWH, PART, 1024, 512, 16384);
    k_red16<<<2048, 256, 0, stream>>>(PART, end_b + i * T_, osm);
    k_lwln<<<B_ * T_, 256, 0, stream>>>(osm, glin_w + i * C_ * N_, glin_b + i * N_, curIn,
                                        gnorm_g + i * N_, gnorm_b + i * N_, cur,
                                        A0h, A0l, meta, i);
    k_padtail<<<512, 256, 0, stream>>>(A0h, A0l, meta, i);
    // ---- attention branch ----
    const int* Mdyn = meta + 15 + i;
    dim3 gT(4, TOKMAX / 128, 1);
    k_mmqkv<<<dim3(12, TOKMAX / 128), 256, 0, stream>>>(A0h, WqkvH, bq, bk, bv,
                                                        A2h, A3h, A4h, TOKMAX, 512, Mdyn);
    k_attn32<<<2048, 256, 0, stream>>>(A2h, A3h, A4h, A5h, meta, i);
    k_attn_small<<<4096, 256, 0, stream>>>(A2h, A3h, A4h, A5h, meta, i);
    k_attn_big<<<1024, 256, 0, stream>>>(A2h, A3h, A4h, A5h, meta, i);
    k_mmb1<<<gT, 256, 0, stream>>>(A5h, WoH, bo, A2h, A2l, TOKMAX, 512, 512, Mdyn, 0);
    k_lnadd<<<TOKMAX, 256, 0, stream>>>(A0h, A0l, A2h, A2l, an1g, an1b, A3h, A3l, meta, i);
    k_mmb1<<<gT, 256, 0, stream>>>(A3h, F1H, ff1b, A4h, nullptr, TOKMAX, 512, 512, Mdyn, 1);
    k_mmb1<<<gT, 256, 0, stream>>>(A4h, F2H, ff2b, A5h, A5l, TOKMAX, 512, 512, Mdyn, 0);
    k_lnfin<<<TOKMAX, 256, 0, stream>>>(A3h, A3l, A5h, A5l, an2g, an2b, nrmg, nrmb,
                                        swb, accb, meta, i);
    curIn = cur;
  }
  k_final<<<(B_ * T_ * N_) / 256, 256, 0, stream>>>(accb, curIn, (float*)d_out);
}

// Round 23
// 1890.502 us; speedup vs baseline: 1.0539x; 1.0539x over previous
//
#include <hip/hip_runtime.h>
#include <math.h>

#define DI __device__ __forceinline__

namespace {
constexpr int B_ = 32;
constexpr int T_ = 512;
constexpr int N_ = 512;   // d_model
constexpr int C_ = 32;    // c_out / conv_ch / skip_ch
constexpr int KH_ = 481;
constexpr int HOP_ = 48;
constexpr int WIN_ = 48;
constexpr int NFR_ = 11;
constexpr int NBIN_ = 257;
constexpr int NMT_ = B_ * NFR_ * 4;   // 1408 sample-tiles (44 per batch, contiguous)
constexpr int TOKMAX = 21760;   // 170*128 == exact max tokens (L=680)
constexpr int PLW = TOKMAX * 512;     // plane elements for token buffers
constexpr float EPS_ = 1e-5f;

constexpr size_t MBY = 1ull << 20;
constexpr size_t OFF_META = 0;
constexpr size_t OFF_FREQ = 4096;
constexpr size_t OFF_SW   = 8192;
constexpr size_t OFF_BEFF = 16384;       // 1024 floats
constexpr size_t OFF_P12  = 32768;       // 2048 floats
constexpr size_t OFF_FSB  = 65536;       // 257*32 floats (per-(k,b) sums)
constexpr size_t OFF_OSM  = 1 * MBY;     // 2MB (1..3MB)
constexpr size_t OFF_TWH  = 3 * MBY;         // twiddle hi planes [2][384][64] bf16
constexpr size_t OFF_TWL  = 3 * MBY + 131072;// twiddle lo planes
constexpr size_t OFF_WB   = 4 * MBY;     // 6 hi planes x 512KB = 3MB (Q,K,V contiguous!)
constexpr size_t OFF_WDH  = 10 * MBY;    // 1MB  (WdT hi plane [512][1024])
constexpr size_t OFF_EWH  = 12 * MBY;    // 16MB
constexpr size_t OFF_CUR  = 44 * MBY;    // 32MB
constexpr size_t OFF_ACC  = 76 * MBY;    // 32MB
constexpr size_t TR       = 108 * MBY;   // transient union region
// graph phase
constexpr size_t OFF_T    = TR;            // 4MB  T [1024][1024]
constexpr size_t OFF_WPH  = TR + 6 * MBY;  // 1MB  W' hi plane
constexpr size_t OFF_G    = TR + 64 * MBY; // 32MB bf16 [16384][1024]
constexpr size_t OFF_G2   = TR + 128 * MBY;// 32MB bf16 [1024][16384]
constexpr size_t OFF_PART = TR + 192 * MBY;// 32MB [16][1024][512]
// attention phase (aliases graph region): each buffer = hi plane + lo plane
constexpr size_t OFF_A0 = TR;              // 44MB stride each
constexpr size_t OFF_A2 = TR + 44 * MBY;
constexpr size_t OFF_A3 = TR + 88 * MBY;
constexpr size_t OFF_A4 = TR + 132 * MBY;
constexpr size_t OFF_A5 = TR + 176 * MBY;  // ends 328MB
// stft scratch aliases TR (stft completes before graph phase starts)
constexpr size_t OFF_XWH = TR;              // 23MB bf16 [180224][64] (x hi)
constexpr size_t OFF_FP  = TR + 48 * MBY;   // NBIN_*NMT_ floats ~1.45MB
} // namespace

typedef __attribute__((ext_vector_type(2))) float f32x2;
typedef __attribute__((ext_vector_type(4))) float f32x4;
typedef __attribute__((ext_vector_type(8))) short bf8;
typedef __attribute__((ext_vector_type(8))) unsigned short u16x8;

DI float gelu_exact(float x) { return 0.5f * x * (1.0f + erff(x * 0.7071067811865475f)); }
DI unsigned short f2bf(float f) {   // round-to-nearest-even
  unsigned u = __float_as_uint(f);
  u += 0x7FFFu + ((u >> 16) & 1u);
  return (unsigned short)(u >> 16);
}
DI float bf2f(unsigned short s) { return __uint_as_float(((unsigned)s) << 16); }
DI float ld2(const unsigned short* __restrict__ H, const unsigned short* __restrict__ L,
             size_t i) { return bf2f(H[i]) + bf2f(L[i]); }
DI void st2(unsigned short* __restrict__ H, unsigned short* __restrict__ L,
            size_t i, float v) {
  unsigned short h = f2bf(v);
  H[i] = h;
  L[i] = f2bf(v - bf2f(h));
}
DI void gll16(const unsigned short* g, unsigned short* l) {
  __builtin_amdgcn_global_load_lds(
      (const __attribute__((address_space(1))) void*)g,
      (__attribute__((address_space(3))) void*)l, 16, 0, 0);
}

// ---------------- build x-hi frames: XW [180224][64] (NO window here) ----------------
__global__ __launch_bounds__(256) void k_xw(const float* __restrict__ x,
                                            unsigned short* __restrict__ XWH) {
  int bf = blockIdx.x;            // b*NFR + f
  int f = bf % NFR_, b = bf / NFR_;
  int tid = threadIdx.x;
  for (int i = tid; i < 512 * 8; i += 256) {
    int n = i >> 3, jc = i & 7;
    size_t m = (size_t)bf * 512 + n;
    u16x8 vh;
#pragma unroll
    for (int q = 0; q < 8; ++q) {
      int j = jc * 8 + q;
      if (j < WIN_) {
        int gi = f * HOP_ + 232 + j - 256;
        if (gi < 0) gi = -gi;   // reflect pad (left only)
        vh[q] = f2bf(x[((size_t)b * T_ + gi) * N_ + n]);
      } else vh[q] = 0;
    }
    *(u16x8*)&XWH[m * 64 + jc * 8] = vh;
  }
}

// ---------------- build twiddle hi/lo planes [2][384][64] (window baked in HERE) ----------------
__global__ void k_tw(unsigned short* __restrict__ TWH, unsigned short* __restrict__ TWL) {
  int idx = blockIdx.x * 256 + threadIdx.x;   // 2*384*64 = 49152
  if (idx >= 2 * 384 * 64) return;
  int pl = idx / (384 * 64);
  int rem = idx % (384 * 64);
  int k = rem >> 6, j = rem & 63;
  float v = 0.f;
  if (k < NBIN_ && j < WIN_) {
    int r = (k * (232 + j)) & 511;
    float ang = (float)r * 0.012271846303085130f;   // 2pi/512
    float w = 0.5f - 0.5f * cosf((float)j * 0.13089969389957472f);
    v = pl == 0 ? w * cosf(ang) : w * sinf(ang);
  }
  unsigned short h = f2bf(v);
  TWH[idx] = h;
  TWL[idx] = f2bf(v - bf2f(h));
}

// ---------------- MFMA STFT: mags summed per (k, sample-tile) ----------------
// A = x-hi [180224][64]; B = windowed twiddles (re/im, hi+lo). 128x128 tile.
__global__ __launch_bounds__(256, 3) void k_stftmm(
    const unsigned short* __restrict__ XWH,
    const unsigned short* __restrict__ TWH, const unsigned short* __restrict__ TWL,
    float* __restrict__ fpart) {
  const int bn = blockIdx.x * 128;     // k-tile base (0,128,256)
  const int mtile = blockIdx.y;
  const int bm = mtile * 128;

  __shared__ __align__(16) unsigned short AHS[4096], RHS[4096], RLS[4096],
                                          IHS[4096], ILS[4096];
  __shared__ float colpart[2][128];

  const int tid = threadIdx.x;
  const int wave = tid >> 6, lane = tid & 63;
  const int wr = wave >> 1, wc = wave & 1;
  const int fr = lane & 15, fs = lane >> 4;

  const int row0 = tid >> 2;
  const int s0 = (tid & 3) ^ ((row0 >> 1) & 3);
  const unsigned short* gAH0 = XWH + (size_t)(bm + row0) * 64 + s0 * 8;
  const unsigned short* gAH1 = gAH0 + (size_t)64 * 64;
  const unsigned short* gRH0 = TWH + (size_t)(bn + row0) * 64 + s0 * 8;
  const unsigned short* gRH1 = gRH0 + (size_t)64 * 64;
  const unsigned short* gRL0 = TWL + (size_t)(bn + row0) * 64 + s0 * 8;
  const unsigned short* gRL1 = gRL0 + (size_t)64 * 64;
  const unsigned short* gIH0 = gRH0 + (size_t)384 * 64;
  const unsigned short* gIH1 = gRH1 + (size_t)384 * 64;
  const unsigned short* gIL0 = gRL0 + (size_t)384 * 64;
  const unsigned short* gIL1 = gRL1 + (size_t)384 * 64;
  const int lb0 = wave * 512, lb1 = 2048 + wave * 512;

  int aoff[4], boff[4];
#pragma unroll
  for (int m = 0; m < 4; ++m) {
    int ra = wr * 64 + m * 16 + fr;
    aoff[m] = ra * 32 + 8 * (fs ^ ((ra >> 1) & 3));
    int rb = wc * 64 + m * 16 + fr;
    boff[m] = rb * 32 + 8 * (fs ^ ((rb >> 1) & 3));
  }

  f32x4 are[4][4], aim[4][4];
#pragma unroll
  for (int m = 0; m < 4; ++m)
#pragma unroll
    for (int n = 0; n < 4; ++n) {
      are[m][n] = (f32x4){0.f, 0.f, 0.f, 0.f};
      aim[m][n] = (f32x4){0.f, 0.f, 0.f, 0.f};
    }

  for (int k0 = 0; k0 < 64; k0 += 32) {
    __syncthreads();
    gll16(gAH0 + k0, &AHS[lb0]); gll16(gAH1 + k0, &AHS[lb1]);
    gll16(gRH0 + k0, &RHS[lb0]); gll16(gRH1 + k0, &RHS[lb1]);
    gll16(gRL0 + k0, &RLS[lb0]); gll16(gRL1 + k0, &RLS[lb1]);
    gll16(gIH0 + k0, &IHS[lb0]); gll16(gIH1 + k0, &IHS[lb1]);
    gll16(gIL0 + k0, &ILS[lb0]); gll16(gIL1 + k0, &ILS[lb1]);
    __syncthreads();
    bf8 ah[4], rh[4], rl[4], ih[4], il[4];
#pragma unroll
    for (int m = 0; m < 4; ++m) ah[m] = *(const bf8*)&AHS[aoff[m]];
#pragma unroll
    for (int n = 0; n < 4; ++n) {
      rh[n] = *(const bf8*)&RHS[boff[n]];
      rl[n] = *(const bf8*)&RLS[boff[n]];
      ih[n] = *(const bf8*)&IHS[boff[n]];
      il[n] = *(const bf8*)&ILS[boff[n]];
    }
#pragma unroll
    for (int m = 0; m < 4; ++m)
#pragma unroll
      for (int n = 0; n < 4; ++n) {
        are[m][n] = __builtin_amdgcn_mfma_f32_16x16x32_bf16(ah[m], rh[n], are[m][n], 0, 0, 0);
        are[m][n] = __builtin_amdgcn_mfma_f32_16x16x32_bf16(ah[m], rl[n], are[m][n], 0, 0, 0);
        aim[m][n] = __builtin_amdgcn_mfma_f32_16x16x32_bf16(ah[m], ih[n], aim[m][n], 0, 0, 0);
        aim[m][n] = __builtin_amdgcn_mfma_f32_16x16x32_bf16(ah[m], il[n], aim[m][n], 0, 0, 0);
      }
  }

  float s[4];
#pragma unroll
  for (int n = 0; n < 4; ++n) {
    float acc = 0.f;
#pragma unroll
    for (int m = 0; m < 4; ++m)
#pragma unroll
      for (int r = 0; r < 4; ++r) {
        float re = are[m][n][r], im = aim[m][n][r];
        acc += __builtin_amdgcn_sqrtf(re * re + im * im);
      }
    acc += __shfl_xor(acc, 16);
    acc += __shfl_xor(acc, 32);
    s[n] = acc;
  }
  if (fs == 0) {
#pragma unroll
    for (int n = 0; n < 4; ++n) colpart[wr][wc * 64 + n * 16 + fr] = s[n];
  }
  __syncthreads();
  if (tid < 128) {
    int k = bn + tid;
    if (k < NBIN_) fpart[(size_t)k * NMT_ + mtile] = colpart[0][tid] + colpart[1][tid];
  }
}

// ---------------- reduce -> freq (all-b) and fsumb (per-b) ----------------
__global__ __launch_bounds__(256) void k_fred(const float* __restrict__ fpart,
                                              float* __restrict__ freq,
                                              float* __restrict__ fsumb) {
  int k = blockIdx.x;
  int tid = threadIdx.x;
  int b = tid >> 3, j = tid & 7;   // 8 lanes per batch, 44 values each batch
  float s = 0.f;
  for (int i = j; i < 44; i += 8) s += fpart[(size_t)k * NMT_ + b * 44 + i];
  for (int off = 4; off > 0; off >>= 1) s += __shfl_xor(s, off);
  __shared__ float bs[32];
  if (j == 0) bs[b] = s;
  __syncthreads();
  if (tid < 32) {
    float v = bs[tid];
    fsumb[k * 32 + tid] = v;
    for (int off = 16; off > 0; off >>= 1) v += __shfl_xor(v, off);
    if (tid == 0) freq[k] = v;
  }
}

// ---------------- top-k + meta + sw softmax (fused) ----------------
__global__ void k_topk(const float* __restrict__ freq, const float* __restrict__ fsumb,
                       int* __restrict__ meta, float* __restrict__ swb) {
  __shared__ int stop[3];
  int tid = threadIdx.x;
  if (tid == 0) {
    float bv[3] = {-1e30f, -1e30f, -1e30f};
    int bi[3] = {1, 1, 1};
    for (int k = 1; k < NBIN_; ++k) {
      float v = freq[k];
      if (v > bv[0]) { bv[2]=bv[1]; bi[2]=bi[1]; bv[1]=bv[0]; bi[1]=bi[0]; bv[0]=v; bi[0]=k; }
      else if (v > bv[1]) { bv[2]=bv[1]; bi[2]=bi[1]; bv[1]=v; bi[1]=k; }
      else if (v > bv[2]) { bv[2]=v; bi[2]=k; }
    }
    for (int i = 0; i < 3; ++i) {
      int top = bi[i];
      int p = T_ / top;
      int L = ((T_ + p - 1) / p) * p;
      meta[i] = top;
      meta[3 + i] = p;
      meta[6 + i] = L;
      meta[9 + i] = L / p;
      meta[15 + i] = B_ * L;   // tokens
      stop[i] = top;
    }
  }
  __syncthreads();
  int b = tid;
  if (b < B_) {
    float inv = 1.0f / (float)(NFR_ * N_);
    float m0 = fsumb[stop[0] * 32 + b] * inv;
    float m1 = fsumb[stop[1] * 32 + b] * inv;
    float m2 = fsumb[stop[2] * 32 + b] * inv;
    float mx = fmaxf(m0, fmaxf(m1, m2));
    float e0 = __expf(m0 - mx), e1 = __expf(m1 - mx), e2 = __expf(m2 - mx);
    float s = e0 + e1 + e2;
    swb[b * 4 + 0] = e0 / s; swb[b * 4 + 1] = e1 / s; swb[b * 4 + 2] = e2 / s;
  }
}

// ---------------- fused adjacency + GCN operator prep ----------------
__global__ __launch_bounds__(1024) void k_adjprep(const float* __restrict__ nv1,
                                                  const float* __restrict__ nv2,
                                                  const float* __restrict__ mw,
                                                  const float* __restrict__ mb,
                                                  const float* __restrict__ sb,
                                                  float* __restrict__ P12,
                                                  float* __restrict__ beff) {
  __shared__ float A32s[32][32];
  __shared__ float Ms[32][32], P1s[32][32], P2s[32][32], S1[32], S2[32], sbl[32];
  int tid = threadIdx.x;
  if (tid < 32) {
    int v = tid;
    float row[32];
    for (int w = 0; w < 32; ++w) {
      float s = 0.f;
      for (int d = 0; d < 10; ++d) s += nv1[v * 10 + d] * nv2[d * 32 + w];
      row[w] = fmaxf(s, 0.f);
    }
    float mx = -1e30f;
    for (int w = 0; w < 32; ++w) mx = fmaxf(mx, row[w]);
    float sm = 0.f;
    for (int w = 0; w < 32; ++w) { row[w] = expf(row[w] - mx); sm += row[w]; }
    for (int w = 0; w < 32; ++w) row[w] /= sm;
    row[v] += 1.0f;
    float rs = 0.f;
    for (int w = 0; w < 32; ++w) rs += row[w];
    for (int w = 0; w < 32; ++w) A32s[v][w] = row[w] / rs;
    sbl[tid] = sb[tid];
  }
  __syncthreads();
  int w = tid >> 5, v = tid & 31;
  Ms[w][v] = A32s[v][w];
  __syncthreads();
  float p1 = 0.95f * Ms[w][v] + (w == v ? 0.05f : 0.f);
  P1s[w][v] = p1;
  __syncthreads();
  float p2 = 0.f;
  for (int u = 0; u < 32; ++u) p2 += P1s[w][u] * Ms[u][v];
  p2 = 0.95f * p2 + (w == v ? 0.05f : 0.f);
  P2s[w][v] = p2;
  P12[tid] = p1;
  P12[1024 + tid] = p2;
  __syncthreads();
  if (tid < 32) {
    float s1 = 0.f, s2 = 0.f;
    for (int u = 0; u < 32; ++u) { s1 += P1s[u][tid]; s2 += P2s[u][tid]; }
    S1[tid] = s1; S2[tid] = s2;
  }
  __syncthreads();
  int o = w;
  float be = mb[o];
  for (int c = 0; c < 32; ++c) {
    float sc = sbl[c];
    be += mw[o * 96 + c] * sc;
    be += mw[o * 96 + 32 + c] * sc * S1[v];
    be += mw[o * 96 + 64 + c] * sc * S2[v];
  }
  beff[tid] = be;
}

// ---------------- build T [1024][1024]: T[(o,v)][(c,w)] ----------------
__global__ __launch_bounds__(256) void k_T(const float* __restrict__ P12,
                                           const float* __restrict__ mw,
                                           float* __restrict__ Tm) {
  int idx = blockIdx.x * 256 + threadIdx.x;
  int r = idx >> 10, k2 = idx & 1023;
  int o = r >> 5, v = r & 31;
  int c = k2 >> 5, w = k2 & 31;
  float t = mw[o * 96 + 32 + c] * P12[w * 32 + v]
          + mw[o * 96 + 64 + c] * P12[1024 + w * 32 + v];
  if (w == v) t += mw[o * 96 + c];
  Tm[idx] = t;
}

// ---------------- build WdT hi: WdT[j][(c,w)] = sw[c][j-w] ----------------
__global__ void k_wdh(const float* __restrict__ swi, unsigned short* __restrict__ WH) {
  int idx = blockIdx.x * 256 + threadIdx.x;   // 512*1024
  int j = idx >> 10, k2 = idx & 1023;
  int c = k2 >> 5, w = k2 & 31;
  int kk = j - w;
  float vv = (kk >= 0 && kk < KH_) ? swi[c * KH_ + kk] : 0.f;
  WH[idx] = f2bf(vv);
}

// ---------------- weight hi split ----------------
__global__ void k_splith(const float* __restrict__ src, unsigned short* __restrict__ Hi,
                         int n) {
  int i = blockIdx.x * 256 + threadIdx.x;
  if (i * 4 >= n) return;
  float4 v = *(const float4*)&src[i * 4];
  ushort4 h;
  h.x = f2bf(v.x); h.y = f2bf(v.y); h.z = f2bf(v.z); h.w = f2bf(v.w);
  *(ushort4*)&Hi[i * 4] = h;
}

// ---------------- 2-MFMA GEMM (fp32 A hi/lo; bf16 weight hi; fold GEMM only) ----------------
__global__ __launch_bounds__(256, 2) void k_mm2(
    const float* __restrict__ A, const unsigned short* __restrict__ Bh,
    const float* __restrict__ bias,
    float* __restrict__ C, float* __restrict__ Cpart,
    int M, int N, int K, int lda, int dogelu) {
  const int bm = blockIdx.y * 128;
  if (bm >= M) return;
  const int bn = blockIdx.x * 128;
  const int nz = gridDim.z, z = blockIdx.z;
  const int kpb = K / nz;
  const int kbeg = z * kpb, kend = kbeg + kpb;

  __shared__ __align__(16) unsigned short AhS[4096], AlS[4096], BhS[4096];

  const int tid = threadIdx.x;
  const int wave = tid >> 6, lane = tid & 63;
  const int wr = wave >> 1, wc = wave & 1;
  const int fr = lane & 15, fs = lane >> 4;

  const int sr = tid >> 1, ss = (tid & 1) * 2;
  const int sx = (sr >> 1) & 3;
  const int so0 = sr * 32 + 8 * (ss ^ sx);
  const int so1 = sr * 32 + 8 * ((ss + 1) ^ sx);

  const int row0 = tid >> 2;
  const int s0 = (tid & 3) ^ ((row0 >> 1) & 3);
  const unsigned short* gBh0 = Bh + (size_t)(bn + row0) * K + s0 * 8;
  const unsigned short* gBh1 = gBh0 + (size_t)64 * K;
  unsigned short* lB0 = &BhS[wave * 512];
  unsigned short* lB1 = &BhS[2048 + wave * 512];

  int aoff[4], boff[4];
#pragma unroll
  for (int m = 0; m < 4; ++m) {
    int ra = wr * 64 + m * 16 + fr;
    aoff[m] = ra * 32 + 8 * (fs ^ ((ra >> 1) & 3));
    int rb = wc * 64 + m * 16 + fr;
    boff[m] = rb * 32 + 8 * (fs ^ ((rb >> 1) & 3));
  }

  const bool aok = (bm + sr) < M;
  const float* Arow = A + (size_t)(bm + sr) * lda + ss * 8;

  f32x4 acc[4][4];
#pragma unroll
  for (int m = 0; m < 4; ++m)
#pragma unroll
    for (int n = 0; n < 4; ++n) acc[m][n] = (f32x4){0.f, 0.f, 0.f, 0.f};

  for (int k0 = kbeg; k0 < kend; k0 += 32) {
    float4 a0, a1, a2, a3;
    if (aok) {
      const float4* p = (const float4*)(Arow + k0);
      a0 = p[0]; a1 = p[1]; a2 = p[2]; a3 = p[3];
    } else {
      a0 = a1 = a2 = a3 = make_float4(0.f, 0.f, 0.f, 0.f);
    }
    float av[16];
    av[0]=a0.x; av[1]=a0.y; av[2]=a0.z; av[3]=a0.w;
    av[4]=a1.x; av[5]=a1.y; av[6]=a1.z; av[7]=a1.w;
    av[8]=a2.x; av[9]=a2.y; av[10]=a2.z; av[11]=a2.w;
    av[12]=a3.x; av[13]=a3.y; av[14]=a3.z; av[15]=a3.w;
    u16x8 h0, h1, l0, l1;
#pragma unroll
    for (int j = 0; j < 8; ++j) {
      unsigned u = __float_as_uint(av[j]);
      h0[j] = (unsigned short)(u >> 16);
      float r2 = av[j] - __uint_as_float(u & 0xffff0000u);
      l0[j] = (unsigned short)(__float_as_uint(r2) >> 16);
      unsigned u2 = __float_as_uint(av[j + 8]);
      h1[j] = (unsigned short)(u2 >> 16);
      float r3 = av[j + 8] - __uint_as_float(u2 & 0xffff0000u);
      l1[j] = (unsigned short)(__float_as_uint(r3) >> 16);
    }
    __syncthreads();   // prior frag reads done
    gll16(gBh0 + k0, lB0); gll16(gBh1 + k0, lB1);
    *(u16x8*)&AhS[so0] = h0; *(u16x8*)&AhS[so1] = h1;
    *(u16x8*)&AlS[so0] = l0; *(u16x8*)&AlS[so1] = l1;
    __syncthreads();   // drains vmcnt + lgkm
    bf8 ah[4], al4[4], bh4[4];
#pragma unroll
    for (int m = 0; m < 4; ++m) {
      ah[m]  = *(const bf8*)&AhS[aoff[m]];
      al4[m] = *(const bf8*)&AlS[aoff[m]];
    }
#pragma unroll
    for (int n = 0; n < 4; ++n) bh4[n] = *(const bf8*)&BhS[boff[n]];
#pragma unroll
    for (int m = 0; m < 4; ++m)
#pragma unroll
      for (int n = 0; n < 4; ++n) {
        acc[m][n] = __builtin_amdgcn_mfma_f32_16x16x32_bf16(ah[m],  bh4[n], acc[m][n], 0, 0, 0);
        acc[m][n] = __builtin_amdgcn_mfma_f32_16x16x32_bf16(al4[m], bh4[n], acc[m][n], 0, 0, 0);
      }
  }

  if (nz > 1) {
    float* P = Cpart + (size_t)z * M * N;
#pragma unroll
    for (int m = 0; m < 4; ++m)
#pragma unroll
      for (int r = 0; r < 4; ++r) {
        int row = bm + wr * 64 + m * 16 + fs * 4 + r;
        if (row < M) {
#pragma unroll
          for (int n = 0; n < 4; ++n) {
            int col = bn + wc * 64 + n * 16 + fr;
            P[(size_t)row * N + col] = acc[m][n][r];
          }
        }
      }
  } else {
    float bcol[4];
#pragma unroll
    for (int n = 0; n < 4; ++n) bcol[n] = bias ? bias[bn + wc * 64 + n * 16 + fr] : 0.f;
#pragma unroll
    for (int m = 0; m < 4; ++m)
#pragma unroll
      for (int r = 0; r < 4; ++r) {
        int row = bm + wr * 64 + m * 16 + fs * 4 + r;
        if (row < M) {
#pragma unroll
          for (int n = 0; n < 4; ++n) {
            int col = bn + wc * 64 + n * 16 + fr;
            float v = acc[m][n][r] + bcol[n];
            if (dogelu) v = gelu_exact(v);
            C[(size_t)row * N + col] = v;
          }
        }
      }
  }
}

// ---------------- conv GEMM: fp32 A hi-only, 1 MFMA, bf16 output + gelu ----------------
__global__ __launch_bounds__(256, 4) void k_mmcv(
    const float* __restrict__ A, const unsigned short* __restrict__ Bh,
    const float* __restrict__ bias,
    unsigned short* __restrict__ C,
    int M, int N, int K, int lda) {
  const int bm = blockIdx.y * 128;
  const int bn = blockIdx.x * 128;

  __shared__ __align__(16) unsigned short AhS[4096], BhS[4096];

  const int tid = threadIdx.x;
  const int wave = tid >> 6, lane = tid & 63;
  const int wr = wave >> 1, wc = wave & 1;
  const int fr = lane & 15, fs = lane >> 4;

  const int sr = tid >> 1, ss = (tid & 1) * 2;
  const int sx = (sr >> 1) & 3;
  const int so0 = sr * 32 + 8 * (ss ^ sx);
  const int so1 = sr * 32 + 8 * ((ss + 1) ^ sx);

  const int row0 = tid >> 2;
  const int s0 = (tid & 3) ^ ((row0 >> 1) & 3);
  const unsigned short* gBh0 = Bh + (size_t)(bn + row0) * K + s0 * 8;
  const unsigned short* gBh1 = gBh0 + (size_t)64 * K;
  unsigned short* lB0 = &BhS[wave * 512];
  unsigned short* lB1 = &BhS[2048 + wave * 512];

  int aoff[4], boff[4];
#pragma unroll
  for (int m = 0; m < 4; ++m) {
    int ra = wr * 64 + m * 16 + fr;
    aoff[m] = ra * 32 + 8 * (fs ^ ((ra >> 1) & 3));
    int rb = wc * 64 + m * 16 + fr;
    boff[m] = rb * 32 + 8 * (fs ^ ((rb >> 1) & 3));
  }

  const float* Arow = A + (size_t)(bm + sr) * lda + ss * 8;

  f32x4 acc[4][4];
#pragma unroll
  for (int m = 0; m < 4; ++m)
#pragma unroll
    for (int n = 0; n < 4; ++n) acc[m][n] = (f32x4){0.f, 0.f, 0.f, 0.f};

  for (int k0 = 0; k0 < K; k0 += 32) {
    const float4* p = (const float4*)(Arow + k0);
    float4 a0 = p[0], a1 = p[1], a2 = p[2], a3 = p[3];
    u16x8 h0, h1;
    h0[0]=f2bf(a0.x); h0[1]=f2bf(a0.y); h0[2]=f2bf(a0.z); h0[3]=f2bf(a0.w);
    h0[4]=f2bf(a1.x); h0[5]=f2bf(a1.y); h0[6]=f2bf(a1.z); h0[7]=f2bf(a1.w);
    h1[0]=f2bf(a2.x); h1[1]=f2bf(a2.y); h1[2]=f2bf(a2.z); h1[3]=f2bf(a2.w);
    h1[4]=f2bf(a3.x); h1[5]=f2bf(a3.y); h1[6]=f2bf(a3.z); h1[7]=f2bf(a3.w);
    __syncthreads();   // prior frag reads done
    gll16(gBh0 + k0, lB0); gll16(gBh1 + k0, lB1);
    *(u16x8*)&AhS[so0] = h0; *(u16x8*)&AhS[so1] = h1;
    __syncthreads();   // drains vmcnt + lgkm
    bf8 ah[4], bh4[4];
#pragma unroll
    for (int m = 0; m < 4; ++m) ah[m] = *(const bf8*)&AhS[aoff[m]];
#pragma unroll
    for (int n = 0; n < 4; ++n) bh4[n] = *(const bf8*)&BhS[boff[n]];
#pragma unroll
    for (int m = 0; m < 4; ++m)
#pragma unroll
      for (int n = 0; n < 4; ++n)
        acc[m][n] = __builtin_amdgcn_mfma_f32_16x16x32_bf16(ah[m], bh4[n], acc[m][n], 0, 0, 0);
  }

  float bcol[4];
#pragma unroll
  for (int n = 0; n < 4; ++n) bcol[n] = bias[bn + wc * 64 + n * 16 + fr];
#pragma unroll
  for (int m = 0; m < 4; ++m)
#pragma unroll
    for (int r = 0; r < 4; ++r) {
      int row = bm + wr * 64 + m * 16 + fs * 4 + r;
#pragma unroll
      for (int n = 0; n < 4; ++n) {
        int col = bn + wc * 64 + n * 16 + fr;
        C[(size_t)row * N + col] = f2bf(gelu_exact(acc[m][n][r] + bcol[n]));
      }
    }
}

// ---------------- end GEMM: bf16 A, bf16 B, 1 MFMA, split-K partials ----------------
__global__ __launch_bounds__(256, 4) void k_mmend(
    const unsigned short* __restrict__ Ah, const unsigned short* __restrict__ Bh,
    float* __restrict__ Cpart, int M, int N, int K) {
  const int bm = blockIdx.y * 128;
  const int bn = blockIdx.x * 128;
  const int nz = gridDim.z, z = blockIdx.z;
  const int kpb = K / nz;
  const int kbeg = z * kpb, kend = kbeg + kpb;

  __shared__ __align__(16) unsigned short AhS[4096], BhS[4096];

  const int tid = threadIdx.x;
  const int wave = tid >> 6, lane = tid & 63;
  const int wr = wave >> 1, wc = wave & 1;
  const int fr = lane & 15, fs = lane >> 4;

  const int row0 = tid >> 2;
  const int s0 = (tid & 3) ^ ((row0 >> 1) & 3);
  const unsigned short* gAh0 = Ah + (size_t)(bm + row0) * K + s0 * 8;
  const unsigned short* gAh1 = gAh0 + (size_t)64 * K;
  const unsigned short* gBh0 = Bh + (size_t)(bn + row0) * K + s0 * 8;
  const unsigned short* gBh1 = gBh0 + (size_t)64 * K;
  const int lb0 = wave * 512, lb1 = 2048 + wave * 512;

  int aoff[4], boff[4];
#pragma unroll
  for (int m = 0; m < 4; ++m) {
    int ra = wr * 64 + m * 16 + fr;
    aoff[m] = ra * 32 + 8 * (fs ^ ((ra >> 1) & 3));
    int rb = wc * 64 + m * 16 + fr;
    boff[m] = rb * 32 + 8 * (fs ^ ((rb >> 1) & 3));
  }

  f32x4 acc[4][4];
#pragma unroll
  for (int m = 0; m < 4; ++m)
#pragma unroll
    for (int n = 0; n < 4; ++n) acc[m][n] = (f32x4){0.f, 0.f, 0.f, 0.f};

  for (int k0 = kbeg; k0 < kend; k0 += 32) {
    __syncthreads();
    gll16(gAh0 + k0, &AhS[lb0]); gll16(gAh1 + k0, &AhS[lb1]);
    gll16(gBh0 + k0, &BhS[lb0]); gll16(gBh1 + k0, &BhS[lb1]);
    __syncthreads();
    bf8 ah[4], bh4[4];
#pragma unroll
    for (int m = 0; m < 4; ++m) ah[m] = *(const bf8*)&AhS[aoff[m]];
#pragma unroll
    for (int n = 0; n < 4; ++n) bh4[n] = *(const bf8*)&BhS[boff[n]];
#pragma unroll
    for (int m = 0; m < 4; ++m)
#pragma unroll
      for (int n = 0; n < 4; ++n)
        acc[m][n] = __builtin_amdgcn_mfma_f32_16x16x32_bf16(ah[m], bh4[n], acc[m][n], 0, 0, 0);
  }

  float* P = Cpart + (size_t)z * M * N;
#pragma unroll
  for (int m = 0; m < 4; ++m)
#pragma unroll
    for (int r = 0; r < 4; ++r) {
      int row = bm + wr * 64 + m * 16 + fs * 4 + r;
#pragma unroll
      for (int n = 0; n < 4; ++n) {
        int col = bn + wc * 64 + n * 16 + fr;
        P[(size_t)row * N + col] = acc[m][n][r];
      }
    }
}

// ---------------- 1-MFMA plane GEMM (attention pipeline; optional lo write) ----------------
__global__ __launch_bounds__(256, 4) void k_mmb1(
    const unsigned short* __restrict__ Ah,
    const unsigned short* __restrict__ Bh,
    const float* __restrict__ bias,
    unsigned short* __restrict__ Ch, unsigned short* __restrict__ Cl,
    int M, int N, int K, const int* __restrict__ Mdyn, int dogelu) {
  if (Mdyn) M = *Mdyn;
  const int bm = blockIdx.y * 128;
  if (bm >= M) return;
  const int bn = blockIdx.x * 128;

  __shared__ __align__(16) unsigned short AhS[4096], BhS[4096];

  const int tid = threadIdx.x;
  const int wave = tid >> 6, lane = tid & 63;
  const int wr = wave >> 1, wc = wave & 1;
  const int fr = lane & 15, fs = lane >> 4;

  const int row0 = tid >> 2;
  const int s0 = (tid & 3) ^ ((row0 >> 1) & 3);
  const unsigned short* gAh0 = Ah + (size_t)(bm + row0) * K + s0 * 8;
  const unsigned short* gAh1 = gAh0 + (size_t)64 * K;
  const unsigned short* gBh0 = Bh + (size_t)(bn + row0) * K + s0 * 8;
  const unsigned short* gBh1 = gBh0 + (size_t)64 * K;
  const int lb0 = wave * 512, lb1 = 2048 + wave * 512;

  int aoff[4], boff[4];
#pragma unroll
  for (int m = 0; m < 4; ++m) {
    int ra = wr * 64 + m * 16 + fr;
    aoff[m] = ra * 32 + 8 * (fs ^ ((ra >> 1) & 3));
    int rb = wc * 64 + m * 16 + fr;
    boff[m] = rb * 32 + 8 * (fs ^ ((rb >> 1) & 3));
  }

  f32x4 acc[4][4];
#pragma unroll
  for (int m = 0; m < 4; ++m)
#pragma unroll
    for (int n = 0; n < 4; ++n) acc[m][n] = (f32x4){0.f, 0.f, 0.f, 0.f};

  for (int k0 = 0; k0 < K; k0 += 32) {
    __syncthreads();
    gll16(gAh0 + k0, &AhS[lb0]); gll16(gAh1 + k0, &AhS[lb1]);
    gll16(gBh0 + k0, &BhS[lb0]); gll16(gBh1 + k0, &BhS[lb1]);
    __syncthreads();
    bf8 ah[4], bh4[4];
#pragma unroll
    for (int m = 0; m < 4; ++m) ah[m] = *(const bf8*)&AhS[aoff[m]];
#pragma unroll
    for (int n = 0; n < 4; ++n) bh4[n] = *(const bf8*)&BhS[boff[n]];
#pragma unroll
    for (int m = 0; m < 4; ++m)
#pragma unroll
      for (int n = 0; n < 4; ++n)
        acc[m][n] = __builtin_amdgcn_mfma_f32_16x16x32_bf16(ah[m], bh4[n], acc[m][n], 0, 0, 0);
  }

  float bcol[4];
#pragma unroll
  for (int n = 0; n < 4; ++n) bcol[n] = bias[bn + wc * 64 + n * 16 + fr];
#pragma unroll
  for (int m = 0; m < 4; ++m)
#pragma unroll
    for (int r = 0; r < 4; ++r) {
      int row = bm + wr * 64 + m * 16 + fs * 4 + r;
      if (row < M) {
#pragma unroll
        for (int n = 0; n < 4; ++n) {
          int col = bn + wc * 64 + n * 16 + fr;
          float v = acc[m][n][r] + bcol[n];
          if (dogelu) v = gelu_exact(v);
          size_t o = (size_t)row * N + col;
          unsigned short h = f2bf(v);
          Ch[o] = h;
          if (Cl) Cl[o] = f2bf(v - bf2f(h));
        }
      }
    }
}

// ---------------- fused QKV GEMM: B=[1536][512] hi; dest selected per n-tile ----------------
__global__ __launch_bounds__(256, 4) void k_mmqkv(
    const unsigned short* __restrict__ Ah,
    const unsigned short* __restrict__ Bh,
    const float* __restrict__ bq, const float* __restrict__ bk,
    const float* __restrict__ bv,
    unsigned short* __restrict__ Qh, unsigned short* __restrict__ Kh,
    unsigned short* __restrict__ Vh,
    int M, int K, const int* __restrict__ Mdyn) {
  if (Mdyn) M = *Mdyn;
  const int bm = blockIdx.y * 128;
  if (bm >= M) return;
  const int bn = blockIdx.x * 128;   // in [0,1536)
  const int sel = bn >> 9;
  unsigned short* Ch = sel == 0 ? Qh : (sel == 1 ? Kh : Vh);
  const float* bias = sel == 0 ? bq : (sel == 1 ? bk : bv);
  const int cb = bn & 511;

  __shared__ __align__(16) unsigned short AhS[4096], BhS[4096];

  const int tid = threadIdx.x;
  const int wave = tid >> 6, lane = tid & 63;
  const int wr = wave >> 1, wc = wave & 1;
  const int fr = lane & 15, fs = lane >> 4;

  const int row0 = tid >> 2;
  const int s0 = (tid & 3) ^ ((row0 >> 1) & 3);
  const unsigned short* gAh0 = Ah + (size_t)(bm + row0) * K + s0 * 8;
  const unsigned short* gAh1 = gAh0 + (size_t)64 * K;
  const unsigned short* gBh0 = Bh + (size_t)(bn + row0) * K + s0 * 8;
  const unsigned short* gBh1 = gBh0 + (size_t)64 * K;
  const int lb0 = wave * 512, lb1 = 2048 + wave * 512;

  int aoff[4], boff[4];
#pragma unroll
  for (int m = 0; m < 4; ++m) {
    int ra = wr * 64 + m * 16 + fr;
    aoff[m] = ra * 32 + 8 * (fs ^ ((ra >> 1) & 3));
    int rb = wc * 64 + m * 16 + fr;
    boff[m] = rb * 32 + 8 * (fs ^ ((rb >> 1) & 3));
  }

  f32x4 acc[4][4];
#pragma unroll
  for (int m = 0; m < 4; ++m)
#pragma unroll
    for (int n = 0; n < 4; ++n) acc[m][n] = (f32x4){0.f, 0.f, 0.f, 0.f};

  for (int k0 = 0; k0 < K; k0 += 32) {
    __syncthreads();
    gll16(gAh0 + k0, &AhS[lb0]); gll16(gAh1 + k0, &AhS[lb1]);
    gll16(gBh0 + k0, &BhS[lb0]); gll16(gBh1 + k0, &BhS[lb1]);
    __syncthreads();
    bf8 ah[4], bh4[4];
#pragma unroll
    for (int m = 0; m < 4; ++m) ah[m] = *(const bf8*)&AhS[aoff[m]];
#pragma unroll
    for (int n = 0; n < 4; ++n) bh4[n] = *(const bf8*)&BhS[boff[n]];
#pragma unroll
    for (int m = 0; m < 4; ++m)
#pragma unroll
      for (int n = 0; n < 4; ++n)
        acc[m][n] = __builtin_amdgcn_mfma_f32_16x16x32_bf16(ah[m], bh4[n], acc[m][n], 0, 0, 0);
  }

  float bcol[4];
#pragma unroll
  for (int n = 0; n < 4; ++n) bcol[n] = bias[cb + wc * 64 + n * 16 + fr];
#pragma unroll
  for (int m = 0; m < 4; ++m)
#pragma unroll
    for (int r = 0; r < 4; ++r) {
      int row = bm + wr * 64 + m * 16 + fs * 4 + r;
      if (row < M) {
#pragma unroll
        for (int n = 0; n < 4; ++n) {
          int col = cb + wc * 64 + n * 16 + fr;
          Ch[(size_t)row * 512 + col] = f2bf(acc[m][n][r] + bcol[n]);
        }
      }
    }
}

// ---------------- split-K reduce 16 (+bias) ----------------
__global__ void k_red16(const float* __restrict__ part, const float* __restrict__ eb,
                        float* __restrict__ dst) {
  int idx = blockIdx.x * 256 + threadIdx.x;   // 1024*512
  float s = eb ? eb[idx & 511] : 0.f;
#pragma unroll
  for (int zz = 0; zz < 16; ++zz) s += part[(size_t)zz * 524288 + idx];
  dst[idx] = s;
}

// ---------------- split-K reduce 8 -> bf16 hi (W' fold) ----------------
__global__ void k_redsplit(const float* __restrict__ part, unsigned short* __restrict__ WH) {
  int idx = blockIdx.x * 256 + threadIdx.x;   // 1024*512
  float s = 0.f;
#pragma unroll
  for (int zz = 0; zz < 8; ++zz) s += part[(size_t)zz * 524288 + idx];
  WH[idx] = f2bf(s);
}

// ---------------- bf16 repack G[(b,s),(c,n)] -> G2[(b,n),(c,s)] ----------------
__global__ __launch_bounds__(256) void k_repackb(const unsigned short* __restrict__ G,
                                                 unsigned short* __restrict__ G2) {
  int bid = blockIdx.x;
  int st = bid & 15, c = (bid >> 4) & 31, b = bid >> 9;
  __shared__ unsigned short tile[32][34];
  int tid = threadIdx.x;
  int n = tid & 31, s = tid >> 5;
  for (int q = 0; q < 4; ++q) {
    int ss = s + q * 8;
    tile[ss][n] = G[((size_t)b * T_ + st * 32 + ss) * 1024 + c * 32 + n];
  }
  __syncthreads();
  int s2 = tid & 31, n2 = tid >> 5;
  for (int q = 0; q < 4; ++q) {
    int nn = n2 + q * 8;
    G2[((size_t)b * 32 + nn) * 16384 + c * 512 + st * 32 + s2] = tile[s2][nn];
  }
}

// ---------------- lw projection + residual + LN -> cur fp32 AND A0 planes ----------------
__global__ __launch_bounds__(256) void k_lwln(const float* __restrict__ osm,
                                              const float* __restrict__ lw,
                                              const float* __restrict__ lb,
                                              const float* __restrict__ curIn,
                                              const float* __restrict__ g,
                                              const float* __restrict__ bt,
                                              float* __restrict__ curOut,
                                              unsigned short* __restrict__ xh,
                                              unsigned short* __restrict__ xl,
                                              const int* __restrict__ meta, int iter) {
  int tok = blockIdx.x;
  int b = tok >> 9, t = tok & 511;
  __shared__ float os[C_];
  __shared__ float red[256];
  int tid = threadIdx.x;
  if (tid < C_) os[tid] = osm[((size_t)b * C_ + tid) * T_ + t];
  __syncthreads();
  float val[2];
#pragma unroll
  for (int q = 0; q < 2; ++q) {
    int m = tid + q * 256;
    float s = lb[m] + curIn[(size_t)tok * N_ + m];
    for (int n2 = 0; n2 < C_; ++n2) s += os[n2] * lw[n2 * N_ + m];
    val[q] = s;
  }
  red[tid] = val[0] + val[1];
  __syncthreads();
  for (int off = 128; off > 0; off >>= 1) { if (tid < off) red[tid] += red[tid + off]; __syncthreads(); }
  float mean = red[0] * (1.0f / N_);
  __syncthreads();
  float d0 = val[0] - mean, d1 = val[1] - mean;
  red[tid] = d0 * d0 + d1 * d1;
  __syncthreads();
  for (int off = 128; off > 0; off >>= 1) { if (tid < off) red[tid] += red[tid + off]; __syncthreads(); }
  float inv = rsqrtf(red[0] * (1.0f / N_) + EPS_);
  float o0 = d0 * inv * g[tid] + bt[tid];
  float o1 = d1 * inv * g[tid + 256] + bt[tid + 256];
  curOut[(size_t)tok * N_ + tid] = o0;
  curOut[(size_t)tok * N_ + tid + 256] = o1;
  int L = meta[6 + iter];
  size_t pi = ((size_t)b * L + t) * N_;
  st2(xh, xl, pi + tid, o0);
  st2(xh, xl, pi + tid + 256, o1);
}

// ---------------- zero pad rows l in [T,L) of A0 planes ----------------
__global__ void k_padtail(unsigned short* __restrict__ xh, unsigned short* __restrict__ xl,
                          const int* __restrict__ meta, int iter) {
  int L = meta[6 + iter];
  int pad = L - T_;
  if (pad <= 0) return;
  size_t total = (size_t)B_ * pad * N_;
  for (size_t idx = (size_t)blockIdx.x * 256 + threadIdx.x; idx < total;
       idx += (size_t)gridDim.x * 256) {
    size_t row = idx >> 9;
    int d = (int)(idx & 511);
    int b = (int)(row / pad), l = T_ + (int)(row % pad);
    size_t o = ((size_t)b * L + l) * N_ + d;
    xh[o] = 0; xl[o] = 0;
  }
}

// ---------------- residual add + LN (planes in, planes out) ----------------
__global__ __launch_bounds__(256) void k_lnadd(const unsigned short* __restrict__ r1h,
                                               const unsigned short* __restrict__ r1l,
                                               const unsigned short* __restrict__ r2h,
                                               const unsigned short* __restrict__ r2l,
                                               const float* __restrict__ g,
                                               const float* __restrict__ bt,
                                               unsigned short* __restrict__ dh,
                                               unsigned short* __restrict__ dl,
                                               const int* __restrict__ meta, int iter) {
  int tokens = meta[15 + iter];
  int tok = blockIdx.x;
  if (tok >= tokens) return;
  __shared__ float red[256];
  int tid = threadIdx.x;
  float val[2];
#pragma unroll
  for (int q = 0; q < 2; ++q) {
    size_t i = (size_t)tok * N_ + tid + q * 256;
    val[q] = ld2(r1h, r1l, i) + ld2(r2h, r2l, i);
  }
  red[tid] = val[0] + val[1];
  __syncthreads();
  for (int off = 128; off > 0; off >>= 1) { if (tid < off) red[tid] += red[tid + off]; __syncthreads(); }
  float mean = red[0] * (1.0f / N_);
  __syncthreads();
  float d0 = val[0] - mean, d1 = val[1] - mean;
  red[tid] = d0 * d0 + d1 * d1;
  __syncthreads();
  for (int off = 128; off > 0; off >>= 1) { if (tid < off) red[tid] += red[tid + off]; __syncthreads(); }
  float inv = rsqrtf(red[0] * (1.0f / N_) + EPS_);
  st2(dh, dl, (size_t)tok * N_ + tid, d0 * inv * g[tid] + bt[tid]);
  st2(dh, dl, (size_t)tok * N_ + tid + 256, d1 * inv * g[tid + 256] + bt[tid + 256]);
}

// ---------------- fused: LN(r1+r2) -> LN -> gelu -> weighted accumulate ----------------
__global__ __launch_bounds__(256) void k_lnfin(const unsigned short* __restrict__ r1h,
                                               const unsigned short* __restrict__ r1l,
                                               const unsigned short* __restrict__ r2h,
                                               const unsigned short* __restrict__ r2l,
                                               const float* __restrict__ g1,
                                               const float* __restrict__ b1,
                                               const float* __restrict__ g2,
                                               const float* __restrict__ b2,
                                               const float* __restrict__ swb,
                                               float* __restrict__ acc,
                                               const int* __restrict__ meta, int iter) {
  int L = meta[6 + iter];
  int tok = blockIdx.x;
  if (tok >= B_ * L) return;
  int b = tok / L, l = tok % L;
  if (l >= T_) return;   // truncated away
  __shared__ float red[256];
  int tid = threadIdx.x;
  float val[2];
#pragma unroll
  for (int q = 0; q < 2; ++q) {
    size_t i = (size_t)tok * N_ + tid + q * 256;
    val[q] = ld2(r1h, r1l, i) + ld2(r2h, r2l, i);
  }
  red[tid] = val[0] + val[1];
  __syncthreads();
  for (int off = 128; off > 0; off >>= 1) { if (tid < off) red[tid] += red[tid + off]; __syncthreads(); }
  float mean = red[0] * (1.0f / N_);
  __syncthreads();
  float d0 = val[0] - mean, d1 = val[1] - mean;
  red[tid] = d0 * d0 + d1 * d1;
  __syncthreads();
  for (int off = 128; off > 0; off >>= 1) { if (tid < off) red[tid] += red[tid + off]; __syncthreads(); }
  float inv = rsqrtf(red[0] * (1.0f / N_) + EPS_);
  float y0 = d0 * inv * g1[tid] + b1[tid];
  float y1 = d1 * inv * g1[tid + 256] + b1[tid + 256];
  // second LN over y
  __syncthreads();
  red[tid] = y0 + y1;
  __syncthreads();
  for (int off = 128; off > 0; off >>= 1) { if (tid < off) red[tid] += red[tid + off]; __syncthreads(); }
  float mean2 = red[0] * (1.0f / N_);
  __syncthreads();
  float e0 = y0 - mean2, e1 = y1 - mean2;
  red[tid] = e0 * e0 + e1 * e1;
  __syncthreads();
  for (int off = 128; off > 0; off >>= 1) { if (tid < off) red[tid] += red[tid + off]; __syncthreads(); }
  float inv2 = rsqrtf(red[0] * (1.0f / N_) + EPS_);
  float s = swb[b * 4 + iter];
  float u0 = gelu_exact(e0 * inv2 * g2[tid] + b2[tid]);
  float u1 = gelu_exact(e1 * inv2 * g2[tid + 256] + b2[tid + 256]);
  size_t o = ((size_t)b * T_ + l) * N_;
  acc[o + tid] += s * u0;
  acc[o + tid + 256] += s * u1;
}

// ---------------- attention S<=32: wave-per-pair, lane=t scores, barrier-free ----------------
__global__ __launch_bounds__(256) void k_attn32(
    const unsigned short* __restrict__ qh,
    const unsigned short* __restrict__ kh,
    const unsigned short* __restrict__ vh,
    unsigned short* __restrict__ oh,
    const int* __restrict__ meta, int iter) {
  int S = meta[3 + iter];
  if (S > 32) return;
  int L = meta[6 + iter], nseq = meta[9 + iter];
  int npair = B_ * nseq * 8;
  __shared__ float Kt[4][64 * 33];
  __shared__ unsigned short Vsh[4][32 * 66];
  __shared__ float qs[4][64];
  int tid = threadIdx.x;
  int wave = tid >> 6, lane = tid & 63;
  float* Ktw = Kt[wave];
  unsigned short* Vw = Vsh[wave];
  int gw = (blockIdx.x * 256 + tid) >> 6;
  int nw = (gridDim.x * 256) >> 6;
  const int tt = lane & 31;
  const int hf = lane >> 5;
  for (int pair = gw; pair < npair; pair += nw) {
    int h = pair & 7;
    int m = pair >> 3;
    int b = m / nseq, g2 = m - b * nseq;
    size_t base = ((size_t)b * L + (size_t)g2 * S) * N_ + h * 64;
    for (int i = lane; i < S * 64; i += 64) {
      int t = i >> 6, d = i & 63;
      size_t gi = base + (size_t)t * N_ + d;
      Ktw[d * 33 + t] = bf2f(kh[gi]);
      Vw[t * 66 + d] = vh[gi];
    }
    bool tok = tt < S;
    for (int s = 0; s < S; ++s) {
      qs[wave][lane] = bf2f(qh[base + (size_t)s * N_ + lane]);
      float part = 0.f;
      if (tok) {
        const float* kp = &Ktw[hf * 32 * 33 + tt];
        const float* qp = &qs[wave][hf * 32];
#pragma unroll 8
        for (int j = 0; j < 32; ++j) part += qp[j] * kp[j * 33];
      }
      part += __shfl_xor(part, 32);
      float sc = tok ? part * 0.125f : -3.0e38f;
      float mx = sc;
      for (int off = 16; off > 0; off >>= 1) mx = fmaxf(mx, __shfl_xor(mx, off));
      float p = tok ? __expf(sc - mx) : 0.f;
      float ssum = p;
      for (int off = 16; off > 0; off >>= 1) ssum += __shfl_xor(ssum, off);
      float ov = 0.f;
      for (int t = 0; t < S; ++t) {
        float pt = __shfl(p, t);
        ov += pt * bf2f(Vw[t * 66 + lane]);
      }
      oh[base + (size_t)s * N_ + lane] = f2bf(ov / ssum);
    }
  }
}

// ---------------- MFMA flash attention, 32<S<=128: one block per (seq,head) ----------------
__global__ __launch_bounds__(256, 3) void k_attn_small(
    const unsigned short* __restrict__ qh,
    const unsigned short* __restrict__ kh,
    const unsigned short* __restrict__ vh,
    unsigned short* __restrict__ oh,
    const int* __restrict__ meta, int iter) {
  int S = meta[3 + iter];
  if (S <= 32 || S > 128) return;
  int L = meta[6 + iter], nseq = meta[9 + iter];
  int M = B_ * nseq;
  int mh = blockIdx.x;
  int m0 = mh >> 3, h = mh & 7;
  if (m0 >= M) return;
  int b = m0 / nseq, g2 = m0 % nseq;
  size_t tok0 = (size_t)b * L + (size_t)g2 * S;

  // U: QK phase = {Q kstep0, Q kstep1, K kstep0, K kstep1}; PV phase = P[4 ksteps]
  __shared__ __align__(16) unsigned short U[16384];
  __shared__ __align__(16) unsigned short VT[8192];   // V^T, 4 k-steps [64][32]
  __shared__ float rb1[2][128], rb2[2][128];

  const int tid = threadIdx.x;
  const int wave = tid >> 6, lane = tid & 63;
  const int wr = wave >> 1, wc = wave & 1;
  const int fr = lane & 15, fs = lane >> 4;

  // ---- stage Q,K via global_load_lds (mmb1 pattern, K=64 -> 2 k-steps) ----
  const int row0 = tid >> 2;
  const int s0 = (tid & 3) ^ ((row0 >> 1) & 3);
  const unsigned short* gQ0 = qh + (tok0 + row0) * N_ + h * 64 + s0 * 8;
  const unsigned short* gQ1 = gQ0 + (size_t)64 * N_;
  const unsigned short* gK0 = kh + (tok0 + row0) * N_ + h * 64 + s0 * 8;
  const unsigned short* gK1 = gK0 + (size_t)64 * N_;
  const int lb0 = wave * 512, lb1 = 2048 + wave * 512;
  gll16(gQ0,      &U[lb0]);         gll16(gQ1,      &U[lb1]);
  gll16(gQ0 + 32, &U[4096 + lb0]);  gll16(gQ1 + 32, &U[4096 + lb1]);
  gll16(gK0,      &U[8192 + lb0]);  gll16(gK1,      &U[8192 + lb1]);
  gll16(gK0 + 32, &U[12288 + lb0]); gll16(gK1 + 32, &U[12288 + lb1]);
  // ---- stage V^T via reg transpose into swizzled B layout ----
  for (int i = tid; i < 128 * 8; i += 256) {
    int t = i >> 3, c8 = i & 7;
    u16x8 vv8 = *(const u16x8*)&vh[(tok0 + t) * N_ + h * 64 + c8 * 8];
    int kk = t >> 5, chunk = (t & 31) >> 3, e = t & 7;
#pragma unroll
    for (int q = 0; q < 8; ++q) {
      int d = c8 * 8 + q;
      VT[kk * 2048 + d * 32 + 8 * (chunk ^ ((d >> 1) & 3)) + e] = vv8[q];
    }
  }
  __syncthreads();

  // ---- QK^T: scores[q][k] ----
  int aoff[4], boff[4];
#pragma unroll
  for (int m = 0; m < 4; ++m) {
    int ra = wr * 64 + m * 16 + fr;
    aoff[m] = ra * 32 + 8 * (fs ^ ((ra >> 1) & 3));
    int rb = wc * 64 + m * 16 + fr;
    boff[m] = rb * 32 + 8 * (fs ^ ((rb >> 1) & 3));
  }
  f32x4 acc[4][4];
#pragma unroll
  for (int m = 0; m < 4; ++m)
#pragma unroll
    for (int n = 0; n < 4; ++n) acc[m][n] = (f32x4){0.f, 0.f, 0.f, 0.f};
#pragma unroll
  for (int kk = 0; kk < 2; ++kk) {
    bf8 ah[4], bh[4];
#pragma unroll
    for (int m = 0; m < 4; ++m) ah[m] = *(const bf8*)&U[kk * 4096 + aoff[m]];
#pragma unroll
    for (int n = 0; n < 4; ++n) bh[n] = *(const bf8*)&U[8192 + kk * 4096 + boff[n]];
#pragma unroll
    for (int m = 0; m < 4; ++m)
#pragma unroll
      for (int n = 0; n < 4; ++n)
        acc[m][n] = __builtin_amdgcn_mfma_f32_16x16x32_bf16(ah[m], bh[n], acc[m][n], 0, 0, 0);
  }

  // ---- mask + scale; row-max partials ----
  bool colok[4];
#pragma unroll
  for (int n = 0; n < 4; ++n) colok[n] = (wc * 64 + n * 16 + fr) < S;
#pragma unroll
  for (int m = 0; m < 4; ++m)
#pragma unroll
    for (int n = 0; n < 4; ++n)
#pragma unroll
      for (int r = 0; r < 4; ++r)
        acc[m][n][r] = colok[n] ? acc[m][n][r] * 0.125f : -3.0e38f;
#pragma unroll
  for (int m = 0; m < 4; ++m)
#pragma unroll
    for (int r = 0; r < 4; ++r) {
      float pm = fmaxf(fmaxf(acc[m][0][r], acc[m][1][r]), fmaxf(acc[m][2][r], acc[m][3][r]));
      pm = fmaxf(pm, __shfl_xor(pm, 1));
      pm = fmaxf(pm, __shfl_xor(pm, 2));
      pm = fmaxf(pm, __shfl_xor(pm, 4));
      pm = fmaxf(pm, __shfl_xor(pm, 8));
      if (fr == 0) rb1[wc][wr * 64 + m * 16 + fs * 4 + r] = pm;
    }
  __syncthreads();   // rb1 ready; all U fragment reads complete

  // ---- exp + row-sum partials; scatter P (bf16) into U as PV A-operand ----
#pragma unroll
  for (int m = 0; m < 4; ++m)
#pragma unroll
    for (int r = 0; r < 4; ++r) {
      int row = wr * 64 + m * 16 + fs * 4 + r;
      float mx = fmaxf(rb1[0][row], rb1[1][row]);
      float ps = 0.f;
#pragma unroll
      for (int n = 0; n < 4; ++n) {
        float e = __expf(acc[m][n][r] - mx);
        acc[m][n][r] = e;
        ps += e;
      }
      ps += __shfl_xor(ps, 1);
      ps += __shfl_xor(ps, 2);
      ps += __shfl_xor(ps, 4);
      ps += __shfl_xor(ps, 8);
      if (fr == 0) rb2[wc][row] = ps;
    }
#pragma unroll
  for (int m = 0; m < 4; ++m)
#pragma unroll
    for (int n = 0; n < 4; ++n) {
      int col = wc * 64 + n * 16 + fr;
      int kk = col >> 5, chunk = (col & 31) >> 3, e = col & 7;
#pragma unroll
      for (int r = 0; r < 4; ++r) {
        int row = wr * 64 + m * 16 + fs * 4 + r;
        U[kk * 4096 + row * 32 + 8 * (chunk ^ ((row >> 1) & 3)) + e] = f2bf(acc[m][n][r]);
      }
    }
  __syncthreads();   // P + rb2 ready

  // ---- PV: out[q][d] = sum_t P[q][t] * VT[d][t]; waves split rows (32 each) ----
  int nk = (S + 31) >> 5;
  int aoff2[2], boff2[4];
#pragma unroll
  for (int m = 0; m < 2; ++m) {
    int ra = wave * 32 + m * 16 + fr;
    aoff2[m] = ra * 32 + 8 * (fs ^ ((ra >> 1) & 3));
  }
#pragma unroll
  for (int n = 0; n < 4; ++n) {
    int rb = n * 16 + fr;
    boff2[n] = rb * 32 + 8 * (fs ^ ((rb >> 1) & 3));
  }
  f32x4 o2[2][4];
#pragma unroll
  for (int m = 0; m < 2; ++m)
#pragma unroll
    for (int n = 0; n < 4; ++n) o2[m][n] = (f32x4){0.f, 0.f, 0.f, 0.f};
  for (int kk = 0; kk < nk; ++kk) {
    bf8 pa[2], vb[4];
#pragma unroll
    for (int m = 0; m < 2; ++m) pa[m] = *(const bf8*)&U[kk * 4096 + aoff2[m]];
#pragma unroll
    for (int n = 0; n < 4; ++n) vb[n] = *(const bf8*)&VT[kk * 2048 + boff2[n]];
#pragma unroll
    for (int m = 0; m < 2; ++m)
#pragma unroll
      for (int n = 0; n < 4; ++n)
        o2[m][n] = __builtin_amdgcn_mfma_f32_16x16x32_bf16(pa[m], vb[n], o2[m][n], 0, 0, 0);
  }

  // ---- epilogue: divide by row sums, write ----
#pragma unroll
  for (int m = 0; m < 2; ++m)
#pragma unroll
    for (int r = 0; r < 4; ++r) {
      int orow = wave * 32 + m * 16 + fs * 4 + r;
      if (orow < S) {
        float inv = 1.0f / (rb2[0][orow] + rb2[1][orow]);
#pragma unroll
        for (int n = 0; n < 4; ++n)
          oh[(tok0 + orow) * N_ + h * 64 + n * 16 + fr] = f2bf(o2[m][n][r] * inv);
      }
    }
}

// ---------------- fused attention, 128<S<=512 — barrier-free waves ----------------
__global__ __launch_bounds__(256) void k_attn_big(
    const unsigned short* __restrict__ qh,
    const unsigned short* __restrict__ kh,
    const unsigned short* __restrict__ vh,
    unsigned short* __restrict__ oh,
    const int* __restrict__ meta, int iter) {
  int p = meta[3 + iter];
  if (p <= 128) return;
  int L = meta[6 + iter], nseq = meta[9 + iter];
  int M = B_ * nseq;
  int mh = blockIdx.x;
  int m = mh >> 3, h = mh & 7;
  if (m >= M) return;
  int S = p;
  int b = m / nseq, g2 = m % nseq;
  size_t tok0 = (size_t)b * L + (size_t)g2 * S;
  __shared__ unsigned short Ks[512 * 66];
  __shared__ unsigned short Vs[512 * 66];
  __shared__ float qrow[4][64];
  __shared__ float Pr[4][512];
  int tid = threadIdx.x;
  for (int i = tid; i < S * 64; i += 256) {
    int t = i >> 6, d = i & 63;
    size_t gi = (tok0 + t) * N_ + h * 64 + d;
    Ks[t * 66 + d] = kh[gi];
    Vs[t * 66 + d] = vh[gi];
  }
  __syncthreads();   // only barrier
  int wave = tid >> 6, lane = tid & 63;
  for (int s = wave; s < S; s += 4) {
    qrow[wave][lane] = bf2f(qh[(tok0 + s) * N_ + h * 64 + lane]);
    const float2* qp = (const float2*)&qrow[wave][0];
    float sc[8];
    float mx = -3.0e38f;
#pragma unroll
    for (int c2 = 0; c2 < 8; ++c2) {
      int t = lane + c2 * 64;
      float sv = -3.0e38f;
      if (t < S) {
        const unsigned int* kp = (const unsigned int*)&Ks[t * 66];
        float ad = 0.f;
#pragma unroll
        for (int j2 = 0; j2 < 32; ++j2) {
          float2 qq = qp[j2];
          unsigned int kw = kp[j2];
          ad += qq.x * bf2f((unsigned short)(kw & 0xffffu));
          ad += qq.y * bf2f((unsigned short)(kw >> 16));
        }
        sv = ad * 0.125f;
      }
      sc[c2] = sv;
      mx = fmaxf(mx, sv);
    }
    for (int off = 32; off > 0; off >>= 1) mx = fmaxf(mx, __shfl_xor(mx, off));
    float ssum = 0.f;
#pragma unroll
    for (int c2 = 0; c2 < 8; ++c2) {
      int t = lane + c2 * 64;
      float e = 0.f;
      if (t < S) { e = __expf(sc[c2] - mx); Pr[wave][t] = e; }
      ssum += e;
    }
    for (int off = 32; off > 0; off >>= 1) ssum += __shfl_xor(ssum, off);
    float inv = 1.0f / ssum;
    float ov = 0.f;
#pragma unroll 8
    for (int t = 0; t < S; ++t) ov += Pr[wave][t] * bf2f(Vs[t * 66 + lane]);
    oh[(tok0 + s) * N_ + h * 64 + lane] = f2bf(ov * inv);
  }
}

// ---------------- final output ----------------
__global__ void k_final(const float* __restrict__ acc, const float* __restrict__ cur,
                        float* __restrict__ out) {
  size_t idx = (size_t)blockIdx.x * 256 + threadIdx.x;
  out[idx] = acc[idx] + cur[idx];
}

extern "C" void kernel_launch(void* const* d_in, const int* in_sizes, int n_in,
                              void* d_out, int out_size, void* d_ws, size_t ws_size,
                              hipStream_t stream) {
  (void)in_sizes; (void)n_in; (void)out_size; (void)ws_size;
  const float* x       = (const float*)d_in[0];
  const float* nv1     = (const float*)d_in[1];
  const float* nv2     = (const float*)d_in[2];
  const float* start_w = (const float*)d_in[3];
  const float* start_b = (const float*)d_in[4];
  const float* mix_w   = (const float*)d_in[5];
  const float* mix_b   = (const float*)d_in[6];
  const float* end_w   = (const float*)d_in[7];
  const float* end_b   = (const float*)d_in[8];
  const float* glin_w  = (const float*)d_in[9];
  const float* glin_b  = (const float*)d_in[10];
  const float* gnorm_g = (const float*)d_in[11];
  const float* gnorm_b = (const float*)d_in[12];
  const float* wq = (const float*)d_in[13];
  const float* bq = (const float*)d_in[14];
  const float* wk = (const float*)d_in[15];
  const float* bk = (const float*)d_in[16];
  const float* wv = (const float*)d_in[17];
  const float* bv = (const float*)d_in[18];
  const float* wo = (const float*)d_in[19];
  const float* bo = (const float*)d_in[20];
  const float* ff1w = (const float*)d_in[21];
  const float* ff1b = (const float*)d_in[22];
  const float* ff2w = (const float*)d_in[23];
  const float* ff2b = (const float*)d_in[24];
  const float* an1g = (const float*)d_in[25];
  const float* an1b = (const float*)d_in[26];
  const float* an2g = (const float*)d_in[27];
  const float* an2b = (const float*)d_in[28];
  const float* nrmg = (const float*)d_in[29];
  const float* nrmb = (const float*)d_in[30];

  char* ws = (char*)d_ws;
  int*   meta = (int*)(ws + OFF_META);
  float* freq = (float*)(ws + OFF_FREQ);
  float* swb  = (float*)(ws + OFF_SW);
  float* beff = (float*)(ws + OFF_BEFF);
  float* P12  = (float*)(ws + OFF_P12);
  float* fsumb = (float*)(ws + OFF_FSB);
  float* osm  = (float*)(ws + OFF_OSM);
  unsigned short* TWH = (unsigned short*)(ws + OFF_TWH);
  unsigned short* TWL = (unsigned short*)(ws + OFF_TWL);
  unsigned short* WB  = (unsigned short*)(ws + OFF_WB);
  unsigned short* WdH = (unsigned short*)(ws + OFF_WDH);
  unsigned short* EWH = (unsigned short*)(ws + OFF_EWH);
  float* cur  = (float*)(ws + OFF_CUR);
  float* accb = (float*)(ws + OFF_ACC);
  unsigned short* XWH = (unsigned short*)(ws + OFF_XWH);
  float* fpart = (float*)(ws + OFF_FP);
  float* Tm   = (float*)(ws + OFF_T);
  unsigned short* WPH = (unsigned short*)(ws + OFF_WPH);
  unsigned short* Gb  = (unsigned short*)(ws + OFF_G);
  unsigned short* G2b = (unsigned short*)(ws + OFF_G2);
  float* PART = (float*)(ws + OFF_PART);
  unsigned short* A0h = (unsigned short*)(ws + OFF_A0); unsigned short* A0l = A0h + PLW;
  unsigned short* A2h = (unsigned short*)(ws + OFF_A2); unsigned short* A2l = A2h + PLW;
  unsigned short* A3h = (unsigned short*)(ws + OFF_A3); unsigned short* A3l = A3h + PLW;
  unsigned short* A4h = (unsigned short*)(ws + OFF_A4);
  unsigned short* A5h = (unsigned short*)(ws + OFF_A5); unsigned short* A5l = A5h + PLW;

  hipMemsetAsync(accb, 0, (size_t)B_ * T_ * N_ * 4, stream);

  // ---- STFT via MFMA (window on twiddle side ONLY; x-hi only, twiddles hi+lo) ----
  k_xw<<<B_ * NFR_, 256, 0, stream>>>(x, XWH);
  k_tw<<<(2 * 384 * 64 + 255) / 256, 256, 0, stream>>>(TWH, TWL);
  k_stftmm<<<dim3(3, NMT_), 256, 0, stream>>>(XWH, TWH, TWL, fpart);
  k_fred<<<NBIN_, 256, 0, stream>>>(fpart, freq, fsumb);
  k_topk<<<1, 64, 0, stream>>>(freq, fsumb, meta, swb);

  // split attention/FF weights into bf16 hi planes (once); Q,K,V contiguous
  const float* wlist[6] = {wq, wk, wv, wo, ff1w, ff2w};
  for (int w = 0; w < 6; ++w)
    k_splith<<<256, 256, 0, stream>>>(wlist[w], WB + (size_t)w * 262144, 262144);
  unsigned short* WqkvH = WB;              // [1536][512]
  unsigned short* WoH = WB + 3 * 262144;
  unsigned short* F1H = WB + 4 * 262144;
  unsigned short* F2H = WB + 5 * 262144;

  const float* curIn = x;
  for (int i = 0; i < 3; ++i) {
    // ---- graph block: fold conv+GCN+mix into one weight W' = T @ Wd ----
    k_adjprep<<<1, 1024, 0, stream>>>(nv1 + i * C_ * 10, nv2 + i * 10 * C_,
                                      mix_w + i * C_ * 96, mix_b + i * C_,
                                      start_b + i * C_, P12, beff);
    k_T<<<4096, 256, 0, stream>>>(P12, mix_w + i * C_ * 96, Tm);
    k_wdh<<<2048, 256, 0, stream>>>(start_w + i * C_ * KH_, WdH);
    k_mm2<<<dim3(4, 8, 8), 256, 0, stream>>>(Tm, WdH, nullptr, nullptr, PART,
                                             1024, 512, 1024, 1024, 0);
    k_redsplit<<<2048, 256, 0, stream>>>(PART, WPH);
    // G = gelu(curIn @ W'^T + b_eff)   [16384 x 1024] bf16
    k_mmcv<<<dim3(8, 128), 256, 0, stream>>>(curIn, WPH, beff, Gb, 16384, 1024, 512, 512);
    k_repackb<<<B_ * C_ * 16, 256, 0, stream>>>(Gb, G2b);
    k_splith<<<8192, 256, 0, stream>>>(end_w + (size_t)i * 8388608, EWH, 8388608);
    k_mmend<<<dim3(4, 8, 16), 256, 0, stream>>>(G2b, EWH, PART, 1024, 512, 16384);
    k_red16<<<2048, 256, 0, stream>>>(PART, end_b + i * T_, osm);
    k_lwln<<<B_ * T_, 256, 0, stream>>>(osm, glin_w + i * C_ * N_, glin_b + i * N_, curIn,
                                        gnorm_g + i * N_, gnorm_b + i * N_, cur,
                                        A0h, A0l, meta, i);
    k_padtail<<<512, 256, 0, stream>>>(A0h, A0l, meta, i);
    // ---- attention branch ----
    const int* Mdyn = meta + 15 + i;
    dim3 gT(4, TOKMAX / 128, 1);
    k_mmqkv<<<dim3(12, TOKMAX / 128), 256, 0, stream>>>(A0h, WqkvH, bq, bk, bv,
                                                        A2h, A3h, A4h, TOKMAX, 512, Mdyn);
    k_attn32<<<2048, 256, 0, stream>>>(A2h, A3h, A4h, A5h, meta, i);
    k_attn_small<<<4096, 256, 0, stream>>>(A2h, A3h, A4h, A5h, meta, i);
    k_attn_big<<<1024, 256, 0, stream>>>(A2h, A3h, A4h, A5h, meta, i);
    k_mmb1<<<gT, 256, 0, stream>>>(A5h, WoH, bo, A2h, A2l, TOKMAX, 512, 512, Mdyn, 0);
    k_lnadd<<<TOKMAX, 256, 0, stream>>>(A0h, A0l, A2h, A2l, an1g, an1b, A3h, A3l, meta, i);
    k_mmb1<<<gT, 256, 0, stream>>>(A3h, F1H, ff1b, A4h, nullptr, TOKMAX, 512, 512, Mdyn, 1);
    k_mmb1<<<gT, 256, 0, stream>>>(A4h, F2H, ff2b, A5h, A5l, TOKMAX, 512, 512, Mdyn, 0);
    k_lnfin<<<TOKMAX, 256, 0, stream>>>(A3h, A3l, A5h, A5l, an2g, an2b, nrmg, nrmb,
                                        swb, accb, meta, i);
    curIn = cur;
  }
  k_final<<<(B_ * T_ * N_) / 256, 256, 0, stream>>>(accb, curIn, (float*)d_out);
}

// Round 24
// 1852.093 us; speedup vs baseline: 1.0758x; 1.0207x over previous
//
#include <hip/hip_runtime.h>
#include <math.h>

#define DI __device__ __forceinline__

namespace {
constexpr int B_ = 32;
constexpr int T_ = 512;
constexpr int N_ = 512;   // d_model
constexpr int C_ = 32;    // c_out / conv_ch / skip_ch
constexpr int KH_ = 481;
constexpr int HOP_ = 48;
constexpr int WIN_ = 48;
constexpr int NFR_ = 11;
constexpr int NBIN_ = 257;
constexpr int NMT_ = B_ * NFR_ * 4;   // 1408 sample-tiles (44 per batch, contiguous)
constexpr int TOKMAX = 21760;   // 170*128 == exact max tokens (L=680)
constexpr int PLW = TOKMAX * 512;     // plane elements for token buffers
constexpr float EPS_ = 1e-5f;

constexpr size_t MBY = 1ull << 20;
constexpr size_t OFF_META = 0;
constexpr size_t OFF_FREQ = 4096;
constexpr size_t OFF_SW   = 8192;
constexpr size_t OFF_BEFF = 16384;       // 1024 floats
constexpr size_t OFF_P12  = 32768;       // 2048 floats
constexpr size_t OFF_FSB  = 65536;       // 257*32 floats (per-(k,b) sums)
constexpr size_t OFF_OSM  = 1 * MBY;     // 2MB (1..3MB)
constexpr size_t OFF_TWH  = 3 * MBY;         // twiddle hi planes [2][384][64] bf16
constexpr size_t OFF_TWL  = 3 * MBY + 131072;// twiddle lo planes
constexpr size_t OFF_WB   = 4 * MBY;     // 6 hi planes x 512KB = 3MB (Q,K,V contiguous!)
constexpr size_t OFF_WDH  = 10 * MBY;    // 1MB  (WdT hi plane [512][1024])
constexpr size_t OFF_EWH  = 12 * MBY;    // 16MB
constexpr size_t OFF_CUR  = 44 * MBY;    // 32MB
constexpr size_t OFF_ACC  = 76 * MBY;    // 32MB
constexpr size_t TR       = 108 * MBY;   // transient union region
// graph phase
constexpr size_t OFF_T    = TR;            // 4MB  T [1024][1024]
constexpr size_t OFF_WPH  = TR + 6 * MBY;  // 1MB  W' hi plane
constexpr size_t OFF_G    = TR + 64 * MBY; // 32MB bf16 [16384][1024]
constexpr size_t OFF_G2   = TR + 128 * MBY;// 32MB bf16 [1024][16384]
constexpr size_t OFF_PART = TR + 192 * MBY;// 32MB [16][1024][512]
// attention phase (aliases graph region): each buffer = hi plane + lo plane
constexpr size_t OFF_A0 = TR;              // 44MB stride each
constexpr size_t OFF_A2 = TR + 44 * MBY;
constexpr size_t OFF_A3 = TR + 88 * MBY;
constexpr size_t OFF_A4 = TR + 132 * MBY;
constexpr size_t OFF_A5 = TR + 176 * MBY;  // ends 328MB
// stft scratch aliases TR (stft completes before graph phase starts)
constexpr size_t OFF_XWH = TR;              // 23MB bf16 [180224][64] (x hi)
constexpr size_t OFF_FP  = TR + 48 * MBY;   // NBIN_*NMT_ floats ~1.45MB
} // namespace

typedef __attribute__((ext_vector_type(2))) float f32x2;
typedef __attribute__((ext_vector_type(4))) float f32x4;
typedef __attribute__((ext_vector_type(8))) short bf8;
typedef __attribute__((ext_vector_type(8))) unsigned short u16x8;

DI float gelu_exact(float x) { return 0.5f * x * (1.0f + erff(x * 0.7071067811865475f)); }
DI unsigned short f2bf(float f) {   // round-to-nearest-even
  unsigned u = __float_as_uint(f);
  u += 0x7FFFu + ((u >> 16) & 1u);
  return (unsigned short)(u >> 16);
}
DI float bf2f(unsigned short s) { return __uint_as_float(((unsigned)s) << 16); }
DI float ld2(const unsigned short* __restrict__ H, const unsigned short* __restrict__ L,
             size_t i) { return bf2f(H[i]) + bf2f(L[i]); }
DI void st2(unsigned short* __restrict__ H, unsigned short* __restrict__ L,
            size_t i, float v) {
  unsigned short h = f2bf(v);
  H[i] = h;
  L[i] = f2bf(v - bf2f(h));
}
DI void gll16(const unsigned short* g, unsigned short* l) {
  __builtin_amdgcn_global_load_lds(
      (const __attribute__((address_space(1))) void*)g,
      (__attribute__((address_space(3))) void*)l, 16, 0, 0);
}

// ---------------- build x-hi frames: XW [180224][64] via LDS transpose ----------------
__global__ __launch_bounds__(256) void k_xw(const float* __restrict__ x,
                                            unsigned short* __restrict__ XWH) {
  int bf = blockIdx.x;            // b*NFR + f
  int f = bf % NFR_, b = bf / NFR_;
  __shared__ unsigned short TS[512 * 58];   // [n][j], pad 58 (stride 29 dw, conflict-free)
  int tid = threadIdx.x;
  // phase 1: coalesced reads (lane = n), LDS write conflict-free
  for (int idx = tid; idx < WIN_ * 512; idx += 256) {
    int j = idx >> 9, n = idx & 511;
    int gi = f * HOP_ + 232 + j - 256;
    if (gi < 0) gi = -gi;   // reflect pad (left only)
    TS[n * 58 + j] = f2bf(x[((size_t)b * T_ + gi) * N_ + n]);
  }
  __syncthreads();
  // phase 2: coalesced 16B global writes
  for (int i = tid; i < 512 * 8; i += 256) {
    int n = i >> 3, jc = i & 7;
    size_t m = (size_t)bf * 512 + n;
    u16x8 v;
    if (jc < 6) {
#pragma unroll
      for (int q = 0; q < 8; ++q) v[q] = TS[n * 58 + jc * 8 + q];
    } else {
#pragma unroll
      for (int q = 0; q < 8; ++q) v[q] = 0;
    }
    *(u16x8*)&XWH[m * 64 + jc * 8] = v;
  }
}

// ---------------- build twiddle hi/lo planes [2][384][64] (window baked in HERE) ----------------
__global__ void k_tw(unsigned short* __restrict__ TWH, unsigned short* __restrict__ TWL) {
  int idx = blockIdx.x * 256 + threadIdx.x;   // 2*384*64 = 49152
  if (idx >= 2 * 384 * 64) return;
  int pl = idx / (384 * 64);
  int rem = idx % (384 * 64);
  int k = rem >> 6, j = rem & 63;
  float v = 0.f;
  if (k < NBIN_ && j < WIN_) {
    int r = (k * (232 + j)) & 511;
    float ang = (float)r * 0.012271846303085130f;   // 2pi/512
    float w = 0.5f - 0.5f * cosf((float)j * 0.13089969389957472f);
    v = pl == 0 ? w * cosf(ang) : w * sinf(ang);
  }
  unsigned short h = f2bf(v);
  TWH[idx] = h;
  TWL[idx] = f2bf(v - bf2f(h));
}

// ---------------- MFMA STFT: mags summed per (k, sample-tile) ----------------
// A = x-hi [180224][64]; B = windowed twiddles (re/im, hi+lo). 128x128 tile.
__global__ __launch_bounds__(256, 3) void k_stftmm(
    const unsigned short* __restrict__ XWH,
    const unsigned short* __restrict__ TWH, const unsigned short* __restrict__ TWL,
    float* __restrict__ fpart) {
  const int bn = blockIdx.x * 128;     // k-tile base (0,128,256)
  const int mtile = blockIdx.y;
  const int bm = mtile * 128;

  __shared__ __align__(16) unsigned short AHS[4096], RHS[4096], RLS[4096],
                                          IHS[4096], ILS[4096];
  __shared__ float colpart[2][128];

  const int tid = threadIdx.x;
  const int wave = tid >> 6, lane = tid & 63;
  const int wr = wave >> 1, wc = wave & 1;
  const int fr = lane & 15, fs = lane >> 4;

  const int row0 = tid >> 2;
  const int s0 = (tid & 3) ^ ((row0 >> 1) & 3);
  const unsigned short* gAH0 = XWH + (size_t)(bm + row0) * 64 + s0 * 8;
  const unsigned short* gAH1 = gAH0 + (size_t)64 * 64;
  const unsigned short* gRH0 = TWH + (size_t)(bn + row0) * 64 + s0 * 8;
  const unsigned short* gRH1 = gRH0 + (size_t)64 * 64;
  const unsigned short* gRL0 = TWL + (size_t)(bn + row0) * 64 + s0 * 8;
  const unsigned short* gRL1 = gRL0 + (size_t)64 * 64;
  const unsigned short* gIH0 = gRH0 + (size_t)384 * 64;
  const unsigned short* gIH1 = gRH1 + (size_t)384 * 64;
  const unsigned short* gIL0 = gRL0 + (size_t)384 * 64;
  const unsigned short* gIL1 = gRL1 + (size_t)384 * 64;
  const int lb0 = wave * 512, lb1 = 2048 + wave * 512;

  int aoff[4], boff[4];
#pragma unroll
  for (int m = 0; m < 4; ++m) {
    int ra = wr * 64 + m * 16 + fr;
    aoff[m] = ra * 32 + 8 * (fs ^ ((ra >> 1) & 3));
    int rb = wc * 64 + m * 16 + fr;
    boff[m] = rb * 32 + 8 * (fs ^ ((rb >> 1) & 3));
  }

  f32x4 are[4][4], aim[4][4];
#pragma unroll
  for (int m = 0; m < 4; ++m)
#pragma unroll
    for (int n = 0; n < 4; ++n) {
      are[m][n] = (f32x4){0.f, 0.f, 0.f, 0.f};
      aim[m][n] = (f32x4){0.f, 0.f, 0.f, 0.f};
    }

  for (int k0 = 0; k0 < 64; k0 += 32) {
    __syncthreads();
    gll16(gAH0 + k0, &AHS[lb0]); gll16(gAH1 + k0, &AHS[lb1]);
    gll16(gRH0 + k0, &RHS[lb0]); gll16(gRH1 + k0, &RHS[lb1]);
    gll16(gRL0 + k0, &RLS[lb0]); gll16(gRL1 + k0, &RLS[lb1]);
    gll16(gIH0 + k0, &IHS[lb0]); gll16(gIH1 + k0, &IHS[lb1]);
    gll16(gIL0 + k0, &ILS[lb0]); gll16(gIL1 + k0, &ILS[lb1]);
    __syncthreads();
    bf8 ah[4], rh[4], rl[4], ih[4], il[4];
#pragma unroll
    for (int m = 0; m < 4; ++m) ah[m] = *(const bf8*)&AHS[aoff[m]];
#pragma unroll
    for (int n = 0; n < 4; ++n) {
      rh[n] = *(const bf8*)&RHS[boff[n]];
      rl[n] = *(const bf8*)&RLS[boff[n]];
      ih[n] = *(const bf8*)&IHS[boff[n]];
      il[n] = *(const bf8*)&ILS[boff[n]];
    }
#pragma unroll
    for (int m = 0; m < 4; ++m)
#pragma unroll
      for (int n = 0; n < 4; ++n) {
        are[m][n] = __builtin_amdgcn_mfma_f32_16x16x32_bf16(ah[m], rh[n], are[m][n], 0, 0, 0);
        are[m][n] = __builtin_amdgcn_mfma_f32_16x16x32_bf16(ah[m], rl[n], are[m][n], 0, 0, 0);
        aim[m][n] = __builtin_amdgcn_mfma_f32_16x16x32_bf16(ah[m], ih[n], aim[m][n], 0, 0, 0);
        aim[m][n] = __builtin_amdgcn_mfma_f32_16x16x32_bf16(ah[m], il[n], aim[m][n], 0, 0, 0);
      }
  }

  float s[4];
#pragma unroll
  for (int n = 0; n < 4; ++n) {
    float acc = 0.f;
#pragma unroll
    for (int m = 0; m < 4; ++m)
#pragma unroll
      for (int r = 0; r < 4; ++r) {
        float re = are[m][n][r], im = aim[m][n][r];
        acc += __builtin_amdgcn_sqrtf(re * re + im * im);
      }
    acc += __shfl_xor(acc, 16);
    acc += __shfl_xor(acc, 32);
    s[n] = acc;
  }
  if (fs == 0) {
#pragma unroll
    for (int n = 0; n < 4; ++n) colpart[wr][wc * 64 + n * 16 + fr] = s[n];
  }
  __syncthreads();
  if (tid < 128) {
    int k = bn + tid;
    if (k < NBIN_) fpart[(size_t)k * NMT_ + mtile] = colpart[0][tid] + colpart[1][tid];
  }
}

// ---------------- reduce -> freq (all-b) and fsumb (per-b) ----------------
__global__ __launch_bounds__(256) void k_fred(const float* __restrict__ fpart,
                                              float* __restrict__ freq,
                                              float* __restrict__ fsumb) {
  int k = blockIdx.x;
  int tid = threadIdx.x;
  int b = tid >> 3, j = tid & 7;   // 8 lanes per batch, 44 values each batch
  float s = 0.f;
  for (int i = j; i < 44; i += 8) s += fpart[(size_t)k * NMT_ + b * 44 + i];
  for (int off = 4; off > 0; off >>= 1) s += __shfl_xor(s, off);
  __shared__ float bs[32];
  if (j == 0) bs[b] = s;
  __syncthreads();
  if (tid < 32) {
    float v = bs[tid];
    fsumb[k * 32 + tid] = v;
    for (int off = 16; off > 0; off >>= 1) v += __shfl_xor(v, off);
    if (tid == 0) freq[k] = v;
  }
}

// ---------------- top-k + meta + sw softmax (fused) ----------------
__global__ void k_topk(const float* __restrict__ freq, const float* __restrict__ fsumb,
                       int* __restrict__ meta, float* __restrict__ swb) {
  __shared__ int stop[3];
  int tid = threadIdx.x;
  if (tid == 0) {
    float bv[3] = {-1e30f, -1e30f, -1e30f};
    int bi[3] = {1, 1, 1};
    for (int k = 1; k < NBIN_; ++k) {
      float v = freq[k];
      if (v > bv[0]) { bv[2]=bv[1]; bi[2]=bi[1]; bv[1]=bv[0]; bi[1]=bi[0]; bv[0]=v; bi[0]=k; }
      else if (v > bv[1]) { bv[2]=bv[1]; bi[2]=bi[1]; bv[1]=v; bi[1]=k; }
      else if (v > bv[2]) { bv[2]=v; bi[2]=k; }
    }
    for (int i = 0; i < 3; ++i) {
      int top = bi[i];
      int p = T_ / top;
      int L = ((T_ + p - 1) / p) * p;
      meta[i] = top;
      meta[3 + i] = p;
      meta[6 + i] = L;
      meta[9 + i] = L / p;
      meta[15 + i] = B_ * L;   // tokens
      stop[i] = top;
    }
  }
  __syncthreads();
  int b = tid;
  if (b < B_) {
    float inv = 1.0f / (float)(NFR_ * N_);
    float m0 = fsumb[stop[0] * 32 + b] * inv;
    float m1 = fsumb[stop[1] * 32 + b] * inv;
    float m2 = fsumb[stop[2] * 32 + b] * inv;
    float mx = fmaxf(m0, fmaxf(m1, m2));
    float e0 = __expf(m0 - mx), e1 = __expf(m1 - mx), e2 = __expf(m2 - mx);
    float s = e0 + e1 + e2;
    swb[b * 4 + 0] = e0 / s; swb[b * 4 + 1] = e1 / s; swb[b * 4 + 2] = e2 / s;
  }
}

// ---------------- fused adjacency + GCN operator prep ----------------
__global__ __launch_bounds__(1024) void k_adjprep(const float* __restrict__ nv1,
                                                  const float* __restrict__ nv2,
                                                  const float* __restrict__ mw,
                                                  const float* __restrict__ mb,
                                                  const float* __restrict__ sb,
                                                  float* __restrict__ P12,
                                                  float* __restrict__ beff) {
  __shared__ float A32s[32][32];
  __shared__ float Ms[32][32], P1s[32][32], P2s[32][32], S1[32], S2[32], sbl[32];
  int tid = threadIdx.x;
  if (tid < 32) {
    int v = tid;
    float row[32];
    for (int w = 0; w < 32; ++w) {
      float s = 0.f;
      for (int d = 0; d < 10; ++d) s += nv1[v * 10 + d] * nv2[d * 32 + w];
      row[w] = fmaxf(s, 0.f);
    }
    float mx = -1e30f;
    for (int w = 0; w < 32; ++w) mx = fmaxf(mx, row[w]);
    float sm = 0.f;
    for (int w = 0; w < 32; ++w) { row[w] = expf(row[w] - mx); sm += row[w]; }
    for (int w = 0; w < 32; ++w) row[w] /= sm;
    row[v] += 1.0f;
    float rs = 0.f;
    for (int w = 0; w < 32; ++w) rs += row[w];
    for (int w = 0; w < 32; ++w) A32s[v][w] = row[w] / rs;
    sbl[tid] = sb[tid];
  }
  __syncthreads();
  int w = tid >> 5, v = tid & 31;
  Ms[w][v] = A32s[v][w];
  __syncthreads();
  float p1 = 0.95f * Ms[w][v] + (w == v ? 0.05f : 0.f);
  P1s[w][v] = p1;
  __syncthreads();
  float p2 = 0.f;
  for (int u = 0; u < 32; ++u) p2 += P1s[w][u] * Ms[u][v];
  p2 = 0.95f * p2 + (w == v ? 0.05f : 0.f);
  P2s[w][v] = p2;
  P12[tid] = p1;
  P12[1024 + tid] = p2;
  __syncthreads();
  if (tid < 32) {
    float s1 = 0.f, s2 = 0.f;
    for (int u = 0; u < 32; ++u) { s1 += P1s[u][tid]; s2 += P2s[u][tid]; }
    S1[tid] = s1; S2[tid] = s2;
  }
  __syncthreads();
  int o = w;
  float be = mb[o];
  for (int c = 0; c < 32; ++c) {
    float sc = sbl[c];
    be += mw[o * 96 + c] * sc;
    be += mw[o * 96 + 32 + c] * sc * S1[v];
    be += mw[o * 96 + 64 + c] * sc * S2[v];
  }
  beff[tid] = be;
}

// ---------------- build T [1024][1024]: T[(o,v)][(c,w)] ----------------
__global__ __launch_bounds__(256) void k_T(const float* __restrict__ P12,
                                           const float* __restrict__ mw,
                                           float* __restrict__ Tm) {
  int idx = blockIdx.x * 256 + threadIdx.x;
  int r = idx >> 10, k2 = idx & 1023;
  int o = r >> 5, v = r & 31;
  int c = k2 >> 5, w = k2 & 31;
  float t = mw[o * 96 + 32 + c] * P12[w * 32 + v]
          + mw[o * 96 + 64 + c] * P12[1024 + w * 32 + v];
  if (w == v) t += mw[o * 96 + c];
  Tm[idx] = t;
}

// ---------------- build WdT hi: WdT[j][(c,w)] = sw[c][j-w] ----------------
__global__ void k_wdh(const float* __restrict__ swi, unsigned short* __restrict__ WH) {
  int idx = blockIdx.x * 256 + threadIdx.x;   // 512*1024
  int j = idx >> 10, k2 = idx & 1023;
  int c = k2 >> 5, w = k2 & 31;
  int kk = j - w;
  float vv = (kk >= 0 && kk < KH_) ? swi[c * KH_ + kk] : 0.f;
  WH[idx] = f2bf(vv);
}

// ---------------- weight hi split ----------------
__global__ void k_splith(const float* __restrict__ src, unsigned short* __restrict__ Hi,
                         int n) {
  int i = blockIdx.x * 256 + threadIdx.x;
  if (i * 4 >= n) return;
  float4 v = *(const float4*)&src[i * 4];
  ushort4 h;
  h.x = f2bf(v.x); h.y = f2bf(v.y); h.z = f2bf(v.z); h.w = f2bf(v.w);
  *(ushort4*)&Hi[i * 4] = h;
}

// ---------------- 2-MFMA GEMM (fp32 A hi/lo; bf16 weight hi; fold GEMM only) ----------------
__global__ __launch_bounds__(256, 2) void k_mm2(
    const float* __restrict__ A, const unsigned short* __restrict__ Bh,
    const float* __restrict__ bias,
    float* __restrict__ C, float* __restrict__ Cpart,
    int M, int N, int K, int lda, int dogelu) {
  const int bm = blockIdx.y * 128;
  if (bm >= M) return;
  const int bn = blockIdx.x * 128;
  const int nz = gridDim.z, z = blockIdx.z;
  const int kpb = K / nz;
  const int kbeg = z * kpb, kend = kbeg + kpb;

  __shared__ __align__(16) unsigned short AhS[4096], AlS[4096], BhS[4096];

  const int tid = threadIdx.x;
  const int wave = tid >> 6, lane = tid & 63;
  const int wr = wave >> 1, wc = wave & 1;
  const int fr = lane & 15, fs = lane >> 4;

  const int sr = tid >> 1, ss = (tid & 1) * 2;
  const int sx = (sr >> 1) & 3;
  const int so0 = sr * 32 + 8 * (ss ^ sx);
  const int so1 = sr * 32 + 8 * ((ss + 1) ^ sx);

  const int row0 = tid >> 2;
  const int s0 = (tid & 3) ^ ((row0 >> 1) & 3);
  const unsigned short* gBh0 = Bh + (size_t)(bn + row0) * K + s0 * 8;
  const unsigned short* gBh1 = gBh0 + (size_t)64 * K;
  unsigned short* lB0 = &BhS[wave * 512];
  unsigned short* lB1 = &BhS[2048 + wave * 512];

  int aoff[4], boff[4];
#pragma unroll
  for (int m = 0; m < 4; ++m) {
    int ra = wr * 64 + m * 16 + fr;
    aoff[m] = ra * 32 + 8 * (fs ^ ((ra >> 1) & 3));
    int rb = wc * 64 + m * 16 + fr;
    boff[m] = rb * 32 + 8 * (fs ^ ((rb >> 1) & 3));
  }

  const bool aok = (bm + sr) < M;
  const float* Arow = A + (size_t)(bm + sr) * lda + ss * 8;

  f32x4 acc[4][4];
#pragma unroll
  for (int m = 0; m < 4; ++m)
#pragma unroll
    for (int n = 0; n < 4; ++n) acc[m][n] = (f32x4){0.f, 0.f, 0.f, 0.f};

  for (int k0 = kbeg; k0 < kend; k0 += 32) {
    float4 a0, a1, a2, a3;
    if (aok) {
      const float4* p = (const float4*)(Arow + k0);
      a0 = p[0]; a1 = p[1]; a2 = p[2]; a3 = p[3];
    } else {
      a0 = a1 = a2 = a3 = make_float4(0.f, 0.f, 0.f, 0.f);
    }
    float av[16];
    av[0]=a0.x; av[1]=a0.y; av[2]=a0.z; av[3]=a0.w;
    av[4]=a1.x; av[5]=a1.y; av[6]=a1.z; av[7]=a1.w;
    av[8]=a2.x; av[9]=a2.y; av[10]=a2.z; av[11]=a2.w;
    av[12]=a3.x; av[13]=a3.y; av[14]=a3.z; av[15]=a3.w;
    u16x8 h0, h1, l0, l1;
#pragma unroll
    for (int j = 0; j < 8; ++j) {
      unsigned u = __float_as_uint(av[j]);
      h0[j] = (unsigned short)(u >> 16);
      float r2 = av[j] - __uint_as_float(u & 0xffff0000u);
      l0[j] = (unsigned short)(__float_as_uint(r2) >> 16);
      unsigned u2 = __float_as_uint(av[j + 8]);
      h1[j] = (unsigned short)(u2 >> 16);
      float r3 = av[j + 8] - __uint_as_float(u2 & 0xffff0000u);
      l1[j] = (unsigned short)(__float_as_uint(r3) >> 16);
    }
    __syncthreads();   // prior frag reads done
    gll16(gBh0 + k0, lB0); gll16(gBh1 + k0, lB1);
    *(u16x8*)&AhS[so0] = h0; *(u16x8*)&AhS[so1] = h1;
    *(u16x8*)&AlS[so0] = l0; *(u16x8*)&AlS[so1] = l1;
    __syncthreads();   // drains vmcnt + lgkm
    bf8 ah[4], al4[4], bh4[4];
#pragma unroll
    for (int m = 0; m < 4; ++m) {
      ah[m]  = *(const bf8*)&AhS[aoff[m]];
      al4[m] = *(const bf8*)&AlS[aoff[m]];
    }
#pragma unroll
    for (int n = 0; n < 4; ++n) bh4[n] = *(const bf8*)&BhS[boff[n]];
#pragma unroll
    for (int m = 0; m < 4; ++m)
#pragma unroll
      for (int n = 0; n < 4; ++n) {
        acc[m][n] = __builtin_amdgcn_mfma_f32_16x16x32_bf16(ah[m],  bh4[n], acc[m][n], 0, 0, 0);
        acc[m][n] = __builtin_amdgcn_mfma_f32_16x16x32_bf16(al4[m], bh4[n], acc[m][n], 0, 0, 0);
      }
  }

  if (nz > 1) {
    float* P = Cpart + (size_t)z * M * N;
#pragma unroll
    for (int m = 0; m < 4; ++m)
#pragma unroll
      for (int r = 0; r < 4; ++r) {
        int row = bm + wr * 64 + m * 16 + fs * 4 + r;
        if (row < M) {
#pragma unroll
          for (int n = 0; n < 4; ++n) {
            int col = bn + wc * 64 + n * 16 + fr;
            P[(size_t)row * N + col] = acc[m][n][r];
          }
        }
      }
  } else {
    float bcol[4];
#pragma unroll
    for (int n = 0; n < 4; ++n) bcol[n] = bias ? bias[bn + wc * 64 + n * 16 + fr] : 0.f;
#pragma unroll
    for (int m = 0; m < 4; ++m)
#pragma unroll
      for (int r = 0; r < 4; ++r) {
        int row = bm + wr * 64 + m * 16 + fs * 4 + r;
        if (row < M) {
#pragma unroll
          for (int n = 0; n < 4; ++n) {
            int col = bn + wc * 64 + n * 16 + fr;
            float v = acc[m][n][r] + bcol[n];
            if (dogelu) v = gelu_exact(v);
            C[(size_t)row * N + col] = v;
          }
        }
      }
  }
}

// ---------------- conv GEMM: fp32 A hi-only, 1 MFMA, bf16 output + gelu ----------------
__global__ __launch_bounds__(256, 4) void k_mmcv(
    const float* __restrict__ A, const unsigned short* __restrict__ Bh,
    const float* __restrict__ bias,
    unsigned short* __restrict__ C,
    int M, int N, int K, int lda) {
  const int bm = blockIdx.y * 128;
  const int bn = blockIdx.x * 128;

  __shared__ __align__(16) unsigned short AhS[4096], BhS[4096];

  const int tid = threadIdx.x;
  const int wave = tid >> 6, lane = tid & 63;
  const int wr = wave >> 1, wc = wave & 1;
  const int fr = lane & 15, fs = lane >> 4;

  const int sr = tid >> 1, ss = (tid & 1) * 2;
  const int sx = (sr >> 1) & 3;
  const int so0 = sr * 32 + 8 * (ss ^ sx);
  const int so1 = sr * 32 + 8 * ((ss + 1) ^ sx);

  const int row0 = tid >> 2;
  const int s0 = (tid & 3) ^ ((row0 >> 1) & 3);
  const unsigned short* gBh0 = Bh + (size_t)(bn + row0) * K + s0 * 8;
  const unsigned short* gBh1 = gBh0 + (size_t)64 * K;
  unsigned short* lB0 = &BhS[wave * 512];
  unsigned short* lB1 = &BhS[2048 + wave * 512];

  int aoff[4], boff[4];
#pragma unroll
  for (int m = 0; m < 4; ++m) {
    int ra = wr * 64 + m * 16 + fr;
    aoff[m] = ra * 32 + 8 * (fs ^ ((ra >> 1) & 3));
    int rb = wc * 64 + m * 16 + fr;
    boff[m] = rb * 32 + 8 * (fs ^ ((rb >> 1) & 3));
  }

  const float* Arow = A + (size_t)(bm + sr) * lda + ss * 8;

  f32x4 acc[4][4];
#pragma unroll
  for (int m = 0; m < 4; ++m)
#pragma unroll
    for (int n = 0; n < 4; ++n) acc[m][n] = (f32x4){0.f, 0.f, 0.f, 0.f};

  for (int k0 = 0; k0 < K; k0 += 32) {
    const float4* p = (const float4*)(Arow + k0);
    float4 a0 = p[0], a1 = p[1], a2 = p[2], a3 = p[3];
    u16x8 h0, h1;
    h0[0]=f2bf(a0.x); h0[1]=f2bf(a0.y); h0[2]=f2bf(a0.z); h0[3]=f2bf(a0.w);
    h0[4]=f2bf(a1.x); h0[5]=f2bf(a1.y); h0[6]=f2bf(a1.z); h0[7]=f2bf(a1.w);
    h1[0]=f2bf(a2.x); h1[1]=f2bf(a2.y); h1[2]=f2bf(a2.z); h1[3]=f2bf(a2.w);
    h1[4]=f2bf(a3.x); h1[5]=f2bf(a3.y); h1[6]=f2bf(a3.z); h1[7]=f2bf(a3.w);
    __syncthreads();   // prior frag reads done
    gll16(gBh0 + k0, lB0); gll16(gBh1 + k0, lB1);
    *(u16x8*)&AhS[so0] = h0; *(u16x8*)&AhS[so1] = h1;
    __syncthreads();   // drains vmcnt + lgkm
    bf8 ah[4], bh4[4];
#pragma unroll
    for (int m = 0; m < 4; ++m) ah[m] = *(const bf8*)&AhS[aoff[m]];
#pragma unroll
    for (int n = 0; n < 4; ++n) bh4[n] = *(const bf8*)&BhS[boff[n]];
#pragma unroll
    for (int m = 0; m < 4; ++m)
#pragma unroll
      for (int n = 0; n < 4; ++n)
        acc[m][n] = __builtin_amdgcn_mfma_f32_16x16x32_bf16(ah[m], bh4[n], acc[m][n], 0, 0, 0);
  }

  float bcol[4];
#pragma unroll
  for (int n = 0; n < 4; ++n) bcol[n] = bias[bn + wc * 64 + n * 16 + fr];
#pragma unroll
  for (int m = 0; m < 4; ++m)
#pragma unroll
    for (int r = 0; r < 4; ++r) {
      int row = bm + wr * 64 + m * 16 + fs * 4 + r;
#pragma unroll
      for (int n = 0; n < 4; ++n) {
        int col = bn + wc * 64 + n * 16 + fr;
        C[(size_t)row * N + col] = f2bf(gelu_exact(acc[m][n][r] + bcol[n]));
      }
    }
}

// ---------------- end GEMM: bf16 A, bf16 B, 1 MFMA, split-K partials ----------------
__global__ __launch_bounds__(256, 4) void k_mmend(
    const unsigned short* __restrict__ Ah, const unsigned short* __restrict__ Bh,
    float* __restrict__ Cpart, int M, int N, int K) {
  const int bm = blockIdx.y * 128;
  const int bn = blockIdx.x * 128;
  const int nz = gridDim.z, z = blockIdx.z;
  const int kpb = K / nz;
  const int kbeg = z * kpb, kend = kbeg + kpb;

  __shared__ __align__(16) unsigned short AhS[4096], BhS[4096];

  const int tid = threadIdx.x;
  const int wave = tid >> 6, lane = tid & 63;
  const int wr = wave >> 1, wc = wave & 1;
  const int fr = lane & 15, fs = lane >> 4;

  const int row0 = tid >> 2;
  const int s0 = (tid & 3) ^ ((row0 >> 1) & 3);
  const unsigned short* gAh0 = Ah + (size_t)(bm + row0) * K + s0 * 8;
  const unsigned short* gAh1 = gAh0 + (size_t)64 * K;
  const unsigned short* gBh0 = Bh + (size_t)(bn + row0) * K + s0 * 8;
  const unsigned short* gBh1 = gBh0 + (size_t)64 * K;
  const int lb0 = wave * 512, lb1 = 2048 + wave * 512;

  int aoff[4], boff[4];
#pragma unroll
  for (int m = 0; m < 4; ++m) {
    int ra = wr * 64 + m * 16 + fr;
    aoff[m] = ra * 32 + 8 * (fs ^ ((ra >> 1) & 3));
    int rb = wc * 64 + m * 16 + fr;
    boff[m] = rb * 32 + 8 * (fs ^ ((rb >> 1) & 3));
  }

  f32x4 acc[4][4];
#pragma unroll
  for (int m = 0; m < 4; ++m)
#pragma unroll
    for (int n = 0; n < 4; ++n) acc[m][n] = (f32x4){0.f, 0.f, 0.f, 0.f};

  for (int k0 = kbeg; k0 < kend; k0 += 32) {
    __syncthreads();
    gll16(gAh0 + k0, &AhS[lb0]); gll16(gAh1 + k0, &AhS[lb1]);
    gll16(gBh0 + k0, &BhS[lb0]); gll16(gBh1 + k0, &BhS[lb1]);
    __syncthreads();
    bf8 ah[4], bh4[4];
#pragma unroll
    for (int m = 0; m < 4; ++m) ah[m] = *(const bf8*)&AhS[aoff[m]];
#pragma unroll
    for (int n = 0; n < 4; ++n) bh4[n] = *(const bf8*)&BhS[boff[n]];
#pragma unroll
    for (int m = 0; m < 4; ++m)
#pragma unroll
      for (int n = 0; n < 4; ++n)
        acc[m][n] = __builtin_amdgcn_mfma_f32_16x16x32_bf16(ah[m], bh4[n], acc[m][n], 0, 0, 0);
  }

  float* P = Cpart + (size_t)z * M * N;
#pragma unroll
  for (int m = 0; m < 4; ++m)
#pragma unroll
    for (int r = 0; r < 4; ++r) {
      int row = bm + wr * 64 + m * 16 + fs * 4 + r;
#pragma unroll
      for (int n = 0; n < 4; ++n) {
        int col = bn + wc * 64 + n * 16 + fr;
        P[(size_t)row * N + col] = acc[m][n][r];
      }
    }
}

// ---------------- 1-MFMA plane GEMM (attention pipeline; optional lo write) ----------------
__global__ __launch_bounds__(256, 4) void k_mmb1(
    const unsigned short* __restrict__ Ah,
    const unsigned short* __restrict__ Bh,
    const float* __restrict__ bias,
    unsigned short* __restrict__ Ch, unsigned short* __restrict__ Cl,
    int M, int N, int K, const int* __restrict__ Mdyn, int dogelu) {
  if (Mdyn) M = *Mdyn;
  const int bm = blockIdx.y * 128;
  if (bm >= M) return;
  const int bn = blockIdx.x * 128;

  __shared__ __align__(16) unsigned short AhS[4096], BhS[4096];

  const int tid = threadIdx.x;
  const int wave = tid >> 6, lane = tid & 63;
  const int wr = wave >> 1, wc = wave & 1;
  const int fr = lane & 15, fs = lane >> 4;

  const int row0 = tid >> 2;
  const int s0 = (tid & 3) ^ ((row0 >> 1) & 3);
  const unsigned short* gAh0 = Ah + (size_t)(bm + row0) * K + s0 * 8;
  const unsigned short* gAh1 = gAh0 + (size_t)64 * K;
  const unsigned short* gBh0 = Bh + (size_t)(bn + row0) * K + s0 * 8;
  const unsigned short* gBh1 = gBh0 + (size_t)64 * K;
  const int lb0 = wave * 512, lb1 = 2048 + wave * 512;

  int aoff[4], boff[4];
#pragma unroll
  for (int m = 0; m < 4; ++m) {
    int ra = wr * 64 + m * 16 + fr;
    aoff[m] = ra * 32 + 8 * (fs ^ ((ra >> 1) & 3));
    int rb = wc * 64 + m * 16 + fr;
    boff[m] = rb * 32 + 8 * (fs ^ ((rb >> 1) & 3));
  }

  f32x4 acc[4][4];
#pragma unroll
  for (int m = 0; m < 4; ++m)
#pragma unroll
    for (int n = 0; n < 4; ++n) acc[m][n] = (f32x4){0.f, 0.f, 0.f, 0.f};

  for (int k0 = 0; k0 < K; k0 += 32) {
    __syncthreads();
    gll16(gAh0 + k0, &AhS[lb0]); gll16(gAh1 + k0, &AhS[lb1]);
    gll16(gBh0 + k0, &BhS[lb0]); gll16(gBh1 + k0, &BhS[lb1]);
    __syncthreads();
    bf8 ah[4], bh4[4];
#pragma unroll
    for (int m = 0; m < 4; ++m) ah[m] = *(const bf8*)&AhS[aoff[m]];
#pragma unroll
    for (int n = 0; n < 4; ++n) bh4[n] = *(const bf8*)&BhS[boff[n]];
#pragma unroll
    for (int m = 0; m < 4; ++m)
#pragma unroll
      for (int n = 0; n < 4; ++n)
        acc[m][n] = __builtin_amdgcn_mfma_f32_16x16x32_bf16(ah[m], bh4[n], acc[m][n], 0, 0, 0);
  }

  float bcol[4];
#pragma unroll
  for (int n = 0; n < 4; ++n) bcol[n] = bias[bn + wc * 64 + n * 16 + fr];
#pragma unroll
  for (int m = 0; m < 4; ++m)
#pragma unroll
    for (int r = 0; r < 4; ++r) {
      int row = bm + wr * 64 + m * 16 + fs * 4 + r;
      if (row < M) {
#pragma unroll
        for (int n = 0; n < 4; ++n) {
          int col = bn + wc * 64 + n * 16 + fr;
          float v = acc[m][n][r] + bcol[n];
          if (dogelu) v = gelu_exact(v);
          size_t o = (size_t)row * N + col;
          unsigned short h = f2bf(v);
          Ch[o] = h;
          if (Cl) Cl[o] = f2bf(v - bf2f(h));
        }
      }
    }
}

// ---------------- fused QKV GEMM: B=[1536][512] hi; dest selected per n-tile ----------------
__global__ __launch_bounds__(256, 4) void k_mmqkv(
    const unsigned short* __restrict__ Ah,
    const unsigned short* __restrict__ Bh,
    const float* __restrict__ bq, const float* __restrict__ bk,
    const float* __restrict__ bv,
    unsigned short* __restrict__ Qh, unsigned short* __restrict__ Kh,
    unsigned short* __restrict__ Vh,
    int M, int K, const int* __restrict__ Mdyn) {
  if (Mdyn) M = *Mdyn;
  const int bm = blockIdx.y * 128;
  if (bm >= M) return;
  const int bn = blockIdx.x * 128;   // in [0,1536)
  const int sel = bn >> 9;
  unsigned short* Ch = sel == 0 ? Qh : (sel == 1 ? Kh : Vh);
  const float* bias = sel == 0 ? bq : (sel == 1 ? bk : bv);
  const int cb = bn & 511;

  __shared__ __align__(16) unsigned short AhS[4096], BhS[4096];

  const int tid = threadIdx.x;
  const int wave = tid >> 6, lane = tid & 63;
  const int wr = wave >> 1, wc = wave & 1;
  const int fr = lane & 15, fs = lane >> 4;

  const int row0 = tid >> 2;
  const int s0 = (tid & 3) ^ ((row0 >> 1) & 3);
  const unsigned short* gAh0 = Ah + (size_t)(bm + row0) * K + s0 * 8;
  const unsigned short* gAh1 = gAh0 + (size_t)64 * K;
  const unsigned short* gBh0 = Bh + (size_t)(bn + row0) * K + s0 * 8;
  const unsigned short* gBh1 = gBh0 + (size_t)64 * K;
  const int lb0 = wave * 512, lb1 = 2048 + wave * 512;

  int aoff[4], boff[4];
#pragma unroll
  for (int m = 0; m < 4; ++m) {
    int ra = wr * 64 + m * 16 + fr;
    aoff[m] = ra * 32 + 8 * (fs ^ ((ra >> 1) & 3));
    int rb = wc * 64 + m * 16 + fr;
    boff[m] = rb * 32 + 8 * (fs ^ ((rb >> 1) & 3));
  }

  f32x4 acc[4][4];
#pragma unroll
  for (int m = 0; m < 4; ++m)
#pragma unroll
    for (int n = 0; n < 4; ++n) acc[m][n] = (f32x4){0.f, 0.f, 0.f, 0.f};

  for (int k0 = 0; k0 < K; k0 += 32) {
    __syncthreads();
    gll16(gAh0 + k0, &AhS[lb0]); gll16(gAh1 + k0, &AhS[lb1]);
    gll16(gBh0 + k0, &BhS[lb0]); gll16(gBh1 + k0, &BhS[lb1]);
    __syncthreads();
    bf8 ah[4], bh4[4];
#pragma unroll
    for (int m = 0; m < 4; ++m) ah[m] = *(const bf8*)&AhS[aoff[m]];
#pragma unroll
    for (int n = 0; n < 4; ++n) bh4[n] = *(const bf8*)&BhS[boff[n]];
#pragma unroll
    for (int m = 0; m < 4; ++m)
#pragma unroll
      for (int n = 0; n < 4; ++n)
        acc[m][n] = __builtin_amdgcn_mfma_f32_16x16x32_bf16(ah[m], bh4[n], acc[m][n], 0, 0, 0);
  }

  float bcol[4];
#pragma unroll
  for (int n = 0; n < 4; ++n) bcol[n] = bias[cb + wc * 64 + n * 16 + fr];
#pragma unroll
  for (int m = 0; m < 4; ++m)
#pragma unroll
    for (int r = 0; r < 4; ++r) {
      int row = bm + wr * 64 + m * 16 + fs * 4 + r;
      if (row < M) {
#pragma unroll
        for (int n = 0; n < 4; ++n) {
          int col = cb + wc * 64 + n * 16 + fr;
          Ch[(size_t)row * 512 + col] = f2bf(acc[m][n][r] + bcol[n]);
        }
      }
    }
}

// ---------------- split-K reduce 16 (+bias) ----------------
__global__ void k_red16(const float* __restrict__ part, const float* __restrict__ eb,
                        float* __restrict__ dst) {
  int idx = blockIdx.x * 256 + threadIdx.x;   // 1024*512
  float s = eb ? eb[idx & 511] : 0.f;
#pragma unroll
  for (int zz = 0; zz < 16; ++zz) s += part[(size_t)zz * 524288 + idx];
  dst[idx] = s;
}

// ---------------- split-K reduce 8 -> bf16 hi (W' fold) ----------------
__global__ void k_redsplit(const float* __restrict__ part, unsigned short* __restrict__ WH) {
  int idx = blockIdx.x * 256 + threadIdx.x;   // 1024*512
  float s = 0.f;
#pragma unroll
  for (int zz = 0; zz < 8; ++zz) s += part[(size_t)zz * 524288 + idx];
  WH[idx] = f2bf(s);
}

// ---------------- bf16 repack G[(b,s),(c,n)] -> G2[(b,n),(c,s)] ----------------
__global__ __launch_bounds__(256) void k_repackb(const unsigned short* __restrict__ G,
                                                 unsigned short* __restrict__ G2) {
  int bid = blockIdx.x;
  int st = bid & 15, c = (bid >> 4) & 31, b = bid >> 9;
  __shared__ unsigned short tile[32][34];
  int tid = threadIdx.x;
  int n = tid & 31, s = tid >> 5;
  for (int q = 0; q < 4; ++q) {
    int ss = s + q * 8;
    tile[ss][n] = G[((size_t)b * T_ + st * 32 + ss) * 1024 + c * 32 + n];
  }
  __syncthreads();
  int s2 = tid & 31, n2 = tid >> 5;
  for (int q = 0; q < 4; ++q) {
    int nn = n2 + q * 8;
    G2[((size_t)b * 32 + nn) * 16384 + c * 512 + st * 32 + s2] = tile[s2][nn];
  }
}

// ---------------- lw projection + residual + LN -> cur fp32 AND A0 planes ----------------
__global__ __launch_bounds__(256) void k_lwln(const float* __restrict__ osm,
                                              const float* __restrict__ lw,
                                              const float* __restrict__ lb,
                                              const float* __restrict__ curIn,
                                              const float* __restrict__ g,
                                              const float* __restrict__ bt,
                                              float* __restrict__ curOut,
                                              unsigned short* __restrict__ xh,
                                              unsigned short* __restrict__ xl,
                                              const int* __restrict__ meta, int iter) {
  int tok = blockIdx.x;
  int b = tok >> 9, t = tok & 511;
  __shared__ float os[C_];
  __shared__ float red[256];
  int tid = threadIdx.x;
  if (tid < C_) os[tid] = osm[((size_t)b * C_ + tid) * T_ + t];
  __syncthreads();
  float val[2];
#pragma unroll
  for (int q = 0; q < 2; ++q) {
    int m = tid + q * 256;
    float s = lb[m] + curIn[(size_t)tok * N_ + m];
    for (int n2 = 0; n2 < C_; ++n2) s += os[n2] * lw[n2 * N_ + m];
    val[q] = s;
  }
  red[tid] = val[0] + val[1];
  __syncthreads();
  for (int off = 128; off > 0; off >>= 1) { if (tid < off) red[tid] += red[tid + off]; __syncthreads(); }
  float mean = red[0] * (1.0f / N_);
  __syncthreads();
  float d0 = val[0] - mean, d1 = val[1] - mean;
  red[tid] = d0 * d0 + d1 * d1;
  __syncthreads();
  for (int off = 128; off > 0; off >>= 1) { if (tid < off) red[tid] += red[tid + off]; __syncthreads(); }
  float inv = rsqrtf(red[0] * (1.0f / N_) + EPS_);
  float o0 = d0 * inv * g[tid] + bt[tid];
  float o1 = d1 * inv * g[tid + 256] + bt[tid + 256];
  curOut[(size_t)tok * N_ + tid] = o0;
  curOut[(size_t)tok * N_ + tid + 256] = o1;
  int L = meta[6 + iter];
  size_t pi = ((size_t)b * L + t) * N_;
  st2(xh, xl, pi + tid, o0);
  st2(xh, xl, pi + tid + 256, o1);
}

// ---------------- zero pad rows l in [T,L) of A0 planes ----------------
__global__ void k_padtail(unsigned short* __restrict__ xh, unsigned short* __restrict__ xl,
                          const int* __restrict__ meta, int iter) {
  int L = meta[6 + iter];
  int pad = L - T_;
  if (pad <= 0) return;
  size_t total = (size_t)B_ * pad * N_;
  for (size_t idx = (size_t)blockIdx.x * 256 + threadIdx.x; idx < total;
       idx += (size_t)gridDim.x * 256) {
    size_t row = idx >> 9;
    int d = (int)(idx & 511);
    int b = (int)(row / pad), l = T_ + (int)(row % pad);
    size_t o = ((size_t)b * L + l) * N_ + d;
    xh[o] = 0; xl[o] = 0;
  }
}

// ---------------- residual add + LN (planes in, planes out) ----------------
__global__ __launch_bounds__(256) void k_lnadd(const unsigned short* __restrict__ r1h,
                                               const unsigned short* __restrict__ r1l,
                                               const unsigned short* __restrict__ r2h,
                                               const unsigned short* __restrict__ r2l,
                                               const float* __restrict__ g,
                                               const float* __restrict__ bt,
                                               unsigned short* __restrict__ dh,
                                               unsigned short* __restrict__ dl,
                                               const int* __restrict__ meta, int iter) {
  int tokens = meta[15 + iter];
  int tok = blockIdx.x;
  if (tok >= tokens) return;
  __shared__ float red[256];
  int tid = threadIdx.x;
  float val[2];
#pragma unroll
  for (int q = 0; q < 2; ++q) {
    size_t i = (size_t)tok * N_ + tid + q * 256;
    val[q] = ld2(r1h, r1l, i) + ld2(r2h, r2l, i);
  }
  red[tid] = val[0] + val[1];
  __syncthreads();
  for (int off = 128; off > 0; off >>= 1) { if (tid < off) red[tid] += red[tid + off]; __syncthreads(); }
  float mean = red[0] * (1.0f / N_);
  __syncthreads();
  float d0 = val[0] - mean, d1 = val[1] - mean;
  red[tid] = d0 * d0 + d1 * d1;
  __syncthreads();
  for (int off = 128; off > 0; off >>= 1) { if (tid < off) red[tid] += red[tid + off]; __syncthreads(); }
  float inv = rsqrtf(red[0] * (1.0f / N_) + EPS_);
  st2(dh, dl, (size_t)tok * N_ + tid, d0 * inv * g[tid] + bt[tid]);
  st2(dh, dl, (size_t)tok * N_ + tid + 256, d1 * inv * g[tid + 256] + bt[tid + 256]);
}

// ---------------- fused: LN(r1+r2) -> LN -> gelu -> weighted accumulate ----------------
__global__ __launch_bounds__(256) void k_lnfin(const unsigned short* __restrict__ r1h,
                                               const unsigned short* __restrict__ r1l,
                                               const unsigned short* __restrict__ r2h,
                                               const unsigned short* __restrict__ r2l,
                                               const float* __restrict__ g1,
                                               const float* __restrict__ b1,
                                               const float* __restrict__ g2,
                                               const float* __restrict__ b2,
                                               const float* __restrict__ swb,
                                               float* __restrict__ acc,
                                               const int* __restrict__ meta, int iter) {
  int L = meta[6 + iter];
  int tok = blockIdx.x;
  if (tok >= B_ * L) return;
  int b = tok / L, l = tok % L;
  if (l >= T_) return;   // truncated away
  __shared__ float red[256];
  int tid = threadIdx.x;
  float val[2];
#pragma unroll
  for (int q = 0; q < 2; ++q) {
    size_t i = (size_t)tok * N_ + tid + q * 256;
    val[q] = ld2(r1h, r1l, i) + ld2(r2h, r2l, i);
  }
  red[tid] = val[0] + val[1];
  __syncthreads();
  for (int off = 128; off > 0; off >>= 1) { if (tid < off) red[tid] += red[tid + off]; __syncthreads(); }
  float mean = red[0] * (1.0f / N_);
  __syncthreads();
  float d0 = val[0] - mean, d1 = val[1] - mean;
  red[tid] = d0 * d0 + d1 * d1;
  __syncthreads();
  for (int off = 128; off > 0; off >>= 1) { if (tid < off) red[tid] += red[tid + off]; __syncthreads(); }
  float inv = rsqrtf(red[0] * (1.0f / N_) + EPS_);
  float y0 = d0 * inv * g1[tid] + b1[tid];
  float y1 = d1 * inv * g1[tid + 256] + b1[tid + 256];
  // second LN over y
  __syncthreads();
  red[tid] = y0 + y1;
  __syncthreads();
  for (int off = 128; off > 0; off >>= 1) { if (tid < off) red[tid] += red[tid + off]; __syncthreads(); }
  float mean2 = red[0] * (1.0f / N_);
  __syncthreads();
  float e0 = y0 - mean2, e1 = y1 - mean2;
  red[tid] = e0 * e0 + e1 * e1;
  __syncthreads();
  for (int off = 128; off > 0; off >>= 1) { if (tid < off) red[tid] += red[tid + off]; __syncthreads(); }
  float inv2 = rsqrtf(red[0] * (1.0f / N_) + EPS_);
  float s = swb[b * 4 + iter];
  float u0 = gelu_exact(e0 * inv2 * g2[tid] + b2[tid]);
  float u1 = gelu_exact(e1 * inv2 * g2[tid + 256] + b2[tid + 256]);
  size_t o = ((size_t)b * T_ + l) * N_;
  acc[o + tid] += s * u0;
  acc[o + tid + 256] += s * u1;
}

// ---------------- attention S<=32: wave-per-pair, lane=t scores, barrier-free ----------------
// K tile stored as raw bf16 bits (convert on read) -> 34.8KB LDS -> 4 blocks/CU
__global__ __launch_bounds__(256) void k_attn32(
    const unsigned short* __restrict__ qh,
    const unsigned short* __restrict__ kh,
    const unsigned short* __restrict__ vh,
    unsigned short* __restrict__ oh,
    const int* __restrict__ meta, int iter) {
  int S = meta[3 + iter];
  if (S > 32) return;
  int L = meta[6 + iter], nseq = meta[9 + iter];
  int npair = B_ * nseq * 8;
  __shared__ unsigned short Kts[4][64 * 33];
  __shared__ unsigned short Vsh[4][32 * 66];
  __shared__ float qs[4][64];
  int tid = threadIdx.x;
  int wave = tid >> 6, lane = tid & 63;
  unsigned short* Ktw = Kts[wave];
  unsigned short* Vw = Vsh[wave];
  int gw = (blockIdx.x * 256 + tid) >> 6;
  int nw = (gridDim.x * 256) >> 6;
  const int tt = lane & 31;
  const int hf = lane >> 5;
  for (int pair = gw; pair < npair; pair += nw) {
    int h = pair & 7;
    int m = pair >> 3;
    int b = m / nseq, g2 = m - b * nseq;
    size_t base = ((size_t)b * L + (size_t)g2 * S) * N_ + h * 64;
    for (int i = lane; i < S * 64; i += 64) {
      int t = i >> 6, d = i & 63;
      size_t gi = base + (size_t)t * N_ + d;
      Ktw[d * 33 + t] = kh[gi];
      Vw[t * 66 + d] = vh[gi];
    }
    bool tok = tt < S;
    for (int s = 0; s < S; ++s) {
      qs[wave][lane] = bf2f(qh[base + (size_t)s * N_ + lane]);
      float part = 0.f;
      if (tok) {
        const unsigned short* kp = &Ktw[hf * 32 * 33 + tt];
        const float* qp = &qs[wave][hf * 32];
#pragma unroll 8
        for (int j = 0; j < 32; ++j) part += qp[j] * bf2f(kp[j * 33]);
      }
      part += __shfl_xor(part, 32);
      float sc = tok ? part * 0.125f : -3.0e38f;
      float mx = sc;
      for (int off = 16; off > 0; off >>= 1) mx = fmaxf(mx, __shfl_xor(mx, off));
      float p = tok ? __expf(sc - mx) : 0.f;
      float ssum = p;
      for (int off = 16; off > 0; off >>= 1) ssum += __shfl_xor(ssum, off);
      float ov = 0.f;
      for (int t = 0; t < S; ++t) {
        float pt = __shfl(p, t);
        ov += pt * bf2f(Vw[t * 66 + lane]);
      }
      oh[base + (size_t)s * N_ + lane] = f2bf(ov / ssum);
    }
  }
}

// ---------------- MFMA flash attention, 32<S<=128: one block per (seq,head) ----------------
__global__ __launch_bounds__(256, 3) void k_attn_small(
    const unsigned short* __restrict__ qh,
    const unsigned short* __restrict__ kh,
    const unsigned short* __restrict__ vh,
    unsigned short* __restrict__ oh,
    const int* __restrict__ meta, int iter) {
  int S = meta[3 + iter];
  if (S <= 32 || S > 128) return;
  int L = meta[6 + iter], nseq = meta[9 + iter];
  int M = B_ * nseq;
  int mh = blockIdx.x;
  int m0 = mh >> 3, h = mh & 7;
  if (m0 >= M) return;
  int b = m0 / nseq, g2 = m0 % nseq;
  size_t tok0 = (size_t)b * L + (size_t)g2 * S;

  // U: QK phase = {Q kstep0, Q kstep1, K kstep0, K kstep1}; PV phase = P[4 ksteps]
  __shared__ __align__(16) unsigned short U[16384];
  __shared__ __align__(16) unsigned short VT[8192];   // V^T, 4 k-steps [64][32]
  __shared__ float rb1[2][128], rb2[2][128];

  const int tid = threadIdx.x;
  const int wave = tid >> 6, lane = tid & 63;
  const int wr = wave >> 1, wc = wave & 1;
  const int fr = lane & 15, fs = lane >> 4;

  // ---- stage Q,K via global_load_lds (mmb1 pattern, K=64 -> 2 k-steps) ----
  const int row0 = tid >> 2;
  const int s0 = (tid & 3) ^ ((row0 >> 1) & 3);
  const unsigned short* gQ0 = qh + (tok0 + row0) * N_ + h * 64 + s0 * 8;
  const unsigned short* gQ1 = gQ0 + (size_t)64 * N_;
  const unsigned short* gK0 = kh + (tok0 + row0) * N_ + h * 64 + s0 * 8;
  const unsigned short* gK1 = gK0 + (size_t)64 * N_;
  const int lb0 = wave * 512, lb1 = 2048 + wave * 512;
  gll16(gQ0,      &U[lb0]);         gll16(gQ1,      &U[lb1]);
  gll16(gQ0 + 32, &U[4096 + lb0]);  gll16(gQ1 + 32, &U[4096 + lb1]);
  gll16(gK0,      &U[8192 + lb0]);  gll16(gK1,      &U[8192 + lb1]);
  gll16(gK0 + 32, &U[12288 + lb0]); gll16(gK1 + 32, &U[12288 + lb1]);
  // ---- stage V^T via reg transpose into swizzled B layout ----
  for (int i = tid; i < 128 * 8; i += 256) {
    int t = i >> 3, c8 = i & 7;
    u16x8 vv8 = *(const u16x8*)&vh[(tok0 + t) * N_ + h * 64 + c8 * 8];
    int kk = t >> 5, chunk = (t & 31) >> 3, e = t & 7;
#pragma unroll
    for (int q = 0; q < 8; ++q) {
      int d = c8 * 8 + q;
      VT[kk * 2048 + d * 32 + 8 * (chunk ^ ((d >> 1) & 3)) + e] = vv8[q];
    }
  }
  __syncthreads();

  // ---- QK^T: scores[q][k] ----
  int aoff[4], boff[4];
#pragma unroll
  for (int m = 0; m < 4; ++m) {
    int ra = wr * 64 + m * 16 + fr;
    aoff[m] = ra * 32 + 8 * (fs ^ ((ra >> 1) & 3));
    int rb = wc * 64 + m * 16 + fr;
    boff[m] = rb * 32 + 8 * (fs ^ ((rb >> 1) & 3));
  }
  f32x4 acc[4][4];
#pragma unroll
  for (int m = 0; m < 4; ++m)
#pragma unroll
    for (int n = 0; n < 4; ++n) acc[m][n] = (f32x4){0.f, 0.f, 0.f, 0.f};
#pragma unroll
  for (int kk = 0; kk < 2; ++kk) {
    bf8 ah[4], bh[4];
#pragma unroll
    for (int m = 0; m < 4; ++m) ah[m] = *(const bf8*)&U[kk * 4096 + aoff[m]];
#pragma unroll
    for (int n = 0; n < 4; ++n) bh[n] = *(const bf8*)&U[8192 + kk * 4096 + boff[n]];
#pragma unroll
    for (int m = 0; m < 4; ++m)
#pragma unroll
      for (int n = 0; n < 4; ++n)
        acc[m][n] = __builtin_amdgcn_mfma_f32_16x16x32_bf16(ah[m], bh[n], acc[m][n], 0, 0, 0);
  }

  // ---- mask + scale; row-max partials ----
  bool colok[4];
#pragma unroll
  for (int n = 0; n < 4; ++n) colok[n] = (wc * 64 + n * 16 + fr) < S;
#pragma unroll
  for (int m = 0; m < 4; ++m)
#pragma unroll
    for (int n = 0; n < 4; ++n)
#pragma unroll
      for (int r = 0; r < 4; ++r)
        acc[m][n][r] = colok[n] ? acc[m][n][r] * 0.125f : -3.0e38f;
#pragma unroll
  for (int m = 0; m < 4; ++m)
#pragma unroll
    for (int r = 0; r < 4; ++r) {
      float pm = fmaxf(fmaxf(acc[m][0][r], acc[m][1][r]), fmaxf(acc[m][2][r], acc[m][3][r]));
      pm = fmaxf(pm, __shfl_xor(pm, 1));
      pm = fmaxf(pm, __shfl_xor(pm, 2));
      pm = fmaxf(pm, __shfl_xor(pm, 4));
      pm = fmaxf(pm, __shfl_xor(pm, 8));
      if (fr == 0) rb1[wc][wr * 64 + m * 16 + fs * 4 + r] = pm;
    }
  __syncthreads();   // rb1 ready; all U fragment reads complete

  // ---- exp + row-sum partials; scatter P (bf16) into U as PV A-operand ----
#pragma unroll
  for (int m = 0; m < 4; ++m)
#pragma unroll
    for (int r = 0; r < 4; ++r) {
      int row = wr * 64 + m * 16 + fs * 4 + r;
      float mx = fmaxf(rb1[0][row], rb1[1][row]);
      float ps = 0.f;
#pragma unroll
      for (int n = 0; n < 4; ++n) {
        float e = __expf(acc[m][n][r] - mx);
        acc[m][n][r] = e;
        ps += e;
      }
      ps += __shfl_xor(ps, 1);
      ps += __shfl_xor(ps, 2);
      ps += __shfl_xor(ps, 4);
      ps += __shfl_xor(ps, 8);
      if (fr == 0) rb2[wc][row] = ps;
    }
#pragma unroll
  for (int m = 0; m < 4; ++m)
#pragma unroll
    for (int n = 0; n < 4; ++n) {
      int col = wc * 64 + n * 16 + fr;
      int kk = col >> 5, chunk = (col & 31) >> 3, e = col & 7;
#pragma unroll
      for (int r = 0; r < 4; ++r) {
        int row = wr * 64 + m * 16 + fs * 4 + r;
        U[kk * 4096 + row * 32 + 8 * (chunk ^ ((row >> 1) & 3)) + e] = f2bf(acc[m][n][r]);
      }
    }
  __syncthreads();   // P + rb2 ready

  // ---- PV: out[q][d] = sum_t P[q][t] * VT[d][t]; waves split rows (32 each) ----
  int nk = (S + 31) >> 5;
  int aoff2[2], boff2[4];
#pragma unroll
  for (int m = 0; m < 2; ++m) {
    int ra = wave * 32 + m * 16 + fr;
    aoff2[m] = ra * 32 + 8 * (fs ^ ((ra >> 1) & 3));
  }
#pragma unroll
  for (int n = 0; n < 4; ++n) {
    int rb = n * 16 + fr;
    boff2[n] = rb * 32 + 8 * (fs ^ ((rb >> 1) & 3));
  }
  f32x4 o2[2][4];
#pragma unroll
  for (int m = 0; m < 2; ++m)
#pragma unroll
    for (int n = 0; n < 4; ++n) o2[m][n] = (f32x4){0.f, 0.f, 0.f, 0.f};
  for (int kk = 0; kk < nk; ++kk) {
    bf8 pa[2], vb[4];
#pragma unroll
    for (int m = 0; m < 2; ++m) pa[m] = *(const bf8*)&U[kk * 4096 + aoff2[m]];
#pragma unroll
    for (int n = 0; n < 4; ++n) vb[n] = *(const bf8*)&VT[kk * 2048 + boff2[n]];
#pragma unroll
    for (int m = 0; m < 2; ++m)
#pragma unroll
      for (int n = 0; n < 4; ++n)
        o2[m][n] = __builtin_amdgcn_mfma_f32_16x16x32_bf16(pa[m], vb[n], o2[m][n], 0, 0, 0);
  }

  // ---- epilogue: divide by row sums, write ----
#pragma unroll
  for (int m = 0; m < 2; ++m)
#pragma unroll
    for (int r = 0; r < 4; ++r) {
      int orow = wave * 32 + m * 16 + fs * 4 + r;
      if (orow < S) {
        float inv = 1.0f / (rb2[0][orow] + rb2[1][orow]);
#pragma unroll
        for (int n = 0; n < 4; ++n)
          oh[(tok0 + orow) * N_ + h * 64 + n * 16 + fr] = f2bf(o2[m][n][r] * inv);
      }
    }
}

// ---------------- fused attention, 128<S<=512 — barrier-free waves ----------------
__global__ __launch_bounds__(256) void k_attn_big(
    const unsigned short* __restrict__ qh,
    const unsigned short* __restrict__ kh,
    const unsigned short* __restrict__ vh,
    unsigned short* __restrict__ oh,
    const int* __restrict__ meta, int iter) {
  int p = meta[3 + iter];
  if (p <= 128) return;
  int L = meta[6 + iter], nseq = meta[9 + iter];
  int M = B_ * nseq;
  int mh = blockIdx.x;
  int m = mh >> 3, h = mh & 7;
  if (m >= M) return;
  int S = p;
  int b = m / nseq, g2 = m % nseq;
  size_t tok0 = (size_t)b * L + (size_t)g2 * S;
  __shared__ unsigned short Ks[512 * 66];
  __shared__ unsigned short Vs[512 * 66];
  __shared__ float qrow[4][64];
  __shared__ float Pr[4][512];
  int tid = threadIdx.x;
  for (int i = tid; i < S * 64; i += 256) {
    int t = i >> 6, d = i & 63;
    size_t gi = (tok0 + t) * N_ + h * 64 + d;
    Ks[t * 66 + d] = kh[gi];
    Vs[t * 66 + d] = vh[gi];
  }
  __syncthreads();   // only barrier
  int wave = tid >> 6, lane = tid & 63;
  for (int s = wave; s < S; s += 4) {
    qrow[wave][lane] = bf2f(qh[(tok0 + s) * N_ + h * 64 + lane]);
    const float2* qp = (const float2*)&qrow[wave][0];
    float sc[8];
    float mx = -3.0e38f;
#pragma unroll
    for (int c2 = 0; c2 < 8; ++c2) {
      int t = lane + c2 * 64;
      float sv = -3.0e38f;
      if (t < S) {
        const unsigned int* kp = (const unsigned int*)&Ks[t * 66];
        float ad = 0.f;
#pragma unroll
        for (int j2 = 0; j2 < 32; ++j2) {
          float2 qq = qp[j2];
          unsigned int kw = kp[j2];
          ad += qq.x * bf2f((unsigned short)(kw & 0xffffu));
          ad += qq.y * bf2f((unsigned short)(kw >> 16));
        }
        sv = ad * 0.125f;
      }
      sc[c2] = sv;
      mx = fmaxf(mx, sv);
    }
    for (int off = 32; off > 0; off >>= 1) mx = fmaxf(mx, __shfl_xor(mx, off));
    float ssum = 0.f;
#pragma unroll
    for (int c2 = 0; c2 < 8; ++c2) {
      int t = lane + c2 * 64;
      float e = 0.f;
      if (t < S) { e = __expf(sc[c2] - mx); Pr[wave][t] = e; }
      ssum += e;
    }
    for (int off = 32; off > 0; off >>= 1) ssum += __shfl_xor(ssum, off);
    float inv = 1.0f / ssum;
    float ov = 0.f;
#pragma unroll 8
    for (int t = 0; t < S; ++t) ov += Pr[wave][t] * bf2f(Vs[t * 66 + lane]);
    oh[(tok0 + s) * N_ + h * 64 + lane] = f2bf(ov * inv);
  }
}

// ---------------- final output ----------------
__global__ void k_final(const float* __restrict__ acc, const float* __restrict__ cur,
                        float* __restrict__ out) {
  size_t idx = (size_t)blockIdx.x * 256 + threadIdx.x;
  out[idx] = acc[idx] + cur[idx];
}

extern "C" void kernel_launch(void* const* d_in, const int* in_sizes, int n_in,
                              void* d_out, int out_size, void* d_ws, size_t ws_size,
                              hipStream_t stream) {
  (void)in_sizes; (void)n_in; (void)out_size; (void)ws_size;
  const float* x       = (const float*)d_in[0];
  const float* nv1     = (const float*)d_in[1];
  const float* nv2     = (const float*)d_in[2];
  const float* start_w = (const float*)d_in[3];
  const float* start_b = (const float*)d_in[4];
  const float* mix_w   = (const float*)d_in[5];
  const float* mix_b   = (const float*)d_in[6];
  const float* end_w   = (const float*)d_in[7];
  const float* end_b   = (const float*)d_in[8];
  const float* glin_w  = (const float*)d_in[9];
  const float* glin_b  = (const float*)d_in[10];
  const float* gnorm_g = (const float*)d_in[11];
  const float* gnorm_b = (const float*)d_in[12];
  const float* wq = (const float*)d_in[13];
  const float* bq = (const float*)d_in[14];
  const float* wk = (const float*)d_in[15];
  const float* bk = (const float*)d_in[16];
  const float* wv = (const float*)d_in[17];
  const float* bv = (const float*)d_in[18];
  const float* wo = (const float*)d_in[19];
  const float* bo = (const float*)d_in[20];
  const float* ff1w = (const float*)d_in[21];
  const float* ff1b = (const float*)d_in[22];
  const float* ff2w = (const float*)d_in[23];
  const float* ff2b = (const float*)d_in[24];
  const float* an1g = (const float*)d_in[25];
  const float* an1b = (const float*)d_in[26];
  const float* an2g = (const float*)d_in[27];
  const float* an2b = (const float*)d_in[28];
  const float* nrmg = (const float*)d_in[29];
  const float* nrmb = (const float*)d_in[30];

  char* ws = (char*)d_ws;
  int*   meta = (int*)(ws + OFF_META);
  float* freq = (float*)(ws + OFF_FREQ);
  float* swb  = (float*)(ws + OFF_SW);
  float* beff = (float*)(ws + OFF_BEFF);
  float* P12  = (float*)(ws + OFF_P12);
  float* fsumb = (float*)(ws + OFF_FSB);
  float* osm  = (float*)(ws + OFF_OSM);
  unsigned short* TWH = (unsigned short*)(ws + OFF_TWH);
  unsigned short* TWL = (unsigned short*)(ws + OFF_TWL);
  unsigned short* WB  = (unsigned short*)(ws + OFF_WB);
  unsigned short* WdH = (unsigned short*)(ws + OFF_WDH);
  unsigned short* EWH = (unsigned short*)(ws + OFF_EWH);
  float* cur  = (float*)(ws + OFF_CUR);
  float* accb = (float*)(ws + OFF_ACC);
  unsigned short* XWH = (unsigned short*)(ws + OFF_XWH);
  float* fpart = (float*)(ws + OFF_FP);
  float* Tm   = (float*)(ws + OFF_T);
  unsigned short* WPH = (unsigned short*)(ws + OFF_WPH);
  unsigned short* Gb  = (unsigned short*)(ws + OFF_G);
  unsigned short* G2b = (unsigned short*)(ws + OFF_G2);
  float* PART = (float*)(ws + OFF_PART);
  unsigned short* A0h = (unsigned short*)(ws + OFF_A0); unsigned short* A0l = A0h + PLW;
  unsigned short* A2h = (unsigned short*)(ws + OFF_A2); unsigned short* A2l = A2h + PLW;
  unsigned short* A3h = (unsigned short*)(ws + OFF_A3); unsigned short* A3l = A3h + PLW;
  unsigned short* A4h = (unsigned short*)(ws + OFF_A4);
  unsigned short* A5h = (unsigned short*)(ws + OFF_A5); unsigned short* A5l = A5h + PLW;

  hipMemsetAsync(accb, 0, (size_t)B_ * T_ * N_ * 4, stream);

  // ---- STFT via MFMA (window on twiddle side ONLY; x-hi only, twiddles hi+lo) ----
  k_xw<<<B_ * NFR_, 256, 0, stream>>>(x, XWH);
  k_tw<<<(2 * 384 * 64 + 255) / 256, 256, 0, stream>>>(TWH, TWL);
  k_stftmm<<<dim3(3, NMT_), 256, 0, stream>>>(XWH, TWH, TWL, fpart);
  k_fred<<<NBIN_, 256, 0, stream>>>(fpart, freq, fsumb);
  k_topk<<<1, 64, 0, stream>>>(freq, fsumb, meta, swb);

  // split attention/FF weights into bf16 hi planes (once); Q,K,V contiguous
  const float* wlist[6] = {wq, wk, wv, wo, ff1w, ff2w};
  for (int w = 0; w < 6; ++w)
    k_splith<<<256, 256, 0, stream>>>(wlist[w], WB + (size_t)w * 262144, 262144);
  unsigned short* WqkvH = WB;              // [1536][512]
  unsigned short* WoH = WB + 3 * 262144;
  unsigned short* F1H = WB + 4 * 262144;
  unsigned short* F2H = WB + 5 * 262144;

  const float* curIn = x;
  for (int i = 0; i < 3; ++i) {
    // ---- graph block: fold conv+GCN+mix into one weight W' = T @ Wd ----
    k_adjprep<<<1, 1024, 0, stream>>>(nv1 + i * C_ * 10, nv2 + i * 10 * C_,
                                      mix_w + i * C_ * 96, mix_b + i * C_,
                                      start_b + i * C_, P12, beff);
    k_T<<<4096, 256, 0, stream>>>(P12, mix_w + i * C_ * 96, Tm);
    k_wdh<<<2048, 256, 0, stream>>>(start_w + i * C_ * KH_, WdH);
    k_mm2<<<dim3(4, 8, 8), 256, 0, stream>>>(Tm, WdH, nullptr, nullptr, PART,
                                             1024, 512, 1024, 1024, 0);
    k_redsplit<<<2048, 256, 0, stream>>>(PART, WPH);
    // G = gelu(curIn @ W'^T + b_eff)   [16384 x 1024] bf16
    k_mmcv<<<dim3(8, 128), 256, 0, stream>>>(curIn, WPH, beff, Gb, 16384, 1024, 512, 512);
    k_repackb<<<B_ * C_ * 16, 256, 0, stream>>>(Gb, G2b);
    k_splith<<<8192, 256, 0, stream>>>(end_w + (size_t)i * 8388608, EWH, 8388608);
    k_mmend<<<dim3(4, 8, 16), 256, 0, stream>>>(G2b, EWH, PART, 1024, 512, 16384);
    k_red16<<<2048, 256, 0, stream>>>(PART, end_b + i * T_, osm);
    k_lwln<<<B_ * T_, 256, 0, stream>>>(osm, glin_w + i * C_ * N_, glin_b + i * N_, curIn,
                                        gnorm_g + i * N_, gnorm_b + i * N_, cur,
                                        A0h, A0l, meta, i);
    k_padtail<<<512, 256, 0, stream>>>(A0h, A0l, meta, i);
    // ---- attention branch ----
    const int* Mdyn = meta + 15 + i;
    dim3 gT(4, TOKMAX / 128, 1);
    k_mmqkv<<<dim3(12, TOKMAX / 128), 256, 0, stream>>>(A0h, WqkvH, bq, bk, bv,
                                                        A2h, A3h, A4h, TOKMAX, 512, Mdyn);
    k_attn32<<<2048, 256, 0, stream>>>(A2h, A3h, A4h, A5h, meta, i);
    k_attn_small<<<4096, 256, 0, stream>>>(A2h, A3h, A4h, A5h, meta, i);
    k_attn_big<<<1024, 256, 0, stream>>>(A2h, A3h, A4h, A5h, meta, i);
    k_mmb1<<<gT, 256, 0, stream>>>(A5h, WoH, bo, A2h, A2l, TOKMAX, 512, 512, Mdyn, 0);
    k_lnadd<<<TOKMAX, 256, 0, stream>>>(A0h, A0l, A2h, A2l, an1g, an1b, A3h, A3l, meta, i);
    k_mmb1<<<gT, 256, 0, stream>>>(A3h, F1H, ff1b, A4h, nullptr, TOKMAX, 512, 512, Mdyn, 1);
    k_mmb1<<<gT, 256, 0, stream>>>(A4h, F2H, ff2b, A5h, A5l, TOKMAX, 512, 512, Mdyn, 0);
    k_lnfin<<<TOKMAX, 256, 0, stream>>>(A3h, A3l, A5h, A5l, an2g, an2b, nrmg, nrmb,
                                        swb, accb, meta, i);
    curIn = cur;
  }
  k_final<<<(B_ * T_ * N_) / 256, 256, 0, stream>>>(accb, curIn, (float*)d_out);
}

// Round 25
// 1849.241 us; speedup vs baseline: 1.0774x; 1.0015x over previous
//
#include <hip/hip_runtime.h>
#include <math.h>

#define DI __device__ __forceinline__

namespace {
constexpr int B_ = 32;
constexpr int T_ = 512;
constexpr int N_ = 512;   // d_model
constexpr int C_ = 32;    // c_out / conv_ch / skip_ch
constexpr int KH_ = 481;
constexpr int HOP_ = 48;
constexpr int WIN_ = 48;
constexpr int NFR_ = 11;
constexpr int NBIN_ = 257;
constexpr int NMT_ = B_ * NFR_ * 4;   // 1408 sample-tiles (44 per batch, contiguous)
constexpr int TOKMAX = 21760;   // 170*128 == exact max tokens (L=680)
constexpr int PLW = TOKMAX * 512;     // plane elements for token buffers
constexpr float EPS_ = 1e-5f;

constexpr size_t MBY = 1ull << 20;
constexpr size_t OFF_META = 0;
constexpr size_t OFF_FREQ = 4096;
constexpr size_t OFF_SW   = 8192;
constexpr size_t OFF_BEFF = 16384;       // 1024 floats
constexpr size_t OFF_P12  = 32768;       // 2048 floats
constexpr size_t OFF_FSB  = 65536;       // 257*32 floats (per-(k,b) sums)
constexpr size_t OFF_OSM  = 1 * MBY;     // 2MB (1..3MB)
constexpr size_t OFF_TWH  = 3 * MBY;         // twiddle hi planes [2][384][64] bf16
constexpr size_t OFF_TWL  = 3 * MBY + 131072;// twiddle lo planes
constexpr size_t OFF_WB   = 4 * MBY;     // 6 hi planes x 512KB = 3MB (Q,K,V contiguous!)
constexpr size_t OFF_WDH  = 10 * MBY;    // 1MB  (WdT hi plane [512][1024])
constexpr size_t OFF_EWH  = 12 * MBY;    // 16MB
constexpr size_t OFF_CUR  = 44 * MBY;    // 32MB
constexpr size_t OFF_ACC  = 76 * MBY;    // 32MB
constexpr size_t TR       = 108 * MBY;   // transient union region
// graph phase
constexpr size_t OFF_T    = TR;            // 4MB  T [1024][1024]
constexpr size_t OFF_WPH  = TR + 6 * MBY;  // 1MB  W' hi plane
constexpr size_t OFF_G    = TR + 64 * MBY; // 32MB bf16 [16384][1024]
constexpr size_t OFF_G2   = TR + 128 * MBY;// 32MB bf16 [1024][16384]
constexpr size_t OFF_PART = TR + 192 * MBY;// 32MB [16][1024][512]
// attention phase (aliases graph region): each buffer = hi plane + lo plane
constexpr size_t OFF_A0 = TR;              // 44MB stride each
constexpr size_t OFF_A2 = TR + 44 * MBY;
constexpr size_t OFF_A3 = TR + 88 * MBY;
constexpr size_t OFF_A4 = TR + 132 * MBY;
constexpr size_t OFF_A5 = TR + 176 * MBY;  // ends 328MB
// stft scratch aliases TR (stft completes before graph phase starts)
constexpr size_t OFF_XWH = TR;              // 23MB bf16 [180224][64] (x hi)
constexpr size_t OFF_FP  = TR + 48 * MBY;   // NBIN_*NMT_ floats ~1.45MB
} // namespace

typedef __attribute__((ext_vector_type(2))) float f32x2;
typedef __attribute__((ext_vector_type(4))) float f32x4;
typedef __attribute__((ext_vector_type(8))) short bf8;
typedef __attribute__((ext_vector_type(8))) unsigned short u16x8;

DI float gelu_exact(float x) { return 0.5f * x * (1.0f + erff(x * 0.7071067811865475f)); }
DI unsigned short f2bf(float f) {   // round-to-nearest-even
  unsigned u = __float_as_uint(f);
  u += 0x7FFFu + ((u >> 16) & 1u);
  return (unsigned short)(u >> 16);
}
DI float bf2f(unsigned short s) { return __uint_as_float(((unsigned)s) << 16); }
DI float ld2(const unsigned short* __restrict__ H, const unsigned short* __restrict__ L,
             size_t i) { return bf2f(H[i]) + bf2f(L[i]); }
DI void st2(unsigned short* __restrict__ H, unsigned short* __restrict__ L,
            size_t i, float v) {
  unsigned short h = f2bf(v);
  H[i] = h;
  L[i] = f2bf(v - bf2f(h));
}
DI void gll16(const unsigned short* g, unsigned short* l) {
  __builtin_amdgcn_global_load_lds(
      (const __attribute__((address_space(1))) void*)g,
      (__attribute__((address_space(3))) void*)l, 16, 0, 0);
}

// ---------------- build x-hi frames: XW [180224][64] via LDS transpose ----------------
__global__ __launch_bounds__(256) void k_xw(const float* __restrict__ x,
                                            unsigned short* __restrict__ XWH) {
  int bf = blockIdx.x;            // b*NFR + f
  int f = bf % NFR_, b = bf / NFR_;
  __shared__ unsigned short TS[512 * 58];   // [n][j], pad 58 (stride 29 dw, conflict-free)
  int tid = threadIdx.x;
  // phase 1: coalesced reads (lane = n), LDS write conflict-free
  for (int idx = tid; idx < WIN_ * 512; idx += 256) {
    int j = idx >> 9, n = idx & 511;
    int gi = f * HOP_ + 232 + j - 256;
    if (gi < 0) gi = -gi;   // reflect pad (left only)
    TS[n * 58 + j] = f2bf(x[((size_t)b * T_ + gi) * N_ + n]);
  }
  __syncthreads();
  // phase 2: coalesced 16B global writes
  for (int i = tid; i < 512 * 8; i += 256) {
    int n = i >> 3, jc = i & 7;
    size_t m = (size_t)bf * 512 + n;
    u16x8 v;
    if (jc < 6) {
#pragma unroll
      for (int q = 0; q < 8; ++q) v[q] = TS[n * 58 + jc * 8 + q];
    } else {
#pragma unroll
      for (int q = 0; q < 8; ++q) v[q] = 0;
    }
    *(u16x8*)&XWH[m * 64 + jc * 8] = v;
  }
}

// ---------------- build twiddle hi/lo planes [2][384][64] (window baked in HERE) ----------------
__global__ void k_tw(unsigned short* __restrict__ TWH, unsigned short* __restrict__ TWL) {
  int idx = blockIdx.x * 256 + threadIdx.x;   // 2*384*64 = 49152
  if (idx >= 2 * 384 * 64) return;
  int pl = idx / (384 * 64);
  int rem = idx % (384 * 64);
  int k = rem >> 6, j = rem & 63;
  float v = 0.f;
  if (k < NBIN_ && j < WIN_) {
    int r = (k * (232 + j)) & 511;
    float ang = (float)r * 0.012271846303085130f;   // 2pi/512
    float w = 0.5f - 0.5f * cosf((float)j * 0.13089969389957472f);
    v = pl == 0 ? w * cosf(ang) : w * sinf(ang);
  }
  unsigned short h = f2bf(v);
  TWH[idx] = h;
  TWL[idx] = f2bf(v - bf2f(h));
}

// ---------------- MFMA STFT: mags summed per (k, sample-tile) ----------------
// A = x-hi [180224][64]; B = windowed twiddles (re/im, hi+lo). 128x128 tile.
__global__ __launch_bounds__(256, 3) void k_stftmm(
    const unsigned short* __restrict__ XWH,
    const unsigned short* __restrict__ TWH, const unsigned short* __restrict__ TWL,
    float* __restrict__ fpart) {
  const int bn = blockIdx.x * 128;     // k-tile base (0,128,256)
  const int mtile = blockIdx.y;
  const int bm = mtile * 128;

  __shared__ __align__(16) unsigned short AHS[4096], RHS[4096], RLS[4096],
                                          IHS[4096], ILS[4096];
  __shared__ float colpart[2][128];

  const int tid = threadIdx.x;
  const int wave = tid >> 6, lane = tid & 63;
  const int wr = wave >> 1, wc = wave & 1;
  const int fr = lane & 15, fs = lane >> 4;

  const int row0 = tid >> 2;
  const int s0 = (tid & 3) ^ ((row0 >> 1) & 3);
  const unsigned short* gAH0 = XWH + (size_t)(bm + row0) * 64 + s0 * 8;
  const unsigned short* gAH1 = gAH0 + (size_t)64 * 64;
  const unsigned short* gRH0 = TWH + (size_t)(bn + row0) * 64 + s0 * 8;
  const unsigned short* gRH1 = gRH0 + (size_t)64 * 64;
  const unsigned short* gRL0 = TWL + (size_t)(bn + row0) * 64 + s0 * 8;
  const unsigned short* gRL1 = gRL0 + (size_t)64 * 64;
  const unsigned short* gIH0 = gRH0 + (size_t)384 * 64;
  const unsigned short* gIH1 = gRH1 + (size_t)384 * 64;
  const unsigned short* gIL0 = gRL0 + (size_t)384 * 64;
  const unsigned short* gIL1 = gRL1 + (size_t)384 * 64;
  const int lb0 = wave * 512, lb1 = 2048 + wave * 512;

  int aoff[4], boff[4];
#pragma unroll
  for (int m = 0; m < 4; ++m) {
    int ra = wr * 64 + m * 16 + fr;
    aoff[m] = ra * 32 + 8 * (fs ^ ((ra >> 1) & 3));
    int rb = wc * 64 + m * 16 + fr;
    boff[m] = rb * 32 + 8 * (fs ^ ((rb >> 1) & 3));
  }

  f32x4 are[4][4], aim[4][4];
#pragma unroll
  for (int m = 0; m < 4; ++m)
#pragma unroll
    for (int n = 0; n < 4; ++n) {
      are[m][n] = (f32x4){0.f, 0.f, 0.f, 0.f};
      aim[m][n] = (f32x4){0.f, 0.f, 0.f, 0.f};
    }

  for (int k0 = 0; k0 < 64; k0 += 32) {
    __syncthreads();
    gll16(gAH0 + k0, &AHS[lb0]); gll16(gAH1 + k0, &AHS[lb1]);
    gll16(gRH0 + k0, &RHS[lb0]); gll16(gRH1 + k0, &RHS[lb1]);
    gll16(gRL0 + k0, &RLS[lb0]); gll16(gRL1 + k0, &RLS[lb1]);
    gll16(gIH0 + k0, &IHS[lb0]); gll16(gIH1 + k0, &IHS[lb1]);
    gll16(gIL0 + k0, &ILS[lb0]); gll16(gIL1 + k0, &ILS[lb1]);
    __syncthreads();
    bf8 ah[4], rh[4], rl[4], ih[4], il[4];
#pragma unroll
    for (int m = 0; m < 4; ++m) ah[m] = *(const bf8*)&AHS[aoff[m]];
#pragma unroll
    for (int n = 0; n < 4; ++n) {
      rh[n] = *(const bf8*)&RHS[boff[n]];
      rl[n] = *(const bf8*)&RLS[boff[n]];
      ih[n] = *(const bf8*)&IHS[boff[n]];
      il[n] = *(const bf8*)&ILS[boff[n]];
    }
#pragma unroll
    for (int m = 0; m < 4; ++m)
#pragma unroll
      for (int n = 0; n < 4; ++n) {
        are[m][n] = __builtin_amdgcn_mfma_f32_16x16x32_bf16(ah[m], rh[n], are[m][n], 0, 0, 0);
        are[m][n] = __builtin_amdgcn_mfma_f32_16x16x32_bf16(ah[m], rl[n], are[m][n], 0, 0, 0);
        aim[m][n] = __builtin_amdgcn_mfma_f32_16x16x32_bf16(ah[m], ih[n], aim[m][n], 0, 0, 0);
        aim[m][n] = __builtin_amdgcn_mfma_f32_16x16x32_bf16(ah[m], il[n], aim[m][n], 0, 0, 0);
      }
  }

  float s[4];
#pragma unroll
  for (int n = 0; n < 4; ++n) {
    float acc = 0.f;
#pragma unroll
    for (int m = 0; m < 4; ++m)
#pragma unroll
      for (int r = 0; r < 4; ++r) {
        float re = are[m][n][r], im = aim[m][n][r];
        acc += __builtin_amdgcn_sqrtf(re * re + im * im);
      }
    acc += __shfl_xor(acc, 16);
    acc += __shfl_xor(acc, 32);
    s[n] = acc;
  }
  if (fs == 0) {
#pragma unroll
    for (int n = 0; n < 4; ++n) colpart[wr][wc * 64 + n * 16 + fr] = s[n];
  }
  __syncthreads();
  if (tid < 128) {
    int k = bn + tid;
    if (k < NBIN_) fpart[(size_t)k * NMT_ + mtile] = colpart[0][tid] + colpart[1][tid];
  }
}

// ---------------- reduce -> freq (all-b) and fsumb (per-b) ----------------
__global__ __launch_bounds__(256) void k_fred(const float* __restrict__ fpart,
                                              float* __restrict__ freq,
                                              float* __restrict__ fsumb) {
  int k = blockIdx.x;
  int tid = threadIdx.x;
  int b = tid >> 3, j = tid & 7;   // 8 lanes per batch, 44 values each batch
  float s = 0.f;
  for (int i = j; i < 44; i += 8) s += fpart[(size_t)k * NMT_ + b * 44 + i];
  for (int off = 4; off > 0; off >>= 1) s += __shfl_xor(s, off);
  __shared__ float bs[32];
  if (j == 0) bs[b] = s;
  __syncthreads();
  if (tid < 32) {
    float v = bs[tid];
    fsumb[k * 32 + tid] = v;
    for (int off = 16; off > 0; off >>= 1) v += __shfl_xor(v, off);
    if (tid == 0) freq[k] = v;
  }
}

// ---------------- top-k + meta + sw softmax (fused) ----------------
__global__ void k_topk(const float* __restrict__ freq, const float* __restrict__ fsumb,
                       int* __restrict__ meta, float* __restrict__ swb) {
  __shared__ int stop[3];
  int tid = threadIdx.x;
  if (tid == 0) {
    float bv[3] = {-1e30f, -1e30f, -1e30f};
    int bi[3] = {1, 1, 1};
    for (int k = 1; k < NBIN_; ++k) {
      float v = freq[k];
      if (v > bv[0]) { bv[2]=bv[1]; bi[2]=bi[1]; bv[1]=bv[0]; bi[1]=bi[0]; bv[0]=v; bi[0]=k; }
      else if (v > bv[1]) { bv[2]=bv[1]; bi[2]=bi[1]; bv[1]=v; bi[1]=k; }
      else if (v > bv[2]) { bv[2]=v; bi[2]=k; }
    }
    for (int i = 0; i < 3; ++i) {
      int top = bi[i];
      int p = T_ / top;
      int L = ((T_ + p - 1) / p) * p;
      meta[i] = top;
      meta[3 + i] = p;
      meta[6 + i] = L;
      meta[9 + i] = L / p;
      meta[15 + i] = B_ * L;   // tokens
      stop[i] = top;
    }
  }
  __syncthreads();
  int b = tid;
  if (b < B_) {
    float inv = 1.0f / (float)(NFR_ * N_);
    float m0 = fsumb[stop[0] * 32 + b] * inv;
    float m1 = fsumb[stop[1] * 32 + b] * inv;
    float m2 = fsumb[stop[2] * 32 + b] * inv;
    float mx = fmaxf(m0, fmaxf(m1, m2));
    float e0 = __expf(m0 - mx), e1 = __expf(m1 - mx), e2 = __expf(m2 - mx);
    float s = e0 + e1 + e2;
    swb[b * 4 + 0] = e0 / s; swb[b * 4 + 1] = e1 / s; swb[b * 4 + 2] = e2 / s;
  }
}

// ---------------- fused adjacency + GCN operator prep ----------------
__global__ __launch_bounds__(1024) void k_adjprep(const float* __restrict__ nv1,
                                                  const float* __restrict__ nv2,
                                                  const float* __restrict__ mw,
                                                  const float* __restrict__ mb,
                                                  const float* __restrict__ sb,
                                                  float* __restrict__ P12,
                                                  float* __restrict__ beff) {
  __shared__ float A32s[32][32];
  __shared__ float Ms[32][32], P1s[32][32], P2s[32][32], S1[32], S2[32], sbl[32];
  int tid = threadIdx.x;
  if (tid < 32) {
    int v = tid;
    float row[32];
    for (int w = 0; w < 32; ++w) {
      float s = 0.f;
      for (int d = 0; d < 10; ++d) s += nv1[v * 10 + d] * nv2[d * 32 + w];
      row[w] = fmaxf(s, 0.f);
    }
    float mx = -1e30f;
    for (int w = 0; w < 32; ++w) mx = fmaxf(mx, row[w]);
    float sm = 0.f;
    for (int w = 0; w < 32; ++w) { row[w] = expf(row[w] - mx); sm += row[w]; }
    for (int w = 0; w < 32; ++w) row[w] /= sm;
    row[v] += 1.0f;
    float rs = 0.f;
    for (int w = 0; w < 32; ++w) rs += row[w];
    for (int w = 0; w < 32; ++w) A32s[v][w] = row[w] / rs;
    sbl[tid] = sb[tid];
  }
  __syncthreads();
  int w = tid >> 5, v = tid & 31;
  Ms[w][v] = A32s[v][w];
  __syncthreads();
  float p1 = 0.95f * Ms[w][v] + (w == v ? 0.05f : 0.f);
  P1s[w][v] = p1;
  __syncthreads();
  float p2 = 0.f;
  for (int u = 0; u < 32; ++u) p2 += P1s[w][u] * Ms[u][v];
  p2 = 0.95f * p2 + (w == v ? 0.05f : 0.f);
  P2s[w][v] = p2;
  P12[tid] = p1;
  P12[1024 + tid] = p2;
  __syncthreads();
  if (tid < 32) {
    float s1 = 0.f, s2 = 0.f;
    for (int u = 0; u < 32; ++u) { s1 += P1s[u][tid]; s2 += P2s[u][tid]; }
    S1[tid] = s1; S2[tid] = s2;
  }
  __syncthreads();
  int o = w;
  float be = mb[o];
  for (int c = 0; c < 32; ++c) {
    float sc = sbl[c];
    be += mw[o * 96 + c] * sc;
    be += mw[o * 96 + 32 + c] * sc * S1[v];
    be += mw[o * 96 + 64 + c] * sc * S2[v];
  }
  beff[tid] = be;
}

// ---------------- build T [1024][1024]: T[(o,v)][(c,w)] ----------------
__global__ __launch_bounds__(256) void k_T(const float* __restrict__ P12,
                                           const float* __restrict__ mw,
                                           float* __restrict__ Tm) {
  int idx = blockIdx.x * 256 + threadIdx.x;
  int r = idx >> 10, k2 = idx & 1023;
  int o = r >> 5, v = r & 31;
  int c = k2 >> 5, w = k2 & 31;
  float t = mw[o * 96 + 32 + c] * P12[w * 32 + v]
          + mw[o * 96 + 64 + c] * P12[1024 + w * 32 + v];
  if (w == v) t += mw[o * 96 + c];
  Tm[idx] = t;
}

// ---------------- build WdT hi: WdT[j][(c,w)] = sw[c][j-w] ----------------
__global__ void k_wdh(const float* __restrict__ swi, unsigned short* __restrict__ WH) {
  int idx = blockIdx.x * 256 + threadIdx.x;   // 512*1024
  int j = idx >> 10, k2 = idx & 1023;
  int c = k2 >> 5, w = k2 & 31;
  int kk = j - w;
  float vv = (kk >= 0 && kk < KH_) ? swi[c * KH_ + kk] : 0.f;
  WH[idx] = f2bf(vv);
}

// ---------------- weight hi split ----------------
__global__ void k_splith(const float* __restrict__ src, unsigned short* __restrict__ Hi,
                         int n) {
  int i = blockIdx.x * 256 + threadIdx.x;
  if (i * 4 >= n) return;
  float4 v = *(const float4*)&src[i * 4];
  ushort4 h;
  h.x = f2bf(v.x); h.y = f2bf(v.y); h.z = f2bf(v.z); h.w = f2bf(v.w);
  *(ushort4*)&Hi[i * 4] = h;
}

// ---------------- 2-MFMA GEMM (fp32 A hi/lo; bf16 weight hi; fold GEMM only) ----------------
__global__ __launch_bounds__(256, 2) void k_mm2(
    const float* __restrict__ A, const unsigned short* __restrict__ Bh,
    const float* __restrict__ bias,
    float* __restrict__ C, float* __restrict__ Cpart,
    int M, int N, int K, int lda, int dogelu) {
  const int bm = blockIdx.y * 128;
  if (bm >= M) return;
  const int bn = blockIdx.x * 128;
  const int nz = gridDim.z, z = blockIdx.z;
  const int kpb = K / nz;
  const int kbeg = z * kpb, kend = kbeg + kpb;

  __shared__ __align__(16) unsigned short AhS[4096], AlS[4096], BhS[4096];

  const int tid = threadIdx.x;
  const int wave = tid >> 6, lane = tid & 63;
  const int wr = wave >> 1, wc = wave & 1;
  const int fr = lane & 15, fs = lane >> 4;

  const int sr = tid >> 1, ss = (tid & 1) * 2;
  const int sx = (sr >> 1) & 3;
  const int so0 = sr * 32 + 8 * (ss ^ sx);
  const int so1 = sr * 32 + 8 * ((ss + 1) ^ sx);

  const int row0 = tid >> 2;
  const int s0 = (tid & 3) ^ ((row0 >> 1) & 3);
  const unsigned short* gBh0 = Bh + (size_t)(bn + row0) * K + s0 * 8;
  const unsigned short* gBh1 = gBh0 + (size_t)64 * K;
  unsigned short* lB0 = &BhS[wave * 512];
  unsigned short* lB1 = &BhS[2048 + wave * 512];

  int aoff[4], boff[4];
#pragma unroll
  for (int m = 0; m < 4; ++m) {
    int ra = wr * 64 + m * 16 + fr;
    aoff[m] = ra * 32 + 8 * (fs ^ ((ra >> 1) & 3));
    int rb = wc * 64 + m * 16 + fr;
    boff[m] = rb * 32 + 8 * (fs ^ ((rb >> 1) & 3));
  }

  const bool aok = (bm + sr) < M;
  const float* Arow = A + (size_t)(bm + sr) * lda + ss * 8;

  f32x4 acc[4][4];
#pragma unroll
  for (int m = 0; m < 4; ++m)
#pragma unroll
    for (int n = 0; n < 4; ++n) acc[m][n] = (f32x4){0.f, 0.f, 0.f, 0.f};

  for (int k0 = kbeg; k0 < kend; k0 += 32) {
    float4 a0, a1, a2, a3;
    if (aok) {
      const float4* p = (const float4*)(Arow + k0);
      a0 = p[0]; a1 = p[1]; a2 = p[2]; a3 = p[3];
    } else {
      a0 = a1 = a2 = a3 = make_float4(0.f, 0.f, 0.f, 0.f);
    }
    float av[16];
    av[0]=a0.x; av[1]=a0.y; av[2]=a0.z; av[3]=a0.w;
    av[4]=a1.x; av[5]=a1.y; av[6]=a1.z; av[7]=a1.w;
    av[8]=a2.x; av[9]=a2.y; av[10]=a2.z; av[11]=a2.w;
    av[12]=a3.x; av[13]=a3.y; av[14]=a3.z; av[15]=a3.w;
    u16x8 h0, h1, l0, l1;
#pragma unroll
    for (int j = 0; j < 8; ++j) {
      unsigned u = __float_as_uint(av[j]);
      h0[j] = (unsigned short)(u >> 16);
      float r2 = av[j] - __uint_as_float(u & 0xffff0000u);
      l0[j] = (unsigned short)(__float_as_uint(r2) >> 16);
      unsigned u2 = __float_as_uint(av[j + 8]);
      h1[j] = (unsigned short)(u2 >> 16);
      float r3 = av[j + 8] - __uint_as_float(u2 & 0xffff0000u);
      l1[j] = (unsigned short)(__float_as_uint(r3) >> 16);
    }
    __syncthreads();   // prior frag reads done
    gll16(gBh0 + k0, lB0); gll16(gBh1 + k0, lB1);
    *(u16x8*)&AhS[so0] = h0; *(u16x8*)&AhS[so1] = h1;
    *(u16x8*)&AlS[so0] = l0; *(u16x8*)&AlS[so1] = l1;
    __syncthreads();   // drains vmcnt + lgkm
    bf8 ah[4], al4[4], bh4[4];
#pragma unroll
    for (int m = 0; m < 4; ++m) {
      ah[m]  = *(const bf8*)&AhS[aoff[m]];
      al4[m] = *(const bf8*)&AlS[aoff[m]];
    }
#pragma unroll
    for (int n = 0; n < 4; ++n) bh4[n] = *(const bf8*)&BhS[boff[n]];
#pragma unroll
    for (int m = 0; m < 4; ++m)
#pragma unroll
      for (int n = 0; n < 4; ++n) {
        acc[m][n] = __builtin_amdgcn_mfma_f32_16x16x32_bf16(ah[m],  bh4[n], acc[m][n], 0, 0, 0);
        acc[m][n] = __builtin_amdgcn_mfma_f32_16x16x32_bf16(al4[m], bh4[n], acc[m][n], 0, 0, 0);
      }
  }

  if (nz > 1) {
    float* P = Cpart + (size_t)z * M * N;
#pragma unroll
    for (int m = 0; m < 4; ++m)
#pragma unroll
      for (int r = 0; r < 4; ++r) {
        int row = bm + wr * 64 + m * 16 + fs * 4 + r;
        if (row < M) {
#pragma unroll
          for (int n = 0; n < 4; ++n) {
            int col = bn + wc * 64 + n * 16 + fr;
            P[(size_t)row * N + col] = acc[m][n][r];
          }
        }
      }
  } else {
    float bcol[4];
#pragma unroll
    for (int n = 0; n < 4; ++n) bcol[n] = bias ? bias[bn + wc * 64 + n * 16 + fr] : 0.f;
#pragma unroll
    for (int m = 0; m < 4; ++m)
#pragma unroll
      for (int r = 0; r < 4; ++r) {
        int row = bm + wr * 64 + m * 16 + fs * 4 + r;
        if (row < M) {
#pragma unroll
          for (int n = 0; n < 4; ++n) {
            int col = bn + wc * 64 + n * 16 + fr;
            float v = acc[m][n][r] + bcol[n];
            if (dogelu) v = gelu_exact(v);
            C[(size_t)row * N + col] = v;
          }
        }
      }
  }
}

// ---------------- conv GEMM: fp32 A hi-only, 1 MFMA, bf16 output + gelu ----------------
__global__ __launch_bounds__(256, 4) void k_mmcv(
    const float* __restrict__ A, const unsigned short* __restrict__ Bh,
    const float* __restrict__ bias,
    unsigned short* __restrict__ C,
    int M, int N, int K, int lda) {
  const int bm = blockIdx.y * 128;
  const int bn = blockIdx.x * 128;

  __shared__ __align__(16) unsigned short AhS[4096], BhS[4096];

  const int tid = threadIdx.x;
  const int wave = tid >> 6, lane = tid & 63;
  const int wr = wave >> 1, wc = wave & 1;
  const int fr = lane & 15, fs = lane >> 4;

  const int sr = tid >> 1, ss = (tid & 1) * 2;
  const int sx = (sr >> 1) & 3;
  const int so0 = sr * 32 + 8 * (ss ^ sx);
  const int so1 = sr * 32 + 8 * ((ss + 1) ^ sx);

  const int row0 = tid >> 2;
  const int s0 = (tid & 3) ^ ((row0 >> 1) & 3);
  const unsigned short* gBh0 = Bh + (size_t)(bn + row0) * K + s0 * 8;
  const unsigned short* gBh1 = gBh0 + (size_t)64 * K;
  unsigned short* lB0 = &BhS[wave * 512];
  unsigned short* lB1 = &BhS[2048 + wave * 512];

  int aoff[4], boff[4];
#pragma unroll
  for (int m = 0; m < 4; ++m) {
    int ra = wr * 64 + m * 16 + fr;
    aoff[m] = ra * 32 + 8 * (fs ^ ((ra >> 1) & 3));
    int rb = wc * 64 + m * 16 + fr;
    boff[m] = rb * 32 + 8 * (fs ^ ((rb >> 1) & 3));
  }

  const float* Arow = A + (size_t)(bm + sr) * lda + ss * 8;

  f32x4 acc[4][4];
#pragma unroll
  for (int m = 0; m < 4; ++m)
#pragma unroll
    for (int n = 0; n < 4; ++n) acc[m][n] = (f32x4){0.f, 0.f, 0.f, 0.f};

  for (int k0 = 0; k0 < K; k0 += 32) {
    const float4* p = (const float4*)(Arow + k0);
    float4 a0 = p[0], a1 = p[1], a2 = p[2], a3 = p[3];
    u16x8 h0, h1;
    h0[0]=f2bf(a0.x); h0[1]=f2bf(a0.y); h0[2]=f2bf(a0.z); h0[3]=f2bf(a0.w);
    h0[4]=f2bf(a1.x); h0[5]=f2bf(a1.y); h0[6]=f2bf(a1.z); h0[7]=f2bf(a1.w);
    h1[0]=f2bf(a2.x); h1[1]=f2bf(a2.y); h1[2]=f2bf(a2.z); h1[3]=f2bf(a2.w);
    h1[4]=f2bf(a3.x); h1[5]=f2bf(a3.y); h1[6]=f2bf(a3.z); h1[7]=f2bf(a3.w);
    __syncthreads();   // prior frag reads done
    gll16(gBh0 + k0, lB0); gll16(gBh1 + k0, lB1);
    *(u16x8*)&AhS[so0] = h0; *(u16x8*)&AhS[so1] = h1;
    __syncthreads();   // drains vmcnt + lgkm
    bf8 ah[4], bh4[4];
#pragma unroll
    for (int m = 0; m < 4; ++m) ah[m] = *(const bf8*)&AhS[aoff[m]];
#pragma unroll
    for (int n = 0; n < 4; ++n) bh4[n] = *(const bf8*)&BhS[boff[n]];
#pragma unroll
    for (int m = 0; m < 4; ++m)
#pragma unroll
      for (int n = 0; n < 4; ++n)
        acc[m][n] = __builtin_amdgcn_mfma_f32_16x16x32_bf16(ah[m], bh4[n], acc[m][n], 0, 0, 0);
  }

  float bcol[4];
#pragma unroll
  for (int n = 0; n < 4; ++n) bcol[n] = bias[bn + wc * 64 + n * 16 + fr];
#pragma unroll
  for (int m = 0; m < 4; ++m)
#pragma unroll
    for (int r = 0; r < 4; ++r) {
      int row = bm + wr * 64 + m * 16 + fs * 4 + r;
#pragma unroll
      for (int n = 0; n < 4; ++n) {
        int col = bn + wc * 64 + n * 16 + fr;
        C[(size_t)row * N + col] = f2bf(gelu_exact(acc[m][n][r] + bcol[n]));
      }
    }
}

// ---------------- end GEMM: bf16 A, bf16 B, 1 MFMA, split-K partials ----------------
__global__ __launch_bounds__(256, 4) void k_mmend(
    const unsigned short* __restrict__ Ah, const unsigned short* __restrict__ Bh,
    float* __restrict__ Cpart, int M, int N, int K) {
  const int bm = blockIdx.y * 128;
  const int bn = blockIdx.x * 128;
  const int nz = gridDim.z, z = blockIdx.z;
  const int kpb = K / nz;
  const int kbeg = z * kpb, kend = kbeg + kpb;

  __shared__ __align__(16) unsigned short AhS[4096], BhS[4096];

  const int tid = threadIdx.x;
  const int wave = tid >> 6, lane = tid & 63;
  const int wr = wave >> 1, wc = wave & 1;
  const int fr = lane & 15, fs = lane >> 4;

  const int row0 = tid >> 2;
  const int s0 = (tid & 3) ^ ((row0 >> 1) & 3);
  const unsigned short* gAh0 = Ah + (size_t)(bm + row0) * K + s0 * 8;
  const unsigned short* gAh1 = gAh0 + (size_t)64 * K;
  const unsigned short* gBh0 = Bh + (size_t)(bn + row0) * K + s0 * 8;
  const unsigned short* gBh1 = gBh0 + (size_t)64 * K;
  const int lb0 = wave * 512, lb1 = 2048 + wave * 512;

  int aoff[4], boff[4];
#pragma unroll
  for (int m = 0; m < 4; ++m) {
    int ra = wr * 64 + m * 16 + fr;
    aoff[m] = ra * 32 + 8 * (fs ^ ((ra >> 1) & 3));
    int rb = wc * 64 + m * 16 + fr;
    boff[m] = rb * 32 + 8 * (fs ^ ((rb >> 1) & 3));
  }

  f32x4 acc[4][4];
#pragma unroll
  for (int m = 0; m < 4; ++m)
#pragma unroll
    for (int n = 0; n < 4; ++n) acc[m][n] = (f32x4){0.f, 0.f, 0.f, 0.f};

  for (int k0 = kbeg; k0 < kend; k0 += 32) {
    __syncthreads();
    gll16(gAh0 + k0, &AhS[lb0]); gll16(gAh1 + k0, &AhS[lb1]);
    gll16(gBh0 + k0, &BhS[lb0]); gll16(gBh1 + k0, &BhS[lb1]);
    __syncthreads();
    bf8 ah[4], bh4[4];
#pragma unroll
    for (int m = 0; m < 4; ++m) ah[m] = *(const bf8*)&AhS[aoff[m]];
#pragma unroll
    for (int n = 0; n < 4; ++n) bh4[n] = *(const bf8*)&BhS[boff[n]];
#pragma unroll
    for (int m = 0; m < 4; ++m)
#pragma unroll
      for (int n = 0; n < 4; ++n)
        acc[m][n] = __builtin_amdgcn_mfma_f32_16x16x32_bf16(ah[m], bh4[n], acc[m][n], 0, 0, 0);
  }

  float* P = Cpart + (size_t)z * M * N;
#pragma unroll
  for (int m = 0; m < 4; ++m)
#pragma unroll
    for (int r = 0; r < 4; ++r) {
      int row = bm + wr * 64 + m * 16 + fs * 4 + r;
#pragma unroll
      for (int n = 0; n < 4; ++n) {
        int col = bn + wc * 64 + n * 16 + fr;
        P[(size_t)row * N + col] = acc[m][n][r];
      }
    }
}

// ---------------- 1-MFMA plane GEMM (attention pipeline; optional lo write) ----------------
__global__ __launch_bounds__(256, 4) void k_mmb1(
    const unsigned short* __restrict__ Ah,
    const unsigned short* __restrict__ Bh,
    const float* __restrict__ bias,
    unsigned short* __restrict__ Ch, unsigned short* __restrict__ Cl,
    int M, int N, int K, const int* __restrict__ Mdyn, int dogelu) {
  if (Mdyn) M = *Mdyn;
  const int bm = blockIdx.y * 128;
  if (bm >= M) return;
  const int bn = blockIdx.x * 128;

  __shared__ __align__(16) unsigned short AhS[4096], BhS[4096];

  const int tid = threadIdx.x;
  const int wave = tid >> 6, lane = tid & 63;
  const int wr = wave >> 1, wc = wave & 1;
  const int fr = lane & 15, fs = lane >> 4;

  const int row0 = tid >> 2;
  const int s0 = (tid & 3) ^ ((row0 >> 1) & 3);
  const unsigned short* gAh0 = Ah + (size_t)(bm + row0) * K + s0 * 8;
  const unsigned short* gAh1 = gAh0 + (size_t)64 * K;
  const unsigned short* gBh0 = Bh + (size_t)(bn + row0) * K + s0 * 8;
  const unsigned short* gBh1 = gBh0 + (size_t)64 * K;
  const int lb0 = wave * 512, lb1 = 2048 + wave * 512;

  int aoff[4], boff[4];
#pragma unroll
  for (int m = 0; m < 4; ++m) {
    int ra = wr * 64 + m * 16 + fr;
    aoff[m] = ra * 32 + 8 * (fs ^ ((ra >> 1) & 3));
    int rb = wc * 64 + m * 16 + fr;
    boff[m] = rb * 32 + 8 * (fs ^ ((rb >> 1) & 3));
  }

  f32x4 acc[4][4];
#pragma unroll
  for (int m = 0; m < 4; ++m)
#pragma unroll
    for (int n = 0; n < 4; ++n) acc[m][n] = (f32x4){0.f, 0.f, 0.f, 0.f};

  for (int k0 = 0; k0 < K; k0 += 32) {
    __syncthreads();
    gll16(gAh0 + k0, &AhS[lb0]); gll16(gAh1 + k0, &AhS[lb1]);
    gll16(gBh0 + k0, &BhS[lb0]); gll16(gBh1 + k0, &BhS[lb1]);
    __syncthreads();
    bf8 ah[4], bh4[4];
#pragma unroll
    for (int m = 0; m < 4; ++m) ah[m] = *(const bf8*)&AhS[aoff[m]];
#pragma unroll
    for (int n = 0; n < 4; ++n) bh4[n] = *(const bf8*)&BhS[boff[n]];
#pragma unroll
    for (int m = 0; m < 4; ++m)
#pragma unroll
      for (int n = 0; n < 4; ++n)
        acc[m][n] = __builtin_amdgcn_mfma_f32_16x16x32_bf16(ah[m], bh4[n], acc[m][n], 0, 0, 0);
  }

  float bcol[4];
#pragma unroll
  for (int n = 0; n < 4; ++n) bcol[n] = bias[bn + wc * 64 + n * 16 + fr];
#pragma unroll
  for (int m = 0; m < 4; ++m)
#pragma unroll
    for (int r = 0; r < 4; ++r) {
      int row = bm + wr * 64 + m * 16 + fs * 4 + r;
      if (row < M) {
#pragma unroll
        for (int n = 0; n < 4; ++n) {
          int col = bn + wc * 64 + n * 16 + fr;
          float v = acc[m][n][r] + bcol[n];
          if (dogelu) v = gelu_exact(v);
          size_t o = (size_t)row * N + col;
          unsigned short h = f2bf(v);
          Ch[o] = h;
          if (Cl) Cl[o] = f2bf(v - bf2f(h));
        }
      }
    }
}

// ---------------- fused QKV GEMM: B=[1536][512] hi; dest selected per n-tile ----------------
__global__ __launch_bounds__(256, 4) void k_mmqkv(
    const unsigned short* __restrict__ Ah,
    const unsigned short* __restrict__ Bh,
    const float* __restrict__ bq, const float* __restrict__ bk,
    const float* __restrict__ bv,
    unsigned short* __restrict__ Qh, unsigned short* __restrict__ Kh,
    unsigned short* __restrict__ Vh,
    int M, int K, const int* __restrict__ Mdyn) {
  if (Mdyn) M = *Mdyn;
  const int bm = blockIdx.y * 128;
  if (bm >= M) return;
  const int bn = blockIdx.x * 128;   // in [0,1536)
  const int sel = bn >> 9;
  unsigned short* Ch = sel == 0 ? Qh : (sel == 1 ? Kh : Vh);
  const float* bias = sel == 0 ? bq : (sel == 1 ? bk : bv);
  const int cb = bn & 511;

  __shared__ __align__(16) unsigned short AhS[4096], BhS[4096];

  const int tid = threadIdx.x;
  const int wave = tid >> 6, lane = tid & 63;
  const int wr = wave >> 1, wc = wave & 1;
  const int fr = lane & 15, fs = lane >> 4;

  const int row0 = tid >> 2;
  const int s0 = (tid & 3) ^ ((row0 >> 1) & 3);
  const unsigned short* gAh0 = Ah + (size_t)(bm + row0) * K + s0 * 8;
  const unsigned short* gAh1 = gAh0 + (size_t)64 * K;
  const unsigned short* gBh0 = Bh + (size_t)(bn + row0) * K + s0 * 8;
  const unsigned short* gBh1 = gBh0 + (size_t)64 * K;
  const int lb0 = wave * 512, lb1 = 2048 + wave * 512;

  int aoff[4], boff[4];
#pragma unroll
  for (int m = 0; m < 4; ++m) {
    int ra = wr * 64 + m * 16 + fr;
    aoff[m] = ra * 32 + 8 * (fs ^ ((ra >> 1) & 3));
    int rb = wc * 64 + m * 16 + fr;
    boff[m] = rb * 32 + 8 * (fs ^ ((rb >> 1) & 3));
  }

  f32x4 acc[4][4];
#pragma unroll
  for (int m = 0; m < 4; ++m)
#pragma unroll
    for (int n = 0; n < 4; ++n) acc[m][n] = (f32x4){0.f, 0.f, 0.f, 0.f};

  for (int k0 = 0; k0 < K; k0 += 32) {
    __syncthreads();
    gll16(gAh0 + k0, &AhS[lb0]); gll16(gAh1 + k0, &AhS[lb1]);
    gll16(gBh0 + k0, &BhS[lb0]); gll16(gBh1 + k0, &BhS[lb1]);
    __syncthreads();
    bf8 ah[4], bh4[4];
#pragma unroll
    for (int m = 0; m < 4; ++m) ah[m] = *(const bf8*)&AhS[aoff[m]];
#pragma unroll
    for (int n = 0; n < 4; ++n) bh4[n] = *(const bf8*)&BhS[boff[n]];
#pragma unroll
    for (int m = 0; m < 4; ++m)
#pragma unroll
      for (int n = 0; n < 4; ++n)
        acc[m][n] = __builtin_amdgcn_mfma_f32_16x16x32_bf16(ah[m], bh4[n], acc[m][n], 0, 0, 0);
  }

  float bcol[4];
#pragma unroll
  for (int n = 0; n < 4; ++n) bcol[n] = bias[cb + wc * 64 + n * 16 + fr];
#pragma unroll
  for (int m = 0; m < 4; ++m)
#pragma unroll
    for (int r = 0; r < 4; ++r) {
      int row = bm + wr * 64 + m * 16 + fs * 4 + r;
      if (row < M) {
#pragma unroll
        for (int n = 0; n < 4; ++n) {
          int col = cb + wc * 64 + n * 16 + fr;
          Ch[(size_t)row * 512 + col] = f2bf(acc[m][n][r] + bcol[n]);
        }
      }
    }
}

// ---------------- split-K reduce 16 (+bias) ----------------
__global__ void k_red16(const float* __restrict__ part, const float* __restrict__ eb,
                        float* __restrict__ dst) {
  int idx = blockIdx.x * 256 + threadIdx.x;   // 1024*512
  float s = eb ? eb[idx & 511] : 0.f;
#pragma unroll
  for (int zz = 0; zz < 16; ++zz) s += part[(size_t)zz * 524288 + idx];
  dst[idx] = s;
}

// ---------------- split-K reduce 8 -> bf16 hi (W' fold) ----------------
__global__ void k_redsplit(const float* __restrict__ part, unsigned short* __restrict__ WH) {
  int idx = blockIdx.x * 256 + threadIdx.x;   // 1024*512
  float s = 0.f;
#pragma unroll
  for (int zz = 0; zz < 8; ++zz) s += part[(size_t)zz * 524288 + idx];
  WH[idx] = f2bf(s);
}

// ---------------- bf16 repack G[(b,s),(c,n)] -> G2[(b,n),(c,s)] ----------------
__global__ __launch_bounds__(256) void k_repackb(const unsigned short* __restrict__ G,
                                                 unsigned short* __restrict__ G2) {
  int bid = blockIdx.x;
  int st = bid & 15, c = (bid >> 4) & 31, b = bid >> 9;
  __shared__ unsigned short tile[32][34];
  int tid = threadIdx.x;
  int n = tid & 31, s = tid >> 5;
  for (int q = 0; q < 4; ++q) {
    int ss = s + q * 8;
    tile[ss][n] = G[((size_t)b * T_ + st * 32 + ss) * 1024 + c * 32 + n];
  }
  __syncthreads();
  int s2 = tid & 31, n2 = tid >> 5;
  for (int q = 0; q < 4; ++q) {
    int nn = n2 + q * 8;
    G2[((size_t)b * 32 + nn) * 16384 + c * 512 + st * 32 + s2] = tile[s2][nn];
  }
}

// ---------------- lw projection + residual + LN -> cur fp32 AND A0 planes ----------------
__global__ __launch_bounds__(256) void k_lwln(const float* __restrict__ osm,
                                              const float* __restrict__ lw,
                                              const float* __restrict__ lb,
                                              const float* __restrict__ curIn,
                                              const float* __restrict__ g,
                                              const float* __restrict__ bt,
                                              float* __restrict__ curOut,
                                              unsigned short* __restrict__ xh,
                                              unsigned short* __restrict__ xl,
                                              const int* __restrict__ meta, int iter) {
  int tok = blockIdx.x;
  int b = tok >> 9, t = tok & 511;
  __shared__ float os[C_];
  __shared__ float red[256];
  int tid = threadIdx.x;
  if (tid < C_) os[tid] = osm[((size_t)b * C_ + tid) * T_ + t];
  __syncthreads();
  float val[2];
#pragma unroll
  for (int q = 0; q < 2; ++q) {
    int m = tid + q * 256;
    float s = lb[m] + curIn[(size_t)tok * N_ + m];
    for (int n2 = 0; n2 < C_; ++n2) s += os[n2] * lw[n2 * N_ + m];
    val[q] = s;
  }
  red[tid] = val[0] + val[1];
  __syncthreads();
  for (int off = 128; off > 0; off >>= 1) { if (tid < off) red[tid] += red[tid + off]; __syncthreads(); }
  float mean = red[0] * (1.0f / N_);
  __syncthreads();
  float d0 = val[0] - mean, d1 = val[1] - mean;
  red[tid] = d0 * d0 + d1 * d1;
  __syncthreads();
  for (int off = 128; off > 0; off >>= 1) { if (tid < off) red[tid] += red[tid + off]; __syncthreads(); }
  float inv = rsqrtf(red[0] * (1.0f / N_) + EPS_);
  float o0 = d0 * inv * g[tid] + bt[tid];
  float o1 = d1 * inv * g[tid + 256] + bt[tid + 256];
  curOut[(size_t)tok * N_ + tid] = o0;
  curOut[(size_t)tok * N_ + tid + 256] = o1;
  int L = meta[6 + iter];
  size_t pi = ((size_t)b * L + t) * N_;
  st2(xh, xl, pi + tid, o0);
  st2(xh, xl, pi + tid + 256, o1);
}

// ---------------- zero pad rows l in [T,L) of A0 planes ----------------
__global__ void k_padtail(unsigned short* __restrict__ xh, unsigned short* __restrict__ xl,
                          const int* __restrict__ meta, int iter) {
  int L = meta[6 + iter];
  int pad = L - T_;
  if (pad <= 0) return;
  size_t total = (size_t)B_ * pad * N_;
  for (size_t idx = (size_t)blockIdx.x * 256 + threadIdx.x; idx < total;
       idx += (size_t)gridDim.x * 256) {
    size_t row = idx >> 9;
    int d = (int)(idx & 511);
    int b = (int)(row / pad), l = T_ + (int)(row % pad);
    size_t o = ((size_t)b * L + l) * N_ + d;
    xh[o] = 0; xl[o] = 0;
  }
}

// ---------------- residual add + LN (planes in, planes out) ----------------
__global__ __launch_bounds__(256) void k_lnadd(const unsigned short* __restrict__ r1h,
                                               const unsigned short* __restrict__ r1l,
                                               const unsigned short* __restrict__ r2h,
                                               const unsigned short* __restrict__ r2l,
                                               const float* __restrict__ g,
                                               const float* __restrict__ bt,
                                               unsigned short* __restrict__ dh,
                                               unsigned short* __restrict__ dl,
                                               const int* __restrict__ meta, int iter) {
  int tokens = meta[15 + iter];
  int tok = blockIdx.x;
  if (tok >= tokens) return;
  __shared__ float red[256];
  int tid = threadIdx.x;
  float val[2];
#pragma unroll
  for (int q = 0; q < 2; ++q) {
    size_t i = (size_t)tok * N_ + tid + q * 256;
    val[q] = ld2(r1h, r1l, i) + ld2(r2h, r2l, i);
  }
  red[tid] = val[0] + val[1];
  __syncthreads();
  for (int off = 128; off > 0; off >>= 1) { if (tid < off) red[tid] += red[tid + off]; __syncthreads(); }
  float mean = red[0] * (1.0f / N_);
  __syncthreads();
  float d0 = val[0] - mean, d1 = val[1] - mean;
  red[tid] = d0 * d0 + d1 * d1;
  __syncthreads();
  for (int off = 128; off > 0; off >>= 1) { if (tid < off) red[tid] += red[tid + off]; __syncthreads(); }
  float inv = rsqrtf(red[0] * (1.0f / N_) + EPS_);
  st2(dh, dl, (size_t)tok * N_ + tid, d0 * inv * g[tid] + bt[tid]);
  st2(dh, dl, (size_t)tok * N_ + tid + 256, d1 * inv * g[tid + 256] + bt[tid + 256]);
}

// ---------------- fused: LN(r1+r2) -> LN -> gelu -> weighted accumulate ----------------
__global__ __launch_bounds__(256) void k_lnfin(const unsigned short* __restrict__ r1h,
                                               const unsigned short* __restrict__ r1l,
                                               const unsigned short* __restrict__ r2h,
                                               const unsigned short* __restrict__ r2l,
                                               const float* __restrict__ g1,
                                               const float* __restrict__ b1,
                                               const float* __restrict__ g2,
                                               const float* __restrict__ b2,
                                               const float* __restrict__ swb,
                                               float* __restrict__ acc,
                                               const int* __restrict__ meta, int iter) {
  int L = meta[6 + iter];
  int tok = blockIdx.x;
  if (tok >= B_ * L) return;
  int b = tok / L, l = tok % L;
  if (l >= T_) return;   // truncated away
  __shared__ float red[256];
  int tid = threadIdx.x;
  float val[2];
#pragma unroll
  for (int q = 0; q < 2; ++q) {
    size_t i = (size_t)tok * N_ + tid + q * 256;
    val[q] = ld2(r1h, r1l, i) + ld2(r2h, r2l, i);
  }
  red[tid] = val[0] + val[1];
  __syncthreads();
  for (int off = 128; off > 0; off >>= 1) { if (tid < off) red[tid] += red[tid + off]; __syncthreads(); }
  float mean = red[0] * (1.0f / N_);
  __syncthreads();
  float d0 = val[0] - mean, d1 = val[1] - mean;
  red[tid] = d0 * d0 + d1 * d1;
  __syncthreads();
  for (int off = 128; off > 0; off >>= 1) { if (tid < off) red[tid] += red[tid + off]; __syncthreads(); }
  float inv = rsqrtf(red[0] * (1.0f / N_) + EPS_);
  float y0 = d0 * inv * g1[tid] + b1[tid];
  float y1 = d1 * inv * g1[tid + 256] + b1[tid + 256];
  // second LN over y
  __syncthreads();
  red[tid] = y0 + y1;
  __syncthreads();
  for (int off = 128; off > 0; off >>= 1) { if (tid < off) red[tid] += red[tid + off]; __syncthreads(); }
  float mean2 = red[0] * (1.0f / N_);
  __syncthreads();
  float e0 = y0 - mean2, e1 = y1 - mean2;
  red[tid] = e0 * e0 + e1 * e1;
  __syncthreads();
  for (int off = 128; off > 0; off >>= 1) { if (tid < off) red[tid] += red[tid + off]; __syncthreads(); }
  float inv2 = rsqrtf(red[0] * (1.0f / N_) + EPS_);
  float s = swb[b * 4 + iter];
  float u0 = gelu_exact(e0 * inv2 * g2[tid] + b2[tid]);
  float u1 = gelu_exact(e1 * inv2 * g2[tid + 256] + b2[tid + 256]);
  size_t o = ((size_t)b * T_ + l) * N_;
  acc[o + tid] += s * u0;
  acc[o + tid + 256] += s * u1;
}

// ---------------- attention S<=32: wave-per-pair, lane=t scores, barrier-free ----------------
__global__ __launch_bounds__(256) void k_attn32(
    const unsigned short* __restrict__ qh,
    const unsigned short* __restrict__ kh,
    const unsigned short* __restrict__ vh,
    unsigned short* __restrict__ oh,
    const int* __restrict__ meta, int iter) {
  int S = meta[3 + iter];
  if (S > 32) return;
  int L = meta[6 + iter], nseq = meta[9 + iter];
  int npair = B_ * nseq * 8;
  __shared__ unsigned short Kts[4][64 * 33];
  __shared__ unsigned short Vsh[4][32 * 66];
  __shared__ float qs[4][64];
  int tid = threadIdx.x;
  int wave = tid >> 6, lane = tid & 63;
  unsigned short* Ktw = Kts[wave];
  unsigned short* Vw = Vsh[wave];
  int gw = (blockIdx.x * 256 + tid) >> 6;
  int nw = (gridDim.x * 256) >> 6;
  const int tt = lane & 31;
  const int hf = lane >> 5;
  for (int pair = gw; pair < npair; pair += nw) {
    int h = pair & 7;
    int m = pair >> 3;
    int b = m / nseq, g2 = m - b * nseq;
    size_t base = ((size_t)b * L + (size_t)g2 * S) * N_ + h * 64;
    for (int i = lane; i < S * 64; i += 64) {
      int t = i >> 6, d = i & 63;
      size_t gi = base + (size_t)t * N_ + d;
      Ktw[d * 33 + t] = kh[gi];
      Vw[t * 66 + d] = vh[gi];
    }
    bool tok = tt < S;
    for (int s = 0; s < S; ++s) {
      qs[wave][lane] = bf2f(qh[base + (size_t)s * N_ + lane]);
      float part = 0.f;
      if (tok) {
        const unsigned short* kp = &Ktw[hf * 32 * 33 + tt];
        const float* qp = &qs[wave][hf * 32];
#pragma unroll 8
        for (int j = 0; j < 32; ++j) part += qp[j] * bf2f(kp[j * 33]);
      }
      part += __shfl_xor(part, 32);
      float sc = tok ? part * 0.125f : -3.0e38f;
      float mx = sc;
      for (int off = 16; off > 0; off >>= 1) mx = fmaxf(mx, __shfl_xor(mx, off));
      float p = tok ? __expf(sc - mx) : 0.f;
      float ssum = p;
      for (int off = 16; off > 0; off >>= 1) ssum += __shfl_xor(ssum, off);
      float ov = 0.f;
      for (int t = 0; t < S; ++t) {
        float pt = __shfl(p, t);
        ov += pt * bf2f(Vw[t * 66 + lane]);
      }
      oh[base + (size_t)s * N_ + lane] = f2bf(ov / ssum);
    }
  }
}

// ---------------- MFMA flash attention, 32<S<=128: one block per (seq,head) ----------------
// VT swizzle uses (d>>3)&3 so the 8 same-row scatter lanes (d = c8*8+q) spread
// across bank groups (was 8-way conflict with (d>>1)&3, which is d+8-invariant).
__global__ __launch_bounds__(256, 3) void k_attn_small(
    const unsigned short* __restrict__ qh,
    const unsigned short* __restrict__ kh,
    const unsigned short* __restrict__ vh,
    unsigned short* __restrict__ oh,
    const int* __restrict__ meta, int iter) {
  int S = meta[3 + iter];
  if (S <= 32 || S > 128) return;
  int L = meta[6 + iter], nseq = meta[9 + iter];
  int M = B_ * nseq;
  int mh = blockIdx.x;
  int m0 = mh >> 3, h = mh & 7;
  if (m0 >= M) return;
  int b = m0 / nseq, g2 = m0 % nseq;
  size_t tok0 = (size_t)b * L + (size_t)g2 * S;

  // U: QK phase = {Q kstep0, Q kstep1, K kstep0, K kstep1}; PV phase = P[4 ksteps]
  __shared__ __align__(16) unsigned short U[16384];
  __shared__ __align__(16) unsigned short VT[8192];   // V^T, 4 k-steps [64][32]
  __shared__ float rb1[2][128], rb2[2][128];

  const int tid = threadIdx.x;
  const int wave = tid >> 6, lane = tid & 63;
  const int wr = wave >> 1, wc = wave & 1;
  const int fr = lane & 15, fs = lane >> 4;

  // ---- stage Q,K via global_load_lds (mmb1 pattern, K=64 -> 2 k-steps) ----
  const int row0 = tid >> 2;
  const int s0 = (tid & 3) ^ ((row0 >> 1) & 3);
  const unsigned short* gQ0 = qh + (tok0 + row0) * N_ + h * 64 + s0 * 8;
  const unsigned short* gQ1 = gQ0 + (size_t)64 * N_;
  const unsigned short* gK0 = kh + (tok0 + row0) * N_ + h * 64 + s0 * 8;
  const unsigned short* gK1 = gK0 + (size_t)64 * N_;
  const int lb0 = wave * 512, lb1 = 2048 + wave * 512;
  gll16(gQ0,      &U[lb0]);         gll16(gQ1,      &U[lb1]);
  gll16(gQ0 + 32, &U[4096 + lb0]);  gll16(gQ1 + 32, &U[4096 + lb1]);
  gll16(gK0,      &U[8192 + lb0]);  gll16(gK1,      &U[8192 + lb1]);
  gll16(gK0 + 32, &U[12288 + lb0]); gll16(gK1 + 32, &U[12288 + lb1]);
  // ---- stage V^T via reg transpose; swizzle on (d>>3)&3 -> 2-way writes ----
  for (int i = tid; i < 128 * 8; i += 256) {
    int t = i >> 3, c8 = i & 7;
    u16x8 vv8 = *(const u16x8*)&vh[(tok0 + t) * N_ + h * 64 + c8 * 8];
    int kk = t >> 5, chunk = (t & 31) >> 3, e = t & 7;
#pragma unroll
    for (int q = 0; q < 8; ++q) {
      int d = c8 * 8 + q;
      VT[kk * 2048 + d * 32 + 8 * (chunk ^ ((d >> 3) & 3)) + e] = vv8[q];
    }
  }
  __syncthreads();

  // ---- QK^T: scores[q][k] ----
  int aoff[4], boff[4];
#pragma unroll
  for (int m = 0; m < 4; ++m) {
    int ra = wr * 64 + m * 16 + fr;
    aoff[m] = ra * 32 + 8 * (fs ^ ((ra >> 1) & 3));
    int rb = wc * 64 + m * 16 + fr;
    boff[m] = rb * 32 + 8 * (fs ^ ((rb >> 1) & 3));
  }
  f32x4 acc[4][4];
#pragma unroll
  for (int m = 0; m < 4; ++m)
#pragma unroll
    for (int n = 0; n < 4; ++n) acc[m][n] = (f32x4){0.f, 0.f, 0.f, 0.f};
#pragma unroll
  for (int kk = 0; kk < 2; ++kk) {
    bf8 ah[4], bh[4];
#pragma unroll
    for (int m = 0; m < 4; ++m) ah[m] = *(const bf8*)&U[kk * 4096 + aoff[m]];
#pragma unroll
    for (int n = 0; n < 4; ++n) bh[n] = *(const bf8*)&U[8192 + kk * 4096 + boff[n]];
#pragma unroll
    for (int m = 0; m < 4; ++m)
#pragma unroll
      for (int n = 0; n < 4; ++n)
        acc[m][n] = __builtin_amdgcn_mfma_f32_16x16x32_bf16(ah[m], bh[n], acc[m][n], 0, 0, 0);
  }

  // ---- mask + scale; row-max partials ----
  bool colok[4];
#pragma unroll
  for (int n = 0; n < 4; ++n) colok[n] = (wc * 64 + n * 16 + fr) < S;
#pragma unroll
  for (int m = 0; m < 4; ++m)
#pragma unroll
    for (int n = 0; n < 4; ++n)
#pragma unroll
      for (int r = 0; r < 4; ++r)
        acc[m][n][r] = colok[n] ? acc[m][n][r] * 0.125f : -3.0e38f;
#pragma unroll
  for (int m = 0; m < 4; ++m)
#pragma unroll
    for (int r = 0; r < 4; ++r) {
      float pm = fmaxf(fmaxf(acc[m][0][r], acc[m][1][r]), fmaxf(acc[m][2][r], acc[m][3][r]));
      pm = fmaxf(pm, __shfl_xor(pm, 1));
      pm = fmaxf(pm, __shfl_xor(pm, 2));
      pm = fmaxf(pm, __shfl_xor(pm, 4));
      pm = fmaxf(pm, __shfl_xor(pm, 8));
      if (fr == 0) rb1[wc][wr * 64 + m * 16 + fs * 4 + r] = pm;
    }
  __syncthreads();   // rb1 ready; all U fragment reads complete

  // ---- exp + row-sum partials; scatter P (bf16) into U as PV A-operand ----
#pragma unroll
  for (int m = 0; m < 4; ++m)
#pragma unroll
    for (int r = 0; r < 4; ++r) {
      int row = wr * 64 + m * 16 + fs * 4 + r;
      float mx = fmaxf(rb1[0][row], rb1[1][row]);
      float ps = 0.f;
#pragma unroll
      for (int n = 0; n < 4; ++n) {
        float e = __expf(acc[m][n][r] - mx);
        acc[m][n][r] = e;
        ps += e;
      }
      ps += __shfl_xor(ps, 1);
      ps += __shfl_xor(ps, 2);
      ps += __shfl_xor(ps, 4);
      ps += __shfl_xor(ps, 8);
      if (fr == 0) rb2[wc][row] = ps;
    }
#pragma unroll
  for (int m = 0; m < 4; ++m)
#pragma unroll
    for (int n = 0; n < 4; ++n) {
      int col = wc * 64 + n * 16 + fr;
      int kk = col >> 5, chunk = (col & 31) >> 3, e = col & 7;
#pragma unroll
      for (int r = 0; r < 4; ++r) {
        int row = wr * 64 + m * 16 + fs * 4 + r;
        U[kk * 4096 + row * 32 + 8 * (chunk ^ ((row >> 1) & 3)) + e] = f2bf(acc[m][n][r]);
      }
    }
  __syncthreads();   // P + rb2 ready

  // ---- PV: out[q][d] = sum_t P[q][t] * VT[d][t]; waves split rows (32 each) ----
  int nk = (S + 31) >> 5;
  int aoff2[2], boff2[4];
#pragma unroll
  for (int m = 0; m < 2; ++m) {
    int ra = wave * 32 + m * 16 + fr;
    aoff2[m] = ra * 32 + 8 * (fs ^ ((ra >> 1) & 3));
  }
#pragma unroll
  for (int n = 0; n < 4; ++n) {
    int rb = n * 16 + fr;
    boff2[n] = rb * 32 + 8 * (fs ^ ((rb >> 3) & 3));
  }
  f32x4 o2[2][4];
#pragma unroll
  for (int m = 0; m < 2; ++m)
#pragma unroll
    for (int n = 0; n < 4; ++n) o2[m][n] = (f32x4){0.f, 0.f, 0.f, 0.f};
  for (int kk = 0; kk < nk; ++kk) {
    bf8 pa[2], vb[4];
#pragma unroll
    for (int m = 0; m < 2; ++m) pa[m] = *(const bf8*)&U[kk * 4096 + aoff2[m]];
#pragma unroll
    for (int n = 0; n < 4; ++n) vb[n] = *(const bf8*)&VT[kk * 2048 + boff2[n]];
#pragma unroll
    for (int m = 0; m < 2; ++m)
#pragma unroll
      for (int n = 0; n < 4; ++n)
        o2[m][n] = __builtin_amdgcn_mfma_f32_16x16x32_bf16(pa[m], vb[n], o2[m][n], 0, 0, 0);
  }

  // ---- epilogue: divide by row sums, write ----
#pragma unroll
  for (int m = 0; m < 2; ++m)
#pragma unroll
    for (int r = 0; r < 4; ++r) {
      int orow = wave * 32 + m * 16 + fs * 4 + r;
      if (orow < S) {
        float inv = 1.0f / (rb2[0][orow] + rb2[1][orow]);
#pragma unroll
        for (int n = 0; n < 4; ++n)
          oh[(tok0 + orow) * N_ + h * 64 + n * 16 + fr] = f2bf(o2[m][n][r] * inv);
      }
    }
}

// ---------------- fused attention, 128<S<=512 — barrier-free waves ----------------
__global__ __launch_bounds__(256) void k_attn_big(
    const unsigned short* __restrict__ qh,
    const unsigned short* __restrict__ kh,
    const unsigned short* __restrict__ vh,
    unsigned short* __restrict__ oh,
    const int* __restrict__ meta, int iter) {
  int p = meta[3 + iter];
  if (p <= 128) return;
  int L = meta[6 + iter], nseq = meta[9 + iter];
  int M = B_ * nseq;
  int mh = blockIdx.x;
  int m = mh >> 3, h = mh & 7;
  if (m >= M) return;
  int S = p;
  int b = m / nseq, g2 = m % nseq;
  size_t tok0 = (size_t)b * L + (size_t)g2 * S;
  __shared__ unsigned short Ks[512 * 66];
  __shared__ unsigned short Vs[512 * 66];
  __shared__ float qrow[4][64];
  __shared__ float Pr[4][512];
  int tid = threadIdx.x;
  for (int i = tid; i < S * 64; i += 256) {
    int t = i >> 6, d = i & 63;
    size_t gi = (tok0 + t) * N_ + h * 64 + d;
    Ks[t * 66 + d] = kh[gi];
    Vs[t * 66 + d] = vh[gi];
  }
  __syncthreads();   // only barrier
  int wave = tid >> 6, lane = tid & 63;
  for (int s = wave; s < S; s += 4) {
    qrow[wave][lane] = bf2f(qh[(tok0 + s) * N_ + h * 64 + lane]);
    const float2* qp = (const float2*)&qrow[wave][0];
    float sc[8];
    float mx = -3.0e38f;
#pragma unroll
    for (int c2 = 0; c2 < 8; ++c2) {
      int t = lane + c2 * 64;
      float sv = -3.0e38f;
      if (t < S) {
        const unsigned int* kp = (const unsigned int*)&Ks[t * 66];
        float ad = 0.f;
#pragma unroll
        for (int j2 = 0; j2 < 32; ++j2) {
          float2 qq = qp[j2];
          unsigned int kw = kp[j2];
          ad += qq.x * bf2f((unsigned short)(kw & 0xffffu));
          ad += qq.y * bf2f((unsigned short)(kw >> 16));
        }
        sv = ad * 0.125f;
      }
      sc[c2] = sv;
      mx = fmaxf(mx, sv);
    }
    for (int off = 32; off > 0; off >>= 1) mx = fmaxf(mx, __shfl_xor(mx, off));
    float ssum = 0.f;
#pragma unroll
    for (int c2 = 0; c2 < 8; ++c2) {
      int t = lane + c2 * 64;
      float e = 0.f;
      if (t < S) { e = __expf(sc[c2] - mx); Pr[wave][t] = e; }
      ssum += e;
    }
    for (int off = 32; off > 0; off >>= 1) ssum += __shfl_xor(ssum, off);
    float inv = 1.0f / ssum;
    float ov = 0.f;
#pragma unroll 8
    for (int t = 0; t < S; ++t) ov += Pr[wave][t] * bf2f(Vs[t * 66 + lane]);
    oh[(tok0 + s) * N_ + h * 64 + lane] = f2bf(ov * inv);
  }
}

// ---------------- final output ----------------
__global__ void k_final(const float* __restrict__ acc, const float* __restrict__ cur,
                        float* __restrict__ out) {
  size_t idx = (size_t)blockIdx.x * 256 + threadIdx.x;
  out[idx] = acc[idx] + cur[idx];
}

extern "C" void kernel_launch(void* const* d_in, const int* in_sizes, int n_in,
                              void* d_out, int out_size, void* d_ws, size_t ws_size,
                              hipStream_t stream) {
  (void)in_sizes; (void)n_in; (void)out_size; (void)ws_size;
  const float* x       = (const float*)d_in[0];
  const float* nv1     = (const float*)d_in[1];
  const float* nv2     = (const float*)d_in[2];
  const float* start_w = (const float*)d_in[3];
  const float* start_b = (const float*)d_in[4];
  const float* mix_w   = (const float*)d_in[5];
  const float* mix_b   = (const float*)d_in[6];
  const float* end_w   = (const float*)d_in[7];
  const float* end_b   = (const float*)d_in[8];
  const float* glin_w  = (const float*)d_in[9];
  const float* glin_b  = (const float*)d_in[10];
  const float* gnorm_g = (const float*)d_in[11];
  const float* gnorm_b = (const float*)d_in[12];
  const float* wq = (const float*)d_in[13];
  const float* bq = (const float*)d_in[14];
  const float* wk = (const float*)d_in[15];
  const float* bk = (const float*)d_in[16];
  const float* wv = (const float*)d_in[17];
  const float* bv = (const float*)d_in[18];
  const float* wo = (const float*)d_in[19];
  const float* bo = (const float*)d_in[20];
  const float* ff1w = (const float*)d_in[21];
  const float* ff1b = (const float*)d_in[22];
  const float* ff2w = (const float*)d_in[23];
  const float* ff2b = (const float*)d_in[24];
  const float* an1g = (const float*)d_in[25];
  const float* an1b = (const float*)d_in[26];
  const float* an2g = (const float*)d_in[27];
  const float* an2b = (const float*)d_in[28];
  const float* nrmg = (const float*)d_in[29];
  const float* nrmb = (const float*)d_in[30];

  char* ws = (char*)d_ws;
  int*   meta = (int*)(ws + OFF_META);
  float* freq = (float*)(ws + OFF_FREQ);
  float* swb  = (float*)(ws + OFF_SW);
  float* beff = (float*)(ws + OFF_BEFF);
  float* P12  = (float*)(ws + OFF_P12);
  float* fsumb = (float*)(ws + OFF_FSB);
  float* osm  = (float*)(ws + OFF_OSM);
  unsigned short* TWH = (unsigned short*)(ws + OFF_TWH);
  unsigned short* TWL = (unsigned short*)(ws + OFF_TWL);
  unsigned short* WB  = (unsigned short*)(ws + OFF_WB);
  unsigned short* WdH = (unsigned short*)(ws + OFF_WDH);
  unsigned short* EWH = (unsigned short*)(ws + OFF_EWH);
  float* cur  = (float*)(ws + OFF_CUR);
  float* accb = (float*)(ws + OFF_ACC);
  unsigned short* XWH = (unsigned short*)(ws + OFF_XWH);
  float* fpart = (float*)(ws + OFF_FP);
  float* Tm   = (float*)(ws + OFF_T);
  unsigned short* WPH = (unsigned short*)(ws + OFF_WPH);
  unsigned short* Gb  = (unsigned short*)(ws + OFF_G);
  unsigned short* G2b = (unsigned short*)(ws + OFF_G2);
  float* PART = (float*)(ws + OFF_PART);
  unsigned short* A0h = (unsigned short*)(ws + OFF_A0); unsigned short* A0l = A0h + PLW;
  unsigned short* A2h = (unsigned short*)(ws + OFF_A2); unsigned short* A2l = A2h + PLW;
  unsigned short* A3h = (unsigned short*)(ws + OFF_A3); unsigned short* A3l = A3h + PLW;
  unsigned short* A4h = (unsigned short*)(ws + OFF_A4);
  unsigned short* A5h = (unsigned short*)(ws + OFF_A5); unsigned short* A5l = A5h + PLW;

  hipMemsetAsync(accb, 0, (size_t)B_ * T_ * N_ * 4, stream);

  // ---- STFT via MFMA (window on twiddle side ONLY; x-hi only, twiddles hi+lo) ----
  k_xw<<<B_ * NFR_, 256, 0, stream>>>(x, XWH);
  k_tw<<<(2 * 384 * 64 + 255) / 256, 256, 0, stream>>>(TWH, TWL);
  k_stftmm<<<dim3(3, NMT_), 256, 0, stream>>>(XWH, TWH, TWL, fpart);
  k_fred<<<NBIN_, 256, 0, stream>>>(fpart, freq, fsumb);
  k_topk<<<1, 64, 0, stream>>>(freq, fsumb, meta, swb);

  // split attention/FF weights into bf16 hi planes (once); Q,K,V contiguous
  const float* wlist[6] = {wq, wk, wv, wo, ff1w, ff2w};
  for (int w = 0; w < 6; ++w)
    k_splith<<<256, 256, 0, stream>>>(wlist[w], WB + (size_t)w * 262144, 262144);
  unsigned short* WqkvH = WB;              // [1536][512]
  unsigned short* WoH = WB + 3 * 262144;
  unsigned short* F1H = WB + 4 * 262144;
  unsigned short* F2H = WB + 5 * 262144;

  const float* curIn = x;
  for (int i = 0; i < 3; ++i) {
    // ---- graph block: fold conv+GCN+mix into one weight W' = T @ Wd ----
    k_adjprep<<<1, 1024, 0, stream>>>(nv1 + i * C_ * 10, nv2 + i * 10 * C_,
                                      mix_w + i * C_ * 96, mix_b + i * C_,
                                      start_b + i * C_, P12, beff);
    k_T<<<4096, 256, 0, stream>>>(P12, mix_w + i * C_ * 96, Tm);
    k_wdh<<<2048, 256, 0, stream>>>(start_w + i * C_ * KH_, WdH);
    k_mm2<<<dim3(4, 8, 8), 256, 0, stream>>>(Tm, WdH, nullptr, nullptr, PART,
                                             1024, 512, 1024, 1024, 0);
    k_redsplit<<<2048, 256, 0, stream>>>(PART, WPH);
    // G = gelu(curIn @ W'^T + b_eff)   [16384 x 1024] bf16
    k_mmcv<<<dim3(8, 128), 256, 0, stream>>>(curIn, WPH, beff, Gb, 16384, 1024, 512, 512);
    k_repackb<<<B_ * C_ * 16, 256, 0, stream>>>(Gb, G2b);
    k_splith<<<8192, 256, 0, stream>>>(end_w + (size_t)i * 8388608, EWH, 8388608);
    k_mmend<<<dim3(4, 8, 16), 256, 0, stream>>>(G2b, EWH, PART, 1024, 512, 16384);
    k_red16<<<2048, 256, 0, stream>>>(PART, end_b + i * T_, osm);
    k_lwln<<<B_ * T_, 256, 0, stream>>>(osm, glin_w + i * C_ * N_, glin_b + i * N_, curIn,
                                        gnorm_g + i * N_, gnorm_b + i * N_, cur,
                                        A0h, A0l, meta, i);
    k_padtail<<<512, 256, 0, stream>>>(A0h, A0l, meta, i);
    // ---- attention branch ----
    const int* Mdyn = meta + 15 + i;
    dim3 gT(4, TOKMAX / 128, 1);
    k_mmqkv<<<dim3(12, TOKMAX / 128), 256, 0, stream>>>(A0h, WqkvH, bq, bk, bv,
                                                        A2h, A3h, A4h, TOKMAX, 512, Mdyn);
    k_attn32<<<2048, 256, 0, stream>>>(A2h, A3h, A4h, A5h, meta, i);
    k_attn_small<<<4096, 256, 0, stream>>>(A2h, A3h, A4h, A5h, meta, i);
    k_attn_big<<<1024, 256, 0, stream>>>(A2h, A3h, A4h, A5h, meta, i);
    k_mmb1<<<gT, 256, 0, stream>>>(A5h, WoH, bo, A2h, A2l, TOKMAX, 512, 512, Mdyn, 0);
    k_lnadd<<<TOKMAX, 256, 0, stream>>>(A0h, A0l, A2h, A2l, an1g, an1b, A3h, A3l, meta, i);
    k_mmb1<<<gT, 256, 0, stream>>>(A3h, F1H, ff1b, A4h, nullptr, TOKMAX, 512, 512, Mdyn, 1);
    k_mmb1<<<gT, 256, 0, stream>>>(A4h, F2H, ff2b, A5h, A5l, TOKMAX, 512, 512, Mdyn, 0);
    k_lnfin<<<TOKMAX, 256, 0, stream>>>(A3h, A3l, A5h, A5l, an2g, an2b, nrmg, nrmb,
                                        swb, accb, meta, i);
    curIn = cur;
  }
  k_final<<<(B_ * T_ * N_) / 256, 256, 0, stream>>>(accb, curIn, (float*)d_out);
}

// Round 26
// 1804.789 us; speedup vs baseline: 1.1040x; 1.0246x over previous
//
#include <hip/hip_runtime.h>
#include <math.h>

#define DI __device__ __forceinline__

namespace {
constexpr int B_ = 32;
constexpr int T_ = 512;
constexpr int N_ = 512;   // d_model
constexpr int C_ = 32;    // c_out / conv_ch / skip_ch
constexpr int KH_ = 481;
constexpr int HOP_ = 48;
constexpr int WIN_ = 48;
constexpr int NFR_ = 11;
constexpr int NBIN_ = 257;
constexpr int NMT_ = B_ * NFR_ * 4;   // 1408 sample-tiles (44 per batch, contiguous)
constexpr int TOKMAX = 21760;   // 170*128 == exact max tokens (L=680)
constexpr int PLW = TOKMAX * 512;     // plane elements for token buffers
constexpr float EPS_ = 1e-5f;

constexpr size_t MBY = 1ull << 20;
constexpr size_t OFF_META = 0;
constexpr size_t OFF_FREQ = 4096;
constexpr size_t OFF_SW   = 8192;
constexpr size_t OFF_BEFF = 16384;       // 1024 floats
constexpr size_t OFF_P12  = 32768;       // 2048 floats
constexpr size_t OFF_FSB  = 65536;       // 257*32 floats (per-(k,b) sums)
constexpr size_t OFF_OSM  = 1 * MBY;     // 2MB (1..3MB)
constexpr size_t OFF_TWH  = 3 * MBY;         // twiddle hi planes [2][384][64] bf16
constexpr size_t OFF_TWL  = 3 * MBY + 131072;// twiddle lo planes
constexpr size_t OFF_WB   = 4 * MBY;     // 6 hi planes x 512KB = 3MB (Q,K,V contiguous!)
constexpr size_t OFF_WDH  = 10 * MBY;    // 1MB  (WdT hi plane [512][1024])
constexpr size_t OFF_EWH  = 12 * MBY;    // 16MB
constexpr size_t OFF_CUR  = 44 * MBY;    // 32MB
constexpr size_t OFF_ACC  = 76 * MBY;    // 32MB
constexpr size_t TR       = 108 * MBY;   // transient union region
// graph phase
constexpr size_t OFF_T    = TR;            // 4MB  T [1024][1024]
constexpr size_t OFF_WPH  = TR + 6 * MBY;  // 1MB  W' hi plane
constexpr size_t OFF_G    = TR + 64 * MBY; // 32MB bf16 [16384][1024]
constexpr size_t OFF_G2   = TR + 128 * MBY;// 32MB bf16 [1024][16384]
constexpr size_t OFF_PART = TR + 192 * MBY;// 32MB [16][1024][512]
// attention phase (aliases graph region): each buffer = hi plane + lo plane
constexpr size_t OFF_A0 = TR;              // 44MB stride each
constexpr size_t OFF_A2 = TR + 44 * MBY;
constexpr size_t OFF_A3 = TR + 88 * MBY;
constexpr size_t OFF_A4 = TR + 132 * MBY;
constexpr size_t OFF_A5 = TR + 176 * MBY;  // ends 328MB
// stft scratch aliases TR (stft completes before graph phase starts)
constexpr size_t OFF_XWH = TR;              // 23MB bf16 [180224][64] (x hi)
constexpr size_t OFF_FP  = TR + 48 * MBY;   // NBIN_*NMT_ floats ~1.45MB
} // namespace

typedef __attribute__((ext_vector_type(2))) float f32x2;
typedef __attribute__((ext_vector_type(4))) float f32x4;
typedef __attribute__((ext_vector_type(8))) short bf8;
typedef __attribute__((ext_vector_type(8))) unsigned short u16x8;

DI float gelu_exact(float x) { return 0.5f * x * (1.0f + erff(x * 0.7071067811865475f)); }
DI unsigned short f2bf(float f) {   // round-to-nearest-even
  unsigned u = __float_as_uint(f);
  u += 0x7FFFu + ((u >> 16) & 1u);
  return (unsigned short)(u >> 16);
}
DI float bf2f(unsigned short s) { return __uint_as_float(((unsigned)s) << 16); }
DI float ld2(const unsigned short* __restrict__ H, const unsigned short* __restrict__ L,
             size_t i) { return bf2f(H[i]) + bf2f(L[i]); }
DI void st2(unsigned short* __restrict__ H, unsigned short* __restrict__ L,
            size_t i, float v) {
  unsigned short h = f2bf(v);
  H[i] = h;
  L[i] = f2bf(v - bf2f(h));
}
DI void gll16(const unsigned short* g, unsigned short* l) {
  __builtin_amdgcn_global_load_lds(
      (const __attribute__((address_space(1))) void*)g,
      (__attribute__((address_space(3))) void*)l, 16, 0, 0);
}

// ---------------- build x-hi frames: XW [180224][64] via LDS transpose ----------------
__global__ __launch_bounds__(256) void k_xw(const float* __restrict__ x,
                                            unsigned short* __restrict__ XWH) {
  int bf = blockIdx.x;            // b*NFR + f
  int f = bf % NFR_, b = bf / NFR_;
  __shared__ unsigned short TS[512 * 58];   // [n][j], pad 58 (stride 29 dw, conflict-free)
  int tid = threadIdx.x;
  // phase 1: coalesced reads (lane = n), LDS write conflict-free
  for (int idx = tid; idx < WIN_ * 512; idx += 256) {
    int j = idx >> 9, n = idx & 511;
    int gi = f * HOP_ + 232 + j - 256;
    if (gi < 0) gi = -gi;   // reflect pad (left only)
    TS[n * 58 + j] = f2bf(x[((size_t)b * T_ + gi) * N_ + n]);
  }
  __syncthreads();
  // phase 2: coalesced 16B global writes
  for (int i = tid; i < 512 * 8; i += 256) {
    int n = i >> 3, jc = i & 7;
    size_t m = (size_t)bf * 512 + n;
    u16x8 v;
    if (jc < 6) {
#pragma unroll
      for (int q = 0; q < 8; ++q) v[q] = TS[n * 58 + jc * 8 + q];
    } else {
#pragma unroll
      for (int q = 0; q < 8; ++q) v[q] = 0;
    }
    *(u16x8*)&XWH[m * 64 + jc * 8] = v;
  }
}

// ---------------- build twiddle hi/lo planes [2][384][64] (window baked in HERE) ----------------
__global__ void k_tw(unsigned short* __restrict__ TWH, unsigned short* __restrict__ TWL) {
  int idx = blockIdx.x * 256 + threadIdx.x;   // 2*384*64 = 49152
  if (idx >= 2 * 384 * 64) return;
  int pl = idx / (384 * 64);
  int rem = idx % (384 * 64);
  int k = rem >> 6, j = rem & 63;
  float v = 0.f;
  if (k < NBIN_ && j < WIN_) {
    int r = (k * (232 + j)) & 511;
    float ang = (float)r * 0.012271846303085130f;   // 2pi/512
    float w = 0.5f - 0.5f * cosf((float)j * 0.13089969389957472f);
    v = pl == 0 ? w * cosf(ang) : w * sinf(ang);
  }
  unsigned short h = f2bf(v);
  TWH[idx] = h;
  TWL[idx] = f2bf(v - bf2f(h));
}

// ---------------- MFMA STFT: mags summed per (k, sample-tile) ----------------
__global__ __launch_bounds__(256, 3) void k_stftmm(
    const unsigned short* __restrict__ XWH,
    const unsigned short* __restrict__ TWH, const unsigned short* __restrict__ TWL,
    float* __restrict__ fpart) {
  const int bn = blockIdx.x * 128;     // k-tile base (0,128,256)
  const int mtile = blockIdx.y;
  const int bm = mtile * 128;

  __shared__ __align__(16) unsigned short AHS[4096], RHS[4096], RLS[4096],
                                          IHS[4096], ILS[4096];
  __shared__ float colpart[2][128];

  const int tid = threadIdx.x;
  const int wave = tid >> 6, lane = tid & 63;
  const int wr = wave >> 1, wc = wave & 1;
  const int fr = lane & 15, fs = lane >> 4;

  const int row0 = tid >> 2;
  const int s0 = (tid & 3) ^ ((row0 >> 1) & 3);
  const unsigned short* gAH0 = XWH + (size_t)(bm + row0) * 64 + s0 * 8;
  const unsigned short* gAH1 = gAH0 + (size_t)64 * 64;
  const unsigned short* gRH0 = TWH + (size_t)(bn + row0) * 64 + s0 * 8;
  const unsigned short* gRH1 = gRH0 + (size_t)64 * 64;
  const unsigned short* gRL0 = TWL + (size_t)(bn + row0) * 64 + s0 * 8;
  const unsigned short* gRL1 = gRL0 + (size_t)64 * 64;
  const unsigned short* gIH0 = gRH0 + (size_t)384 * 64;
  const unsigned short* gIH1 = gRH1 + (size_t)384 * 64;
  const unsigned short* gIL0 = gRL0 + (size_t)384 * 64;
  const unsigned short* gIL1 = gRL1 + (size_t)384 * 64;
  const int lb0 = wave * 512, lb1 = 2048 + wave * 512;

  int aoff[4], boff[4];
#pragma unroll
  for (int m = 0; m < 4; ++m) {
    int ra = wr * 64 + m * 16 + fr;
    aoff[m] = ra * 32 + 8 * (fs ^ ((ra >> 1) & 3));
    int rb = wc * 64 + m * 16 + fr;
    boff[m] = rb * 32 + 8 * (fs ^ ((rb >> 1) & 3));
  }

  f32x4 are[4][4], aim[4][4];
#pragma unroll
  for (int m = 0; m < 4; ++m)
#pragma unroll
    for (int n = 0; n < 4; ++n) {
      are[m][n] = (f32x4){0.f, 0.f, 0.f, 0.f};
      aim[m][n] = (f32x4){0.f, 0.f, 0.f, 0.f};
    }

  for (int k0 = 0; k0 < 64; k0 += 32) {
    __syncthreads();
    gll16(gAH0 + k0, &AHS[lb0]); gll16(gAH1 + k0, &AHS[lb1]);
    gll16(gRH0 + k0, &RHS[lb0]); gll16(gRH1 + k0, &RHS[lb1]);
    gll16(gRL0 + k0, &RLS[lb0]); gll16(gRL1 + k0, &RLS[lb1]);
    gll16(gIH0 + k0, &IHS[lb0]); gll16(gIH1 + k0, &IHS[lb1]);
    gll16(gIL0 + k0, &ILS[lb0]); gll16(gIL1 + k0, &ILS[lb1]);
    __syncthreads();
    bf8 ah[4], rh[4], rl[4], ih[4], il[4];
#pragma unroll
    for (int m = 0; m < 4; ++m) ah[m] = *(const bf8*)&AHS[aoff[m]];
#pragma unroll
    for (int n = 0; n < 4; ++n) {
      rh[n] = *(const bf8*)&RHS[boff[n]];
      rl[n] = *(const bf8*)&RLS[boff[n]];
      ih[n] = *(const bf8*)&IHS[boff[n]];
      il[n] = *(const bf8*)&ILS[boff[n]];
    }
#pragma unroll
    for (int m = 0; m < 4; ++m)
#pragma unroll
      for (int n = 0; n < 4; ++n) {
        are[m][n] = __builtin_amdgcn_mfma_f32_16x16x32_bf16(ah[m], rh[n], are[m][n], 0, 0, 0);
        are[m][n] = __builtin_amdgcn_mfma_f32_16x16x32_bf16(ah[m], rl[n], are[m][n], 0, 0, 0);
        aim[m][n] = __builtin_amdgcn_mfma_f32_16x16x32_bf16(ah[m], ih[n], aim[m][n], 0, 0, 0);
        aim[m][n] = __builtin_amdgcn_mfma_f32_16x16x32_bf16(ah[m], il[n], aim[m][n], 0, 0, 0);
      }
  }

  float s[4];
#pragma unroll
  for (int n = 0; n < 4; ++n) {
    float acc = 0.f;
#pragma unroll
    for (int m = 0; m < 4; ++m)
#pragma unroll
      for (int r = 0; r < 4; ++r) {
        float re = are[m][n][r], im = aim[m][n][r];
        acc += __builtin_amdgcn_sqrtf(re * re + im * im);
      }
    acc += __shfl_xor(acc, 16);
    acc += __shfl_xor(acc, 32);
    s[n] = acc;
  }
  if (fs == 0) {
#pragma unroll
    for (int n = 0; n < 4; ++n) colpart[wr][wc * 64 + n * 16 + fr] = s[n];
  }
  __syncthreads();
  if (tid < 128) {
    int k = bn + tid;
    if (k < NBIN_) fpart[(size_t)k * NMT_ + mtile] = colpart[0][tid] + colpart[1][tid];
  }
}

// ---------------- reduce -> freq (all-b) and fsumb (per-b) ----------------
__global__ __launch_bounds__(256) void k_fred(const float* __restrict__ fpart,
                                              float* __restrict__ freq,
                                              float* __restrict__ fsumb) {
  int k = blockIdx.x;
  int tid = threadIdx.x;
  int b = tid >> 3, j = tid & 7;   // 8 lanes per batch, 44 values each batch
  float s = 0.f;
  for (int i = j; i < 44; i += 8) s += fpart[(size_t)k * NMT_ + b * 44 + i];
  for (int off = 4; off > 0; off >>= 1) s += __shfl_xor(s, off);
  __shared__ float bs[32];
  if (j == 0) bs[b] = s;
  __syncthreads();
  if (tid < 32) {
    float v = bs[tid];
    fsumb[k * 32 + tid] = v;
    for (int off = 16; off > 0; off >>= 1) v += __shfl_xor(v, off);
    if (tid == 0) freq[k] = v;
  }
}

// ---------------- top-k + meta + sw softmax (fused) ----------------
__global__ void k_topk(const float* __restrict__ freq, const float* __restrict__ fsumb,
                       int* __restrict__ meta, float* __restrict__ swb) {
  __shared__ int stop[3];
  int tid = threadIdx.x;
  if (tid == 0) {
    float bv[3] = {-1e30f, -1e30f, -1e30f};
    int bi[3] = {1, 1, 1};
    for (int k = 1; k < NBIN_; ++k) {
      float v = freq[k];
      if (v > bv[0]) { bv[2]=bv[1]; bi[2]=bi[1]; bv[1]=bv[0]; bi[1]=bi[0]; bv[0]=v; bi[0]=k; }
      else if (v > bv[1]) { bv[2]=bv[1]; bi[2]=bi[1]; bv[1]=v; bi[1]=k; }
      else if (v > bv[2]) { bv[2]=v; bi[2]=k; }
    }
    for (int i = 0; i < 3; ++i) {
      int top = bi[i];
      int p = T_ / top;
      int L = ((T_ + p - 1) / p) * p;
      meta[i] = top;
      meta[3 + i] = p;
      meta[6 + i] = L;
      meta[9 + i] = L / p;
      meta[15 + i] = B_ * L;   // tokens
      stop[i] = top;
    }
  }
  __syncthreads();
  int b = tid;
  if (b < B_) {
    float inv = 1.0f / (float)(NFR_ * N_);
    float m0 = fsumb[stop[0] * 32 + b] * inv;
    float m1 = fsumb[stop[1] * 32 + b] * inv;
    float m2 = fsumb[stop[2] * 32 + b] * inv;
    float mx = fmaxf(m0, fmaxf(m1, m2));
    float e0 = __expf(m0 - mx), e1 = __expf(m1 - mx), e2 = __expf(m2 - mx);
    float s = e0 + e1 + e2;
    swb[b * 4 + 0] = e0 / s; swb[b * 4 + 1] = e1 / s; swb[b * 4 + 2] = e2 / s;
  }
}

// ---------------- fused adjacency + GCN operator prep ----------------
__global__ __launch_bounds__(1024) void k_adjprep(const float* __restrict__ nv1,
                                                  const float* __restrict__ nv2,
                                                  const float* __restrict__ mw,
                                                  const float* __restrict__ mb,
                                                  const float* __restrict__ sb,
                                                  float* __restrict__ P12,
                                                  float* __restrict__ beff) {
  __shared__ float A32s[32][32];
  __shared__ float Ms[32][32], P1s[32][32], P2s[32][32], S1[32], S2[32], sbl[32];
  int tid = threadIdx.x;
  if (tid < 32) {
    int v = tid;
    float row[32];
    for (int w = 0; w < 32; ++w) {
      float s = 0.f;
      for (int d = 0; d < 10; ++d) s += nv1[v * 10 + d] * nv2[d * 32 + w];
      row[w] = fmaxf(s, 0.f);
    }
    float mx = -1e30f;
    for (int w = 0; w < 32; ++w) mx = fmaxf(mx, row[w]);
    float sm = 0.f;
    for (int w = 0; w < 32; ++w) { row[w] = expf(row[w] - mx); sm += row[w]; }
    for (int w = 0; w < 32; ++w) row[w] /= sm;
    row[v] += 1.0f;
    float rs = 0.f;
    for (int w = 0; w < 32; ++w) rs += row[w];
    for (int w = 0; w < 32; ++w) A32s[v][w] = row[w] / rs;
    sbl[tid] = sb[tid];
  }
  __syncthreads();
  int w = tid >> 5, v = tid & 31;
  Ms[w][v] = A32s[v][w];
  __syncthreads();
  float p1 = 0.95f * Ms[w][v] + (w == v ? 0.05f : 0.f);
  P1s[w][v] = p1;
  __syncthreads();
  float p2 = 0.f;
  for (int u = 0; u < 32; ++u) p2 += P1s[w][u] * Ms[u][v];
  p2 = 0.95f * p2 + (w == v ? 0.05f : 0.f);
  P2s[w][v] = p2;
  P12[tid] = p1;
  P12[1024 + tid] = p2;
  __syncthreads();
  if (tid < 32) {
    float s1 = 0.f, s2 = 0.f;
    for (int u = 0; u < 32; ++u) { s1 += P1s[u][tid]; s2 += P2s[u][tid]; }
    S1[tid] = s1; S2[tid] = s2;
  }
  __syncthreads();
  int o = w;
  float be = mb[o];
  for (int c = 0; c < 32; ++c) {
    float sc = sbl[c];
    be += mw[o * 96 + c] * sc;
    be += mw[o * 96 + 32 + c] * sc * S1[v];
    be += mw[o * 96 + 64 + c] * sc * S2[v];
  }
  beff[tid] = be;
}

// ---------------- build T [1024][1024]: T[(o,v)][(c,w)] ----------------
__global__ __launch_bounds__(256) void k_T(const float* __restrict__ P12,
                                           const float* __restrict__ mw,
                                           float* __restrict__ Tm) {
  int idx = blockIdx.x * 256 + threadIdx.x;
  int r = idx >> 10, k2 = idx & 1023;
  int o = r >> 5, v = r & 31;
  int c = k2 >> 5, w = k2 & 31;
  float t = mw[o * 96 + 32 + c] * P12[w * 32 + v]
          + mw[o * 96 + 64 + c] * P12[1024 + w * 32 + v];
  if (w == v) t += mw[o * 96 + c];
  Tm[idx] = t;
}

// ---------------- build WdT hi: WdT[j][(c,w)] = sw[c][j-w] ----------------
__global__ void k_wdh(const float* __restrict__ swi, unsigned short* __restrict__ WH) {
  int idx = blockIdx.x * 256 + threadIdx.x;   // 512*1024
  int j = idx >> 10, k2 = idx & 1023;
  int c = k2 >> 5, w = k2 & 31;
  int kk = j - w;
  float vv = (kk >= 0 && kk < KH_) ? swi[c * KH_ + kk] : 0.f;
  WH[idx] = f2bf(vv);
}

// ---------------- weight hi split ----------------
__global__ void k_splith(const float* __restrict__ src, unsigned short* __restrict__ Hi,
                         int n) {
  int i = blockIdx.x * 256 + threadIdx.x;
  if (i * 4 >= n) return;
  float4 v = *(const float4*)&src[i * 4];
  ushort4 h;
  h.x = f2bf(v.x); h.y = f2bf(v.y); h.z = f2bf(v.z); h.w = f2bf(v.w);
  *(ushort4*)&Hi[i * 4] = h;
}

// ---------------- 2-MFMA GEMM (fp32 A hi/lo; bf16 weight hi; fold GEMM only) ----------------
__global__ __launch_bounds__(256, 2) void k_mm2(
    const float* __restrict__ A, const unsigned short* __restrict__ Bh,
    const float* __restrict__ bias,
    float* __restrict__ C, float* __restrict__ Cpart,
    int M, int N, int K, int lda, int dogelu) {
  const int bm = blockIdx.y * 128;
  if (bm >= M) return;
  const int bn = blockIdx.x * 128;
  const int nz = gridDim.z, z = blockIdx.z;
  const int kpb = K / nz;
  const int kbeg = z * kpb, kend = kbeg + kpb;

  __shared__ __align__(16) unsigned short AhS[4096], AlS[4096], BhS[4096];

  const int tid = threadIdx.x;
  const int wave = tid >> 6, lane = tid & 63;
  const int wr = wave >> 1, wc = wave & 1;
  const int fr = lane & 15, fs = lane >> 4;

  const int sr = tid >> 1, ss = (tid & 1) * 2;
  const int sx = (sr >> 1) & 3;
  const int so0 = sr * 32 + 8 * (ss ^ sx);
  const int so1 = sr * 32 + 8 * ((ss + 1) ^ sx);

  const int row0 = tid >> 2;
  const int s0 = (tid & 3) ^ ((row0 >> 1) & 3);
  const unsigned short* gBh0 = Bh + (size_t)(bn + row0) * K + s0 * 8;
  const unsigned short* gBh1 = gBh0 + (size_t)64 * K;
  unsigned short* lB0 = &BhS[wave * 512];
  unsigned short* lB1 = &BhS[2048 + wave * 512];

  int aoff[4], boff[4];
#pragma unroll
  for (int m = 0; m < 4; ++m) {
    int ra = wr * 64 + m * 16 + fr;
    aoff[m] = ra * 32 + 8 * (fs ^ ((ra >> 1) & 3));
    int rb = wc * 64 + m * 16 + fr;
    boff[m] = rb * 32 + 8 * (fs ^ ((rb >> 1) & 3));
  }

  const bool aok = (bm + sr) < M;
  const float* Arow = A + (size_t)(bm + sr) * lda + ss * 8;

  f32x4 acc[4][4];
#pragma unroll
  for (int m = 0; m < 4; ++m)
#pragma unroll
    for (int n = 0; n < 4; ++n) acc[m][n] = (f32x4){0.f, 0.f, 0.f, 0.f};

  for (int k0 = kbeg; k0 < kend; k0 += 32) {
    float4 a0, a1, a2, a3;
    if (aok) {
      const float4* p = (const float4*)(Arow + k0);
      a0 = p[0]; a1 = p[1]; a2 = p[2]; a3 = p[3];
    } else {
      a0 = a1 = a2 = a3 = make_float4(0.f, 0.f, 0.f, 0.f);
    }
    float av[16];
    av[0]=a0.x; av[1]=a0.y; av[2]=a0.z; av[3]=a0.w;
    av[4]=a1.x; av[5]=a1.y; av[6]=a1.z; av[7]=a1.w;
    av[8]=a2.x; av[9]=a2.y; av[10]=a2.z; av[11]=a2.w;
    av[12]=a3.x; av[13]=a3.y; av[14]=a3.z; av[15]=a3.w;
    u16x8 h0, h1, l0, l1;
#pragma unroll
    for (int j = 0; j < 8; ++j) {
      unsigned u = __float_as_uint(av[j]);
      h0[j] = (unsigned short)(u >> 16);
      float r2 = av[j] - __uint_as_float(u & 0xffff0000u);
      l0[j] = (unsigned short)(__float_as_uint(r2) >> 16);
      unsigned u2 = __float_as_uint(av[j + 8]);
      h1[j] = (unsigned short)(u2 >> 16);
      float r3 = av[j + 8] - __uint_as_float(u2 & 0xffff0000u);
      l1[j] = (unsigned short)(__float_as_uint(r3) >> 16);
    }
    __syncthreads();   // prior frag reads done
    gll16(gBh0 + k0, lB0); gll16(gBh1 + k0, lB1);
    *(u16x8*)&AhS[so0] = h0; *(u16x8*)&AhS[so1] = h1;
    *(u16x8*)&AlS[so0] = l0; *(u16x8*)&AlS[so1] = l1;
    __syncthreads();   // drains vmcnt + lgkm
    bf8 ah[4], al4[4], bh4[4];
#pragma unroll
    for (int m = 0; m < 4; ++m) {
      ah[m]  = *(const bf8*)&AhS[aoff[m]];
      al4[m] = *(const bf8*)&AlS[aoff[m]];
    }
#pragma unroll
    for (int n = 0; n < 4; ++n) bh4[n] = *(const bf8*)&BhS[boff[n]];
#pragma unroll
    for (int m = 0; m < 4; ++m)
#pragma unroll
      for (int n = 0; n < 4; ++n) {
        acc[m][n] = __builtin_amdgcn_mfma_f32_16x16x32_bf16(ah[m],  bh4[n], acc[m][n], 0, 0, 0);
        acc[m][n] = __builtin_amdgcn_mfma_f32_16x16x32_bf16(al4[m], bh4[n], acc[m][n], 0, 0, 0);
      }
  }

  if (nz > 1) {
    float* P = Cpart + (size_t)z * M * N;
#pragma unroll
    for (int m = 0; m < 4; ++m)
#pragma unroll
      for (int r = 0; r < 4; ++r) {
        int row = bm + wr * 64 + m * 16 + fs * 4 + r;
        if (row < M) {
#pragma unroll
          for (int n = 0; n < 4; ++n) {
            int col = bn + wc * 64 + n * 16 + fr;
            P[(size_t)row * N + col] = acc[m][n][r];
          }
        }
      }
  } else {
    float bcol[4];
#pragma unroll
    for (int n = 0; n < 4; ++n) bcol[n] = bias ? bias[bn + wc * 64 + n * 16 + fr] : 0.f;
#pragma unroll
    for (int m = 0; m < 4; ++m)
#pragma unroll
      for (int r = 0; r < 4; ++r) {
        int row = bm + wr * 64 + m * 16 + fs * 4 + r;
        if (row < M) {
#pragma unroll
          for (int n = 0; n < 4; ++n) {
            int col = bn + wc * 64 + n * 16 + fr;
            float v = acc[m][n][r] + bcol[n];
            if (dogelu) v = gelu_exact(v);
            C[(size_t)row * N + col] = v;
          }
        }
      }
  }
}

// ---------------- conv GEMM: fp32 A hi-only, 1 MFMA, bf16 output + gelu ----------------
// XCD-grouped 1D launch: all 8 n-tiles of an m-panel land on one XCD back-to-back
// (bid%8 == m%8 under round-robin dispatch) -> A panel fetched from HBM once.
__global__ __launch_bounds__(256, 4) void k_mmcv(
    const float* __restrict__ A, const unsigned short* __restrict__ Bh,
    const float* __restrict__ bias,
    unsigned short* __restrict__ C,
    int M, int N, int K, int lda) {
  const int bid = blockIdx.x;          // 1024 = 8 xcd * 8 n * 16 mhi
  const int xcd = bid & 7, rest = bid >> 3;
  const int nt = rest & 7, mhi = rest >> 3;
  const int bm = (mhi * 8 + xcd) * 128;
  const int bn = nt * 128;

  __shared__ __align__(16) unsigned short AhS[4096], BhS[4096];

  const int tid = threadIdx.x;
  const int wave = tid >> 6, lane = tid & 63;
  const int wr = wave >> 1, wc = wave & 1;
  const int fr = lane & 15, fs = lane >> 4;

  const int sr = tid >> 1, ss = (tid & 1) * 2;
  const int sx = (sr >> 1) & 3;
  const int so0 = sr * 32 + 8 * (ss ^ sx);
  const int so1 = sr * 32 + 8 * ((ss + 1) ^ sx);

  const int row0 = tid >> 2;
  const int s0 = (tid & 3) ^ ((row0 >> 1) & 3);
  const unsigned short* gBh0 = Bh + (size_t)(bn + row0) * K + s0 * 8;
  const unsigned short* gBh1 = gBh0 + (size_t)64 * K;
  unsigned short* lB0 = &BhS[wave * 512];
  unsigned short* lB1 = &BhS[2048 + wave * 512];

  int aoff[4], boff[4];
#pragma unroll
  for (int m = 0; m < 4; ++m) {
    int ra = wr * 64 + m * 16 + fr;
    aoff[m] = ra * 32 + 8 * (fs ^ ((ra >> 1) & 3));
    int rb = wc * 64 + m * 16 + fr;
    boff[m] = rb * 32 + 8 * (fs ^ ((rb >> 1) & 3));
  }

  const float* Arow = A + (size_t)(bm + sr) * lda + ss * 8;

  f32x4 acc[4][4];
#pragma unroll
  for (int m = 0; m < 4; ++m)
#pragma unroll
    for (int n = 0; n < 4; ++n) acc[m][n] = (f32x4){0.f, 0.f, 0.f, 0.f};

  for (int k0 = 0; k0 < K; k0 += 32) {
    const float4* p = (const float4*)(Arow + k0);
    float4 a0 = p[0], a1 = p[1], a2 = p[2], a3 = p[3];
    u16x8 h0, h1;
    h0[0]=f2bf(a0.x); h0[1]=f2bf(a0.y); h0[2]=f2bf(a0.z); h0[3]=f2bf(a0.w);
    h0[4]=f2bf(a1.x); h0[5]=f2bf(a1.y); h0[6]=f2bf(a1.z); h0[7]=f2bf(a1.w);
    h1[0]=f2bf(a2.x); h1[1]=f2bf(a2.y); h1[2]=f2bf(a2.z); h1[3]=f2bf(a2.w);
    h1[4]=f2bf(a3.x); h1[5]=f2bf(a3.y); h1[6]=f2bf(a3.z); h1[7]=f2bf(a3.w);
    __syncthreads();   // prior frag reads done
    gll16(gBh0 + k0, lB0); gll16(gBh1 + k0, lB1);
    *(u16x8*)&AhS[so0] = h0; *(u16x8*)&AhS[so1] = h1;
    __syncthreads();   // drains vmcnt + lgkm
    bf8 ah[4], bh4[4];
#pragma unroll
    for (int m = 0; m < 4; ++m) ah[m] = *(const bf8*)&AhS[aoff[m]];
#pragma unroll
    for (int n = 0; n < 4; ++n) bh4[n] = *(const bf8*)&BhS[boff[n]];
#pragma unroll
    for (int m = 0; m < 4; ++m)
#pragma unroll
      for (int n = 0; n < 4; ++n)
        acc[m][n] = __builtin_amdgcn_mfma_f32_16x16x32_bf16(ah[m], bh4[n], acc[m][n], 0, 0, 0);
  }

  float bcol[4];
#pragma unroll
  for (int n = 0; n < 4; ++n) bcol[n] = bias[bn + wc * 64 + n * 16 + fr];
#pragma unroll
  for (int m = 0; m < 4; ++m)
#pragma unroll
    for (int r = 0; r < 4; ++r) {
      int row = bm + wr * 64 + m * 16 + fs * 4 + r;
#pragma unroll
      for (int n = 0; n < 4; ++n) {
        int col = bn + wc * 64 + n * 16 + fr;
        C[(size_t)row * N + col] = f2bf(gelu_exact(acc[m][n][r] + bcol[n]));
      }
    }
}

// ---------------- end GEMM: bf16 A, bf16 B, 1 MFMA, split-K partials ----------------
__global__ __launch_bounds__(256, 4) void k_mmend(
    const unsigned short* __restrict__ Ah, const unsigned short* __restrict__ Bh,
    float* __restrict__ Cpart, int M, int N, int K) {
  const int bm = blockIdx.y * 128;
  const int bn = blockIdx.x * 128;
  const int nz = gridDim.z, z = blockIdx.z;
  const int kpb = K / nz;
  const int kbeg = z * kpb, kend = kbeg + kpb;

  __shared__ __align__(16) unsigned short AhS[4096], BhS[4096];

  const int tid = threadIdx.x;
  const int wave = tid >> 6, lane = tid & 63;
  const int wr = wave >> 1, wc = wave & 1;
  const int fr = lane & 15, fs = lane >> 4;

  const int row0 = tid >> 2;
  const int s0 = (tid & 3) ^ ((row0 >> 1) & 3);
  const unsigned short* gAh0 = Ah + (size_t)(bm + row0) * K + s0 * 8;
  const unsigned short* gAh1 = gAh0 + (size_t)64 * K;
  const unsigned short* gBh0 = Bh + (size_t)(bn + row0) * K + s0 * 8;
  const unsigned short* gBh1 = gBh0 + (size_t)64 * K;
  const int lb0 = wave * 512, lb1 = 2048 + wave * 512;

  int aoff[4], boff[4];
#pragma unroll
  for (int m = 0; m < 4; ++m) {
    int ra = wr * 64 + m * 16 + fr;
    aoff[m] = ra * 32 + 8 * (fs ^ ((ra >> 1) & 3));
    int rb = wc * 64 + m * 16 + fr;
    boff[m] = rb * 32 + 8 * (fs ^ ((rb >> 1) & 3));
  }

  f32x4 acc[4][4];
#pragma unroll
  for (int m = 0; m < 4; ++m)
#pragma unroll
    for (int n = 0; n < 4; ++n) acc[m][n] = (f32x4){0.f, 0.f, 0.f, 0.f};

  for (int k0 = kbeg; k0 < kend; k0 += 32) {
    __syncthreads();
    gll16(gAh0 + k0, &AhS[lb0]); gll16(gAh1 + k0, &AhS[lb1]);
    gll16(gBh0 + k0, &BhS[lb0]); gll16(gBh1 + k0, &BhS[lb1]);
    __syncthreads();
    bf8 ah[4], bh4[4];
#pragma unroll
    for (int m = 0; m < 4; ++m) ah[m] = *(const bf8*)&AhS[aoff[m]];
#pragma unroll
    for (int n = 0; n < 4; ++n) bh4[n] = *(const bf8*)&BhS[boff[n]];
#pragma unroll
    for (int m = 0; m < 4; ++m)
#pragma unroll
      for (int n = 0; n < 4; ++n)
        acc[m][n] = __builtin_amdgcn_mfma_f32_16x16x32_bf16(ah[m], bh4[n], acc[m][n], 0, 0, 0);
  }

  float* P = Cpart + (size_t)z * M * N;
#pragma unroll
  for (int m = 0; m < 4; ++m)
#pragma unroll
    for (int r = 0; r < 4; ++r) {
      int row = bm + wr * 64 + m * 16 + fs * 4 + r;
#pragma unroll
      for (int n = 0; n < 4; ++n) {
        int col = bn + wc * 64 + n * 16 + fr;
        P[(size_t)row * N + col] = acc[m][n][r];
      }
    }
}

// ---------------- 1-MFMA plane GEMM (attention pipeline; XCD-grouped 1D launch) ----------------
// grid = 8 * NT4 * 22 = 704; decode keeps all 4 n-tiles of an m-panel on one XCD.
__global__ __launch_bounds__(256, 4) void k_mmb1(
    const unsigned short* __restrict__ Ah,
    const unsigned short* __restrict__ Bh,
    const float* __restrict__ bias,
    unsigned short* __restrict__ Ch, unsigned short* __restrict__ Cl,
    int M, int N, int K, const int* __restrict__ Mdyn, int dogelu) {
  if (Mdyn) M = *Mdyn;
  const int bid = blockIdx.x;
  const int xcd = bid & 7, rest = bid >> 3;
  const int nt = rest & 3, mhi = rest >> 2;
  const int mt = mhi * 8 + xcd;
  if (mt >= TOKMAX / 128) return;
  const int bm = mt * 128;
  if (bm >= M) return;
  const int bn = nt * 128;

  __shared__ __align__(16) unsigned short AhS[4096], BhS[4096];

  const int tid = threadIdx.x;
  const int wave = tid >> 6, lane = tid & 63;
  const int wr = wave >> 1, wc = wave & 1;
  const int fr = lane & 15, fs = lane >> 4;

  const int row0 = tid >> 2;
  const int s0 = (tid & 3) ^ ((row0 >> 1) & 3);
  const unsigned short* gAh0 = Ah + (size_t)(bm + row0) * K + s0 * 8;
  const unsigned short* gAh1 = gAh0 + (size_t)64 * K;
  const unsigned short* gBh0 = Bh + (size_t)(bn + row0) * K + s0 * 8;
  const unsigned short* gBh1 = gBh0 + (size_t)64 * K;
  const int lb0 = wave * 512, lb1 = 2048 + wave * 512;

  int aoff[4], boff[4];
#pragma unroll
  for (int m = 0; m < 4; ++m) {
    int ra = wr * 64 + m * 16 + fr;
    aoff[m] = ra * 32 + 8 * (fs ^ ((ra >> 1) & 3));
    int rb = wc * 64 + m * 16 + fr;
    boff[m] = rb * 32 + 8 * (fs ^ ((rb >> 1) & 3));
  }

  f32x4 acc[4][4];
#pragma unroll
  for (int m = 0; m < 4; ++m)
#pragma unroll
    for (int n = 0; n < 4; ++n) acc[m][n] = (f32x4){0.f, 0.f, 0.f, 0.f};

  for (int k0 = 0; k0 < K; k0 += 32) {
    __syncthreads();
    gll16(gAh0 + k0, &AhS[lb0]); gll16(gAh1 + k0, &AhS[lb1]);
    gll16(gBh0 + k0, &BhS[lb0]); gll16(gBh1 + k0, &BhS[lb1]);
    __syncthreads();
    bf8 ah[4], bh4[4];
#pragma unroll
    for (int m = 0; m < 4; ++m) ah[m] = *(const bf8*)&AhS[aoff[m]];
#pragma unroll
    for (int n = 0; n < 4; ++n) bh4[n] = *(const bf8*)&BhS[boff[n]];
#pragma unroll
    for (int m = 0; m < 4; ++m)
#pragma unroll
      for (int n = 0; n < 4; ++n)
        acc[m][n] = __builtin_amdgcn_mfma_f32_16x16x32_bf16(ah[m], bh4[n], acc[m][n], 0, 0, 0);
  }

  float bcol[4];
#pragma unroll
  for (int n = 0; n < 4; ++n) bcol[n] = bias[bn + wc * 64 + n * 16 + fr];
#pragma unroll
  for (int m = 0; m < 4; ++m)
#pragma unroll
    for (int r = 0; r < 4; ++r) {
      int row = bm + wr * 64 + m * 16 + fs * 4 + r;
      if (row < M) {
#pragma unroll
        for (int n = 0; n < 4; ++n) {
          int col = bn + wc * 64 + n * 16 + fr;
          float v = acc[m][n][r] + bcol[n];
          if (dogelu) v = gelu_exact(v);
          size_t o = (size_t)row * N + col;
          unsigned short h = f2bf(v);
          Ch[o] = h;
          if (Cl) Cl[o] = f2bf(v - bf2f(h));
        }
      }
    }
}

// ---------------- fused QKV GEMM: XCD-grouped 1D launch (NT=12) ----------------
__global__ __launch_bounds__(256, 4) void k_mmqkv(
    const unsigned short* __restrict__ Ah,
    const unsigned short* __restrict__ Bh,
    const float* __restrict__ bq, const float* __restrict__ bk,
    const float* __restrict__ bv,
    unsigned short* __restrict__ Qh, unsigned short* __restrict__ Kh,
    unsigned short* __restrict__ Vh,
    int M, int K, const int* __restrict__ Mdyn) {
  if (Mdyn) M = *Mdyn;
  const int bid = blockIdx.x;           // 8 * 12 * 22 = 2112
  const int xcd = bid & 7, rest = bid >> 3;
  const int nt = rest % 12, mhi = rest / 12;
  const int mt = mhi * 8 + xcd;
  if (mt >= TOKMAX / 128) return;
  const int bm = mt * 128;
  if (bm >= M) return;
  const int bn = nt * 128;   // in [0,1536)
  const int sel = bn >> 9;
  unsigned short* Ch = sel == 0 ? Qh : (sel == 1 ? Kh : Vh);
  const float* bias = sel == 0 ? bq : (sel == 1 ? bk : bv);
  const int cb = bn & 511;

  __shared__ __align__(16) unsigned short AhS[4096], BhS[4096];

  const int tid = threadIdx.x;
  const int wave = tid >> 6, lane = tid & 63;
  const int wr = wave >> 1, wc = wave & 1;
  const int fr = lane & 15, fs = lane >> 4;

  const int row0 = tid >> 2;
  const int s0 = (tid & 3) ^ ((row0 >> 1) & 3);
  const unsigned short* gAh0 = Ah + (size_t)(bm + row0) * K + s0 * 8;
  const unsigned short* gAh1 = gAh0 + (size_t)64 * K;
  const unsigned short* gBh0 = Bh + (size_t)(bn + row0) * K + s0 * 8;
  const unsigned short* gBh1 = gBh0 + (size_t)64 * K;
  const int lb0 = wave * 512, lb1 = 2048 + wave * 512;

  int aoff[4], boff[4];
#pragma unroll
  for (int m = 0; m < 4; ++m) {
    int ra = wr * 64 + m * 16 + fr;
    aoff[m] = ra * 32 + 8 * (fs ^ ((ra >> 1) & 3));
    int rb = wc * 64 + m * 16 + fr;
    boff[m] = rb * 32 + 8 * (fs ^ ((rb >> 1) & 3));
  }

  f32x4 acc[4][4];
#pragma unroll
  for (int m = 0; m < 4; ++m)
#pragma unroll
    for (int n = 0; n < 4; ++n) acc[m][n] = (f32x4){0.f, 0.f, 0.f, 0.f};

  for (int k0 = 0; k0 < K; k0 += 32) {
    __syncthreads();
    gll16(gAh0 + k0, &AhS[lb0]); gll16(gAh1 + k0, &AhS[lb1]);
    gll16(gBh0 + k0, &BhS[lb0]); gll16(gBh1 + k0, &BhS[lb1]);
    __syncthreads();
    bf8 ah[4], bh4[4];
#pragma unroll
    for (int m = 0; m < 4; ++m) ah[m] = *(const bf8*)&AhS[aoff[m]];
#pragma unroll
    for (int n = 0; n < 4; ++n) bh4[n] = *(const bf8*)&BhS[boff[n]];
#pragma unroll
    for (int m = 0; m < 4; ++m)
#pragma unroll
      for (int n = 0; n < 4; ++n)
        acc[m][n] = __builtin_amdgcn_mfma_f32_16x16x32_bf16(ah[m], bh4[n], acc[m][n], 0, 0, 0);
  }

  float bcol[4];
#pragma unroll
  for (int n = 0; n < 4; ++n) bcol[n] = bias[cb + wc * 64 + n * 16 + fr];
#pragma unroll
  for (int m = 0; m < 4; ++m)
#pragma unroll
    for (int r = 0; r < 4; ++r) {
      int row = bm + wr * 64 + m * 16 + fs * 4 + r;
      if (row < M) {
#pragma unroll
        for (int n = 0; n < 4; ++n) {
          int col = cb + wc * 64 + n * 16 + fr;
          Ch[(size_t)row * 512 + col] = f2bf(acc[m][n][r] + bcol[n]);
        }
      }
    }
}

// ---------------- split-K reduce 16 (+bias) ----------------
__global__ void k_red16(const float* __restrict__ part, const float* __restrict__ eb,
                        float* __restrict__ dst) {
  int idx = blockIdx.x * 256 + threadIdx.x;   // 1024*512
  float s = eb ? eb[idx & 511] : 0.f;
#pragma unroll
  for (int zz = 0; zz < 16; ++zz) s += part[(size_t)zz * 524288 + idx];
  dst[idx] = s;
}

// ---------------- split-K reduce 8 -> bf16 hi (W' fold) ----------------
__global__ void k_redsplit(const float* __restrict__ part, unsigned short* __restrict__ WH) {
  int idx = blockIdx.x * 256 + threadIdx.x;   // 1024*512
  float s = 0.f;
#pragma unroll
  for (int zz = 0; zz < 8; ++zz) s += part[(size_t)zz * 524288 + idx];
  WH[idx] = f2bf(s);
}

// ---------------- bf16 repack G[(b,s),(c,n)] -> G2[(b,n),(c,s)] ----------------
__global__ __launch_bounds__(256) void k_repackb(const unsigned short* __restrict__ G,
                                                 unsigned short* __restrict__ G2) {
  int bid = blockIdx.x;
  int st = bid & 15, c = (bid >> 4) & 31, b = bid >> 9;
  __shared__ unsigned short tile[32][34];
  int tid = threadIdx.x;
  int n = tid & 31, s = tid >> 5;
  for (int q = 0; q < 4; ++q) {
    int ss = s + q * 8;
    tile[ss][n] = G[((size_t)b * T_ + st * 32 + ss) * 1024 + c * 32 + n];
  }
  __syncthreads();
  int s2 = tid & 31, n2 = tid >> 5;
  for (int q = 0; q < 4; ++q) {
    int nn = n2 + q * 8;
    G2[((size_t)b * 32 + nn) * 16384 + c * 512 + st * 32 + s2] = tile[s2][nn];
  }
}

// ---------------- lw projection + residual + LN -> cur fp32 AND A0 planes ----------------
__global__ __launch_bounds__(256) void k_lwln(const float* __restrict__ osm,
                                              const float* __restrict__ lw,
                                              const float* __restrict__ lb,
                                              const float* __restrict__ curIn,
                                              const float* __restrict__ g,
                                              const float* __restrict__ bt,
                                              float* __restrict__ curOut,
                                              unsigned short* __restrict__ xh,
                                              unsigned short* __restrict__ xl,
                                              const int* __restrict__ meta, int iter) {
  int tok = blockIdx.x;
  int b = tok >> 9, t = tok & 511;
  __shared__ float os[C_];
  __shared__ float red[256];
  int tid = threadIdx.x;
  if (tid < C_) os[tid] = osm[((size_t)b * C_ + tid) * T_ + t];
  __syncthreads();
  float val[2];
#pragma unroll
  for (int q = 0; q < 2; ++q) {
    int m = tid + q * 256;
    float s = lb[m] + curIn[(size_t)tok * N_ + m];
    for (int n2 = 0; n2 < C_; ++n2) s += os[n2] * lw[n2 * N_ + m];
    val[q] = s;
  }
  red[tid] = val[0] + val[1];
  __syncthreads();
  for (int off = 128; off > 0; off >>= 1) { if (tid < off) red[tid] += red[tid + off]; __syncthreads(); }
  float mean = red[0] * (1.0f / N_);
  __syncthreads();
  float d0 = val[0] - mean, d1 = val[1] - mean;
  red[tid] = d0 * d0 + d1 * d1;
  __syncthreads();
  for (int off = 128; off > 0; off >>= 1) { if (tid < off) red[tid] += red[tid + off]; __syncthreads(); }
  float inv = rsqrtf(red[0] * (1.0f / N_) + EPS_);
  float o0 = d0 * inv * g[tid] + bt[tid];
  float o1 = d1 * inv * g[tid + 256] + bt[tid + 256];
  curOut[(size_t)tok * N_ + tid] = o0;
  curOut[(size_t)tok * N_ + tid + 256] = o1;
  int L = meta[6 + iter];
  size_t pi = ((size_t)b * L + t) * N_;
  st2(xh, xl, pi + tid, o0);
  st2(xh, xl, pi + tid + 256, o1);
}

// ---------------- zero pad rows l in [T,L) of A0 planes ----------------
__global__ void k_padtail(unsigned short* __restrict__ xh, unsigned short* __restrict__ xl,
                          const int* __restrict__ meta, int iter) {
  int L = meta[6 + iter];
  int pad = L - T_;
  if (pad <= 0) return;
  size_t total = (size_t)B_ * pad * N_;
  for (size_t idx = (size_t)blockIdx.x * 256 + threadIdx.x; idx < total;
       idx += (size_t)gridDim.x * 256) {
    size_t row = idx >> 9;
    int d = (int)(idx & 511);
    int b = (int)(row / pad), l = T_ + (int)(row % pad);
    size_t o = ((size_t)b * L + l) * N_ + d;
    xh[o] = 0; xl[o] = 0;
  }
}

// ---------------- residual add + LN (planes in, planes out) ----------------
__global__ __launch_bounds__(256) void k_lnadd(const unsigned short* __restrict__ r1h,
                                               const unsigned short* __restrict__ r1l,
                                               const unsigned short* __restrict__ r2h,
                                               const unsigned short* __restrict__ r2l,
                                               const float* __restrict__ g,
                                               const float* __restrict__ bt,
                                               unsigned short* __restrict__ dh,
                                               unsigned short* __restrict__ dl,
                                               const int* __restrict__ meta, int iter) {
  int tokens = meta[15 + iter];
  int tok = blockIdx.x;
  if (tok >= tokens) return;
  __shared__ float red[256];
  int tid = threadIdx.x;
  float val[2];
#pragma unroll
  for (int q = 0; q < 2; ++q) {
    size_t i = (size_t)tok * N_ + tid + q * 256;
    val[q] = ld2(r1h, r1l, i) + ld2(r2h, r2l, i);
  }
  red[tid] = val[0] + val[1];
  __syncthreads();
  for (int off = 128; off > 0; off >>= 1) { if (tid < off) red[tid] += red[tid + off]; __syncthreads(); }
  float mean = red[0] * (1.0f / N_);
  __syncthreads();
  float d0 = val[0] - mean, d1 = val[1] - mean;
  red[tid] = d0 * d0 + d1 * d1;
  __syncthreads();
  for (int off = 128; off > 0; off >>= 1) { if (tid < off) red[tid] += red[tid + off]; __syncthreads(); }
  float inv = rsqrtf(red[0] * (1.0f / N_) + EPS_);
  st2(dh, dl, (size_t)tok * N_ + tid, d0 * inv * g[tid] + bt[tid]);
  st2(dh, dl, (size_t)tok * N_ + tid + 256, d1 * inv * g[tid + 256] + bt[tid + 256]);
}

// ---------------- fused: LN(r1+r2) -> LN -> gelu -> weighted accumulate ----------------
__global__ __launch_bounds__(256) void k_lnfin(const unsigned short* __restrict__ r1h,
                                               const unsigned short* __restrict__ r1l,
                                               const unsigned short* __restrict__ r2h,
                                               const unsigned short* __restrict__ r2l,
                                               const float* __restrict__ g1,
                                               const float* __restrict__ b1,
                                               const float* __restrict__ g2,
                                               const float* __restrict__ b2,
                                               const float* __restrict__ swb,
                                               float* __restrict__ acc,
                                               const int* __restrict__ meta, int iter) {
  int L = meta[6 + iter];
  int tok = blockIdx.x;
  if (tok >= B_ * L) return;
  int b = tok / L, l = tok % L;
  if (l >= T_) return;   // truncated away
  __shared__ float red[256];
  int tid = threadIdx.x;
  float val[2];
#pragma unroll
  for (int q = 0; q < 2; ++q) {
    size_t i = (size_t)tok * N_ + tid + q * 256;
    val[q] = ld2(r1h, r1l, i) + ld2(r2h, r2l, i);
  }
  red[tid] = val[0] + val[1];
  __syncthreads();
  for (int off = 128; off > 0; off >>= 1) { if (tid < off) red[tid] += red[tid + off]; __syncthreads(); }
  float mean = red[0] * (1.0f / N_);
  __syncthreads();
  float d0 = val[0] - mean, d1 = val[1] - mean;
  red[tid] = d0 * d0 + d1 * d1;
  __syncthreads();
  for (int off = 128; off > 0; off >>= 1) { if (tid < off) red[tid] += red[tid + off]; __syncthreads(); }
  float inv = rsqrtf(red[0] * (1.0f / N_) + EPS_);
  float y0 = d0 * inv * g1[tid] + b1[tid];
  float y1 = d1 * inv * g1[tid + 256] + b1[tid + 256];
  // second LN over y
  __syncthreads();
  red[tid] = y0 + y1;
  __syncthreads();
  for (int off = 128; off > 0; off >>= 1) { if (tid < off) red[tid] += red[tid + off]; __syncthreads(); }
  float mean2 = red[0] * (1.0f / N_);
  __syncthreads();
  float e0 = y0 - mean2, e1 = y1 - mean2;
  red[tid] = e0 * e0 + e1 * e1;
  __syncthreads();
  for (int off = 128; off > 0; off >>= 1) { if (tid < off) red[tid] += red[tid + off]; __syncthreads(); }
  float inv2 = rsqrtf(red[0] * (1.0f / N_) + EPS_);
  float s = swb[b * 4 + iter];
  float u0 = gelu_exact(e0 * inv2 * g2[tid] + b2[tid]);
  float u1 = gelu_exact(e1 * inv2 * g2[tid + 256] + b2[tid + 256]);
  size_t o = ((size_t)b * T_ + l) * N_;
  acc[o + tid] += s * u0;
  acc[o + tid + 256] += s * u1;
}

// ---------------- attention S<=32: wave-per-pair, lane=t scores, barrier-free ----------------
__global__ __launch_bounds__(256) void k_attn32(
    const unsigned short* __restrict__ qh,
    const unsigned short* __restrict__ kh,
    const unsigned short* __restrict__ vh,
    unsigned short* __restrict__ oh,
    const int* __restrict__ meta, int iter) {
  int S = meta[3 + iter];
  if (S > 32) return;
  int L = meta[6 + iter], nseq = meta[9 + iter];
  int npair = B_ * nseq * 8;
  __shared__ unsigned short Kts[4][64 * 33];
  __shared__ unsigned short Vsh[4][32 * 66];
  __shared__ float qs[4][64];
  int tid = threadIdx.x;
  int wave = tid >> 6, lane = tid & 63;
  unsigned short* Ktw = Kts[wave];
  unsigned short* Vw = Vsh[wave];
  int gw = (blockIdx.x * 256 + tid) >> 6;
  int nw = (gridDim.x * 256) >> 6;
  const int tt = lane & 31;
  const int hf = lane >> 5;
  for (int pair = gw; pair < npair; pair += nw) {
    int h = pair & 7;
    int m = pair >> 3;
    int b = m / nseq, g2 = m - b * nseq;
    size_t base = ((size_t)b * L + (size_t)g2 * S) * N_ + h * 64;
    for (int i = lane; i < S * 64; i += 64) {
      int t = i >> 6, d = i & 63;
      size_t gi = base + (size_t)t * N_ + d;
      Ktw[d * 33 + t] = kh[gi];
      Vw[t * 66 + d] = vh[gi];
    }
    bool tok = tt < S;
    for (int s = 0; s < S; ++s) {
      qs[wave][lane] = bf2f(qh[base + (size_t)s * N_ + lane]);
      float part = 0.f;
      if (tok) {
        const unsigned short* kp = &Ktw[hf * 32 * 33 + tt];
        const float* qp = &qs[wave][hf * 32];
#pragma unroll 8
        for (int j = 0; j < 32; ++j) part += qp[j] * bf2f(kp[j * 33]);
      }
      part += __shfl_xor(part, 32);
      float sc = tok ? part * 0.125f : -3.0e38f;
      float mx = sc;
      for (int off = 16; off > 0; off >>= 1) mx = fmaxf(mx, __shfl_xor(mx, off));
      float p = tok ? __expf(sc - mx) : 0.f;
      float ssum = p;
      for (int off = 16; off > 0; off >>= 1) ssum += __shfl_xor(ssum, off);
      float ov = 0.f;
      for (int t = 0; t < S; ++t) {
        float pt = __shfl(p, t);
        ov += pt * bf2f(Vw[t * 66 + lane]);
      }
      oh[base + (size_t)s * N_ + lane] = f2bf(ov / ssum);
    }
  }
}

// ---------------- MFMA flash attention, 32<S<=128: one block per (seq,head) ----------------
__global__ __launch_bounds__(256, 3) void k_attn_small(
    const unsigned short* __restrict__ qh,
    const unsigned short* __restrict__ kh,
    const unsigned short* __restrict__ vh,
    unsigned short* __restrict__ oh,
    const int* __restrict__ meta, int iter) {
  int S = meta[3 + iter];
  if (S <= 32 || S > 128) return;
  int L = meta[6 + iter], nseq = meta[9 + iter];
  int M = B_ * nseq;
  int mh = blockIdx.x;
  int m0 = mh >> 3, h = mh & 7;
  if (m0 >= M) return;
  int b = m0 / nseq, g2 = m0 % nseq;
  size_t tok0 = (size_t)b * L + (size_t)g2 * S;

  // U: QK phase = {Q kstep0, Q kstep1, K kstep0, K kstep1}; PV phase = P[4 ksteps]
  __shared__ __align__(16) unsigned short U[16384];
  __shared__ __align__(16) unsigned short VT[8192];   // V^T, 4 k-steps [64][32]
  __shared__ float rb1[2][128], rb2[2][128];

  const int tid = threadIdx.x;
  const int wave = tid >> 6, lane = tid & 63;
  const int wr = wave >> 1, wc = wave & 1;
  const int fr = lane & 15, fs = lane >> 4;

  // ---- stage Q,K via global_load_lds (mmb1 pattern, K=64 -> 2 k-steps) ----
  const int row0 = tid >> 2;
  const int s0 = (tid & 3) ^ ((row0 >> 1) & 3);
  const unsigned short* gQ0 = qh + (tok0 + row0) * N_ + h * 64 + s0 * 8;
  const unsigned short* gQ1 = gQ0 + (size_t)64 * N_;
  const unsigned short* gK0 = kh + (tok0 + row0) * N_ + h * 64 + s0 * 8;
  const unsigned short* gK1 = gK0 + (size_t)64 * N_;
  const int lb0 = wave * 512, lb1 = 2048 + wave * 512;
  gll16(gQ0,      &U[lb0]);         gll16(gQ1,      &U[lb1]);
  gll16(gQ0 + 32, &U[4096 + lb0]);  gll16(gQ1 + 32, &U[4096 + lb1]);
  gll16(gK0,      &U[8192 + lb0]);  gll16(gK1,      &U[8192 + lb1]);
  gll16(gK0 + 32, &U[12288 + lb0]); gll16(gK1 + 32, &U[12288 + lb1]);
  // ---- stage V^T via reg transpose; swizzle on (d>>3)&3 -> 2-way writes ----
  for (int i = tid; i < 128 * 8; i += 256) {
    int t = i >> 3, c8 = i & 7;
    u16x8 vv8 = *(const u16x8*)&vh[(tok0 + t) * N_ + h * 64 + c8 * 8];
    int kk = t >> 5, chunk = (t & 31) >> 3, e = t & 7;
#pragma unroll
    for (int q = 0; q < 8; ++q) {
      int d = c8 * 8 + q;
      VT[kk * 2048 + d * 32 + 8 * (chunk ^ ((d >> 3) & 3)) + e] = vv8[q];
    }
  }
  __syncthreads();

  // ---- QK^T: scores[q][k] ----
  int aoff[4], boff[4];
#pragma unroll
  for (int m = 0; m < 4; ++m) {
    int ra = wr * 64 + m * 16 + fr;
    aoff[m] = ra * 32 + 8 * (fs ^ ((ra >> 1) & 3));
    int rb = wc * 64 + m * 16 + fr;
    boff[m] = rb * 32 + 8 * (fs ^ ((rb >> 1) & 3));
  }
  f32x4 acc[4][4];
#pragma unroll
  for (int m = 0; m < 4; ++m)
#pragma unroll
    for (int n = 0; n < 4; ++n) acc[m][n] = (f32x4){0.f, 0.f, 0.f, 0.f};
#pragma unroll
  for (int kk = 0; kk < 2; ++kk) {
    bf8 ah[4], bh[4];
#pragma unroll
    for (int m = 0; m < 4; ++m) ah[m] = *(const bf8*)&U[kk * 4096 + aoff[m]];
#pragma unroll
    for (int n = 0; n < 4; ++n) bh[n] = *(const bf8*)&U[8192 + kk * 4096 + boff[n]];
#pragma unroll
    for (int m = 0; m < 4; ++m)
#pragma unroll
      for (int n = 0; n < 4; ++n)
        acc[m][n] = __builtin_amdgcn_mfma_f32_16x16x32_bf16(ah[m], bh[n], acc[m][n], 0, 0, 0);
  }

  // ---- mask + scale; row-max partials ----
  bool colok[4];
#pragma unroll
  for (int n = 0; n < 4; ++n) colok[n] = (wc * 64 + n * 16 + fr) < S;
#pragma unroll
  for (int m = 0; m < 4; ++m)
#pragma unroll
    for (int n = 0; n < 4; ++n)
#pragma unroll
      for (int r = 0; r < 4; ++r)
        acc[m][n][r] = colok[n] ? acc[m][n][r] * 0.125f : -3.0e38f;
#pragma unroll
  for (int m = 0; m < 4; ++m)
#pragma unroll
    for (int r = 0; r < 4; ++r) {
      float pm = fmaxf(fmaxf(acc[m][0][r], acc[m][1][r]), fmaxf(acc[m][2][r], acc[m][3][r]));
      pm = fmaxf(pm, __shfl_xor(pm, 1));
      pm = fmaxf(pm, __shfl_xor(pm, 2));
      pm = fmaxf(pm, __shfl_xor(pm, 4));
      pm = fmaxf(pm, __shfl_xor(pm, 8));
      if (fr == 0) rb1[wc][wr * 64 + m * 16 + fs * 4 + r] = pm;
    }
  __syncthreads();   // rb1 ready; all U fragment reads complete

  // ---- exp + row-sum partials; scatter P (bf16) into U as PV A-operand ----
#pragma unroll
  for (int m = 0; m < 4; ++m)
#pragma unroll
    for (int r = 0; r < 4; ++r) {
      int row = wr * 64 + m * 16 + fs * 4 + r;
      float mx = fmaxf(rb1[0][row], rb1[1][row]);
      float ps = 0.f;
#pragma unroll
      for (int n = 0; n < 4; ++n) {
        float e = __expf(acc[m][n][r] - mx);
        acc[m][n][r] = e;
        ps += e;
      }
      ps += __shfl_xor(ps, 1);
      ps += __shfl_xor(ps, 2);
      ps += __shfl_xor(ps, 4);
      ps += __shfl_xor(ps, 8);
      if (fr == 0) rb2[wc][row] = ps;
    }
#pragma unroll
  for (int m = 0; m < 4; ++m)
#pragma unroll
    for (int n = 0; n < 4; ++n) {
      int col = wc * 64 + n * 16 + fr;
      int kk = col >> 5, chunk = (col & 31) >> 3, e = col & 7;
#pragma unroll
      for (int r = 0; r < 4; ++r) {
        int row = wr * 64 + m * 16 + fs * 4 + r;
        U[kk * 4096 + row * 32 + 8 * (chunk ^ ((row >> 1) & 3)) + e] = f2bf(acc[m][n][r]);
      }
    }
  __syncthreads();   // P + rb2 ready

  // ---- PV: out[q][d] = sum_t P[q][t] * VT[d][t]; waves split rows (32 each) ----
  int nk = (S + 31) >> 5;
  int aoff2[2], boff2[4];
#pragma unroll
  for (int m = 0; m < 2; ++m) {
    int ra = wave * 32 + m * 16 + fr;
    aoff2[m] = ra * 32 + 8 * (fs ^ ((ra >> 1) & 3));
  }
#pragma unroll
  for (int n = 0; n < 4; ++n) {
    int rb = n * 16 + fr;
    boff2[n] = rb * 32 + 8 * (fs ^ ((rb >> 3) & 3));
  }
  f32x4 o2[2][4];
#pragma unroll
  for (int m = 0; m < 2; ++m)
#pragma unroll
    for (int n = 0; n < 4; ++n) o2[m][n] = (f32x4){0.f, 0.f, 0.f, 0.f};
  for (int kk = 0; kk < nk; ++kk) {
    bf8 pa[2], vb[4];
#pragma unroll
    for (int m = 0; m < 2; ++m) pa[m] = *(const bf8*)&U[kk * 4096 + aoff2[m]];
#pragma unroll
    for (int n = 0; n < 4; ++n) vb[n] = *(const bf8*)&VT[kk * 2048 + boff2[n]];
#pragma unroll
    for (int m = 0; m < 2; ++m)
#pragma unroll
      for (int n = 0; n < 4; ++n)
        o2[m][n] = __builtin_amdgcn_mfma_f32_16x16x32_bf16(pa[m], vb[n], o2[m][n], 0, 0, 0);
  }

  // ---- epilogue: divide by row sums, write ----
#pragma unroll
  for (int m = 0; m < 2; ++m)
#pragma unroll
    for (int r = 0; r < 4; ++r) {
      int orow = wave * 32 + m * 16 + fs * 4 + r;
      if (orow < S) {
        float inv = 1.0f / (rb2[0][orow] + rb2[1][orow]);
#pragma unroll
        for (int n = 0; n < 4; ++n)
          oh[(tok0 + orow) * N_ + h * 64 + n * 16 + fr] = f2bf(o2[m][n][r] * inv);
      }
    }
}

// ---------------- fused attention, 128<S<=512 — barrier-free waves ----------------
__global__ __launch_bounds__(256) void k_attn_big(
    const unsigned short* __restrict__ qh,
    const unsigned short* __restrict__ kh,
    const unsigned short* __restrict__ vh,
    unsigned short* __restrict__ oh,
    const int* __restrict__ meta, int iter) {
  int p = meta[3 + iter];
  if (p <= 128) return;
  int L = meta[6 + iter], nseq = meta[9 + iter];
  int M = B_ * nseq;
  int mh = blockIdx.x;
  int m = mh >> 3, h = mh & 7;
  if (m >= M) return;
  int S = p;
  int b = m / nseq, g2 = m % nseq;
  size_t tok0 = (size_t)b * L + (size_t)g2 * S;
  __shared__ unsigned short Ks[512 * 66];
  __shared__ unsigned short Vs[512 * 66];
  __shared__ float qrow[4][64];
  __shared__ float Pr[4][512];
  int tid = threadIdx.x;
  for (int i = tid; i < S * 64; i += 256) {
    int t = i >> 6, d = i & 63;
    size_t gi = (tok0 + t) * N_ + h * 64 + d;
    Ks[t * 66 + d] = kh[gi];
    Vs[t * 66 + d] = vh[gi];
  }
  __syncthreads();   // only barrier
  int wave = tid >> 6, lane = tid & 63;
  for (int s = wave; s < S; s += 4) {
    qrow[wave][lane] = bf2f(qh[(tok0 + s) * N_ + h * 64 + lane]);
    const float2* qp = (const float2*)&qrow[wave][0];
    float sc[8];
    float mx = -3.0e38f;
#pragma unroll
    for (int c2 = 0; c2 < 8; ++c2) {
      int t = lane + c2 * 64;
      float sv = -3.0e38f;
      if (t < S) {
        const unsigned int* kp = (const unsigned int*)&Ks[t * 66];
        float ad = 0.f;
#pragma unroll
        for (int j2 = 0; j2 < 32; ++j2) {
          float2 qq = qp[j2];
          unsigned int kw = kp[j2];
          ad += qq.x * bf2f((unsigned short)(kw & 0xffffu));
          ad += qq.y * bf2f((unsigned short)(kw >> 16));
        }
        sv = ad * 0.125f;
      }
      sc[c2] = sv;
      mx = fmaxf(mx, sv);
    }
    for (int off = 32; off > 0; off >>= 1) mx = fmaxf(mx, __shfl_xor(mx, off));
    float ssum = 0.f;
#pragma unroll
    for (int c2 = 0; c2 < 8; ++c2) {
      int t = lane + c2 * 64;
      float e = 0.f;
      if (t < S) { e = __expf(sc[c2] - mx); Pr[wave][t] = e; }
      ssum += e;
    }
    for (int off = 32; off > 0; off >>= 1) ssum += __shfl_xor(ssum, off);
    float inv = 1.0f / ssum;
    float ov = 0.f;
#pragma unroll 8
    for (int t = 0; t < S; ++t) ov += Pr[wave][t] * bf2f(Vs[t * 66 + lane]);
    oh[(tok0 + s) * N_ + h * 64 + lane] = f2bf(ov * inv);
  }
}

// ---------------- final output ----------------
__global__ void k_final(const float* __restrict__ acc, const float* __restrict__ cur,
                        float* __restrict__ out) {
  size_t idx = (size_t)blockIdx.x * 256 + threadIdx.x;
  out[idx] = acc[idx] + cur[idx];
}

extern "C" void kernel_launch(void* const* d_in, const int* in_sizes, int n_in,
                              void* d_out, int out_size, void* d_ws, size_t ws_size,
                              hipStream_t stream) {
  (void)in_sizes; (void)n_in; (void)out_size; (void)ws_size;
  const float* x       = (const float*)d_in[0];
  const float* nv1     = (const float*)d_in[1];
  const float* nv2     = (const float*)d_in[2];
  const float* start_w = (const float*)d_in[3];
  const float* start_b = (const float*)d_in[4];
  const float* mix_w   = (const float*)d_in[5];
  const float* mix_b   = (const float*)d_in[6];
  const float* end_w   = (const float*)d_in[7];
  const float* end_b   = (const float*)d_in[8];
  const float* glin_w  = (const float*)d_in[9];
  const float* glin_b  = (const float*)d_in[10];
  const float* gnorm_g = (const float*)d_in[11];
  const float* gnorm_b = (const float*)d_in[12];
  const float* wq = (const float*)d_in[13];
  const float* bq = (const float*)d_in[14];
  const float* wk = (const float*)d_in[15];
  const float* bk = (const float*)d_in[16];
  const float* wv = (const float*)d_in[17];
  const float* bv = (const float*)d_in[18];
  const float* wo = (const float*)d_in[19];
  const float* bo = (const float*)d_in[20];
  const float* ff1w = (const float*)d_in[21];
  const float* ff1b = (const float*)d_in[22];
  const float* ff2w = (const float*)d_in[23];
  const float* ff2b = (const float*)d_in[24];
  const float* an1g = (const float*)d_in[25];
  const float* an1b = (const float*)d_in[26];
  const float* an2g = (const float*)d_in[27];
  const float* an2b = (const float*)d_in[28];
  const float* nrmg = (const float*)d_in[29];
  const float* nrmb = (const float*)d_in[30];

  char* ws = (char*)d_ws;
  int*   meta = (int*)(ws + OFF_META);
  float* freq = (float*)(ws + OFF_FREQ);
  float* swb  = (float*)(ws + OFF_SW);
  float* beff = (float*)(ws + OFF_BEFF);
  float* P12  = (float*)(ws + OFF_P12);
  float* fsumb = (float*)(ws + OFF_FSB);
  float* osm  = (float*)(ws + OFF_OSM);
  unsigned short* TWH = (unsigned short*)(ws + OFF_TWH);
  unsigned short* TWL = (unsigned short*)(ws + OFF_TWL);
  unsigned short* WB  = (unsigned short*)(ws + OFF_WB);
  unsigned short* WdH = (unsigned short*)(ws + OFF_WDH);
  unsigned short* EWH = (unsigned short*)(ws + OFF_EWH);
  float* cur  = (float*)(ws + OFF_CUR);
  float* accb = (float*)(ws + OFF_ACC);
  unsigned short* XWH = (unsigned short*)(ws + OFF_XWH);
  float* fpart = (float*)(ws + OFF_FP);
  float* Tm   = (float*)(ws + OFF_T);
  unsigned short* WPH = (unsigned short*)(ws + OFF_WPH);
  unsigned short* Gb  = (unsigned short*)(ws + OFF_G);
  unsigned short* G2b = (unsigned short*)(ws + OFF_G2);
  float* PART = (float*)(ws + OFF_PART);
  unsigned short* A0h = (unsigned short*)(ws + OFF_A0); unsigned short* A0l = A0h + PLW;
  unsigned short* A2h = (unsigned short*)(ws + OFF_A2); unsigned short* A2l = A2h + PLW;
  unsigned short* A3h = (unsigned short*)(ws + OFF_A3); unsigned short* A3l = A3h + PLW;
  unsigned short* A4h = (unsigned short*)(ws + OFF_A4);
  unsigned short* A5h = (unsigned short*)(ws + OFF_A5); unsigned short* A5l = A5h + PLW;

  hipMemsetAsync(accb, 0, (size_t)B_ * T_ * N_ * 4, stream);

  // ---- STFT via MFMA (window on twiddle side ONLY; x-hi only, twiddles hi+lo) ----
  k_xw<<<B_ * NFR_, 256, 0, stream>>>(x, XWH);
  k_tw<<<(2 * 384 * 64 + 255) / 256, 256, 0, stream>>>(TWH, TWL);
  k_stftmm<<<dim3(3, NMT_), 256, 0, stream>>>(XWH, TWH, TWL, fpart);
  k_fred<<<NBIN_, 256, 0, stream>>>(fpart, freq, fsumb);
  k_topk<<<1, 64, 0, stream>>>(freq, fsumb, meta, swb);

  // split attention/FF weights into bf16 hi planes (once); Q,K,V contiguous
  const float* wlist[6] = {wq, wk, wv, wo, ff1w, ff2w};
  for (int w = 0; w < 6; ++w)
    k_splith<<<256, 256, 0, stream>>>(wlist[w], WB + (size_t)w * 262144, 262144);
  unsigned short* WqkvH = WB;              // [1536][512]
  unsigned short* WoH = WB + 3 * 262144;
  unsigned short* F1H = WB + 4 * 262144;
  unsigned short* F2H = WB + 5 * 262144;

  const float* curIn = x;
  for (int i = 0; i < 3; ++i) {
    // ---- graph block: fold conv+GCN+mix into one weight W' = T @ Wd ----
    k_adjprep<<<1, 1024, 0, stream>>>(nv1 + i * C_ * 10, nv2 + i * 10 * C_,
                                      mix_w + i * C_ * 96, mix_b + i * C_,
                                      start_b + i * C_, P12, beff);
    k_T<<<4096, 256, 0, stream>>>(P12, mix_w + i * C_ * 96, Tm);
    k_wdh<<<2048, 256, 0, stream>>>(start_w + i * C_ * KH_, WdH);
    k_mm2<<<dim3(4, 8, 8), 256, 0, stream>>>(Tm, WdH, nullptr, nullptr, PART,
                                             1024, 512, 1024, 1024, 0);
    k_redsplit<<<2048, 256, 0, stream>>>(PART, WPH);
    // G = gelu(curIn @ W'^T + b_eff)   [16384 x 1024] bf16; XCD-grouped 1D grid
    k_mmcv<<<1024, 256, 0, stream>>>(curIn, WPH, beff, Gb, 16384, 1024, 512, 512);
    k_repackb<<<B_ * C_ * 16, 256, 0, stream>>>(Gb, G2b);
    k_splith<<<8192, 256, 0, stream>>>(end_w + (size_t)i * 8388608, EWH, 8388608);
    k_mmend<<<dim3(4, 8, 16), 256, 0, stream>>>(G2b, EWH, PART, 1024, 512, 16384);
    k_red16<<<2048, 256, 0, stream>>>(PART, end_b + i * T_, osm);
    k_lwln<<<B_ * T_, 256, 0, stream>>>(osm, glin_w + i * C_ * N_, glin_b + i * N_, curIn,
                                        gnorm_g + i * N_, gnorm_b + i * N_, cur,
                                        A0h, A0l, meta, i);
    k_padtail<<<512, 256, 0, stream>>>(A0h, A0l, meta, i);
    // ---- attention branch (XCD-grouped 1D grids for the GEMMs) ----
    const int* Mdyn = meta + 15 + i;
    k_mmqkv<<<8 * 12 * 22, 256, 0, stream>>>(A0h, WqkvH, bq, bk, bv,
                                             A2h, A3h, A4h, TOKMAX, 512, Mdyn);
    k_attn32<<<2048, 256, 0, stream>>>(A2h, A3h, A4h, A5h, meta, i);
    k_attn_small<<<4096, 256, 0, stream>>>(A2h, A3h, A4h, A5h, meta, i);
    k_attn_big<<<1024, 256, 0, stream>>>(A2h, A3h, A4h, A5h, meta, i);
    k_mmb1<<<8 * 4 * 22, 256, 0, stream>>>(A5h, WoH, bo, A2h, A2l, TOKMAX, 512, 512, Mdyn, 0);
    k_lnadd<<<TOKMAX, 256, 0, stream>>>(A0h, A0l, A2h, A2l, an1g, an1b, A3h, A3l, meta, i);
    k_mmb1<<<8 * 4 * 22, 256, 0, stream>>>(A3h, F1H, ff1b, A4h, nullptr, TOKMAX, 512, 512, Mdyn, 1);
    k_mmb1<<<8 * 4 * 22, 256, 0, stream>>>(A4h, F2H, ff2b, A5h, A5l, TOKMAX, 512, 512, Mdyn, 0);
    k_lnfin<<<TOKMAX, 256, 0, stream>>>(A3h, A3l, A5h, A5l, an2g, an2b, nrmg, nrmb,
                                        swb, accb, meta, i);
    curIn = cur;
  }
  k_final<<<(B_ * T_ * N_) / 256, 256, 0, stream>>>(accb, curIn, (float*)d_out);
}